// Round 1
// baseline (18745.097 us; speedup 1.0000x reference)
//
#include <hip/hip_runtime.h>
#include <math.h>

#define BB   512   // batch
#define CD   512   // channels c
#define HD   512   // hidden
#define LS   256   // spatial keys h*w
#define LP1  257   // keys + EOS
#define NCLS 38    // num classes
#define G4   2048  // 4*hid

// ---------------- eos_p[hh] = sum_c i2h_w[hh][c]*eos_emb[c] (once) -------------
__global__ void k_eos_p(const float* __restrict__ i2h_w, const float* __restrict__ eos_emb,
                        float* __restrict__ eos_p) {
  int hh = blockIdx.x * blockDim.x + threadIdx.x;
  if (hh >= HD) return;
  const float* row = i2h_w + (size_t)hh * CD;
  float acc = 0.f;
  for (int c = 0; c < CD; ++c) acc += row[c] * eos_emb[c];
  eos_p[hh] = acc;
}

// ---------------- Hp[b][m][n] = sum_k i2h_w[m][k] * batch_H[b][k][n] -----------
// NN GEMM per b: M=HD(hh), N=LS(l), K=CD(c). 64x64 tile, BK=16, 256 thr, 4x4/thr.
__global__ __launch_bounds__(256) void k_hp(const float* __restrict__ A,
                                            const float* __restrict__ Bh,
                                            float* __restrict__ Hp) {
  __shared__ float As[64][17];
  __shared__ float Bs[16][68];
  int b  = blockIdx.z;
  int m0 = blockIdx.y * 64;
  int n0 = blockIdx.x * 64;
  int tid = threadIdx.x;
  const float* Bb = Bh + (size_t)b * CD * LS;
  float acc[4][4] = {};
  int lr = tid >> 2, lk4 = (tid & 3) * 4;    // A tile load
  int bk = tid >> 4, bn4 = (tid & 15) * 4;   // B tile load
  int tr = (tid >> 4) * 4, tc = (tid & 15) * 4;
  for (int k0 = 0; k0 < CD; k0 += 16) {
    float4 av = *(const float4*)&A[(size_t)(m0 + lr) * CD + k0 + lk4];
    As[lr][lk4 + 0] = av.x; As[lr][lk4 + 1] = av.y;
    As[lr][lk4 + 2] = av.z; As[lr][lk4 + 3] = av.w;
    float4 bv = *(const float4*)&Bb[(size_t)(k0 + bk) * LS + n0 + bn4];
    Bs[bk][bn4 + 0] = bv.x; Bs[bk][bn4 + 1] = bv.y;
    Bs[bk][bn4 + 2] = bv.z; Bs[bk][bn4 + 3] = bv.w;
    __syncthreads();
#pragma unroll
    for (int kk = 0; kk < 16; ++kk) {
      float a0 = As[tr + 0][kk], a1 = As[tr + 1][kk], a2 = As[tr + 2][kk], a3 = As[tr + 3][kk];
      float b0 = Bs[kk][tc + 0], b1 = Bs[kk][tc + 1], b2 = Bs[kk][tc + 2], b3 = Bs[kk][tc + 3];
      acc[0][0] += a0 * b0; acc[0][1] += a0 * b1; acc[0][2] += a0 * b2; acc[0][3] += a0 * b3;
      acc[1][0] += a1 * b0; acc[1][1] += a1 * b1; acc[1][2] += a1 * b2; acc[1][3] += a1 * b3;
      acc[2][0] += a2 * b0; acc[2][1] += a2 * b1; acc[2][2] += a2 * b2; acc[2][3] += a2 * b3;
      acc[3][0] += a3 * b0; acc[3][1] += a3 * b1; acc[3][2] += a3 * b2; acc[3][3] += a3 * b3;
    }
    __syncthreads();
  }
#pragma unroll
  for (int i = 0; i < 4; ++i) {
    float4 v = make_float4(acc[i][0], acc[i][1], acc[i][2], acc[i][3]);
    *(float4*)&Hp[((size_t)b * HD + m0 + tr + i) * LS + n0 + tc] = v;
  }
}

// ---------------- NT GEMM: C[m][n] = sum_k A[m][k]*B[n][k] (+optional 2nd pair, biases)
__global__ __launch_bounds__(256) void k_gemm_nt(const float* __restrict__ A1,
                                                 const float* __restrict__ B1,
                                                 const float* __restrict__ A2,
                                                 const float* __restrict__ B2,
                                                 const float* __restrict__ bias1,
                                                 const float* __restrict__ bias2,
                                                 float* __restrict__ Cm,
                                                 int M, int N, int K) {
  __shared__ float As[64][17];
  __shared__ float Bs[64][17];
  int m0 = blockIdx.y * 64, n0 = blockIdx.x * 64;
  int tid = threadIdx.x;
  int lr = tid >> 2, lk4 = (tid & 3) * 4;
  int tr = (tid >> 4) * 4, tc = (tid & 15) * 4;
  float acc[4][4] = {};
  for (int pass = 0; pass < 2; ++pass) {
    const float* A = pass ? A2 : A1;
    const float* Bm = pass ? B2 : B1;
    if (!A) continue;
    for (int k0 = 0; k0 < K; k0 += 16) {
      float4 av = *(const float4*)&A[(size_t)(m0 + lr) * K + k0 + lk4];
      As[lr][lk4 + 0] = av.x; As[lr][lk4 + 1] = av.y;
      As[lr][lk4 + 2] = av.z; As[lr][lk4 + 3] = av.w;
      float4 bv = *(const float4*)&Bm[(size_t)(n0 + lr) * K + k0 + lk4];
      Bs[lr][lk4 + 0] = bv.x; Bs[lr][lk4 + 1] = bv.y;
      Bs[lr][lk4 + 2] = bv.z; Bs[lr][lk4 + 3] = bv.w;
      __syncthreads();
#pragma unroll
      for (int kk = 0; kk < 16; ++kk) {
        float a0 = As[tr + 0][kk], a1 = As[tr + 1][kk], a2 = As[tr + 2][kk], a3 = As[tr + 3][kk];
        float b0 = Bs[tc + 0][kk], b1 = Bs[tc + 1][kk], b2 = Bs[tc + 2][kk], b3 = Bs[tc + 3][kk];
        acc[0][0] += a0 * b0; acc[0][1] += a0 * b1; acc[0][2] += a0 * b2; acc[0][3] += a0 * b3;
        acc[1][0] += a1 * b0; acc[1][1] += a1 * b1; acc[1][2] += a1 * b2; acc[1][3] += a1 * b3;
        acc[2][0] += a2 * b0; acc[2][1] += a2 * b1; acc[2][2] += a2 * b2; acc[2][3] += a2 * b3;
        acc[3][0] += a3 * b0; acc[3][1] += a3 * b1; acc[3][2] += a3 * b2; acc[3][3] += a3 * b3;
      }
      __syncthreads();
    }
  }
  float bs[4];
#pragma unroll
  for (int j = 0; j < 4; ++j) {
    int n = n0 + tc + j;
    bs[j] = (bias1 ? bias1[n] : 0.f) + (bias2 ? bias2[n] : 0.f);
  }
#pragma unroll
  for (int i = 0; i < 4; ++i) {
    float4 v = make_float4(acc[i][0] + bs[0], acc[i][1] + bs[1],
                           acc[i][2] + bs[2], acc[i][3] + bs[3]);
    *(float4*)&Cm[(size_t)(m0 + tr + i) * N + n0 + tc] = v;
  }
}

// ---------------- fused attention: e -> softmax -> alpha(out) -> ctx -----------
// one block (256 thr) per b; lane l owns key l; Hp layout [b][hh][l] coalesces.
__global__ __launch_bounds__(256) void k_att(const float* __restrict__ Hp,
                                             const float* __restrict__ eos_p,
                                             const float* __restrict__ q,
                                             const float* __restrict__ score_w,
                                             const float* __restrict__ mask,
                                             const float* __restrict__ batch_H,
                                             const float* __restrict__ eos_emb,
                                             float* __restrict__ ctx,
                                             float* __restrict__ char_maps,
                                             int t, int T) {
  __shared__ float q_s[HD];
  __shared__ float sw[HD];
  __shared__ float a_s[LP1];
  __shared__ float red[256];
  int b = blockIdx.x, tid = threadIdx.x;
  q_s[tid]       = q[(size_t)b * HD + tid];
  q_s[tid + 256] = q[(size_t)b * HD + tid + 256];
  sw[tid]        = score_w[tid];
  sw[tid + 256]  = score_w[tid + 256];
  __syncthreads();

  const float* hpB = Hp + (size_t)b * HD * LS;
  float e = 0.f;
  for (int hh = 0; hh < HD; ++hh)
    e += tanhf(hpB[(size_t)hh * LS + tid] + q_s[hh]) * sw[hh];

  // EOS score (parallel partial + tree reduce)
  float pe = tanhf(eos_p[tid] + q_s[tid]) * sw[tid]
           + tanhf(eos_p[tid + 256] + q_s[tid + 256]) * sw[tid + 256];
  red[tid] = pe; __syncthreads();
  for (int s = 128; s > 0; s >>= 1) { if (tid < s) red[tid] += red[tid + s]; __syncthreads(); }
  float e_eos = red[0]; __syncthreads();

  // padding mask (1 = masked)
  float pm = rintf(1.0f - mask[(size_t)b * LS + tid]);
  if (pm >= 0.5f) e = -INFINITY;

  // softmax over 257
  red[tid] = e; __syncthreads();
  for (int s = 128; s > 0; s >>= 1) { if (tid < s) red[tid] = fmaxf(red[tid], red[tid + s]); __syncthreads(); }
  float m = fmaxf(red[0], e_eos); __syncthreads();
  float p = expf(e - m);
  red[tid] = p; __syncthreads();
  for (int s = 128; s > 0; s >>= 1) { if (tid < s) red[tid] += red[tid + s]; __syncthreads(); }
  float peos = expf(e_eos - m);
  float inv = 1.0f / (red[0] + peos); __syncthreads();

  float al = p * inv;
  a_s[tid] = al;
  if (tid == 0) a_s[256] = peos * inv;
  float* cm = char_maps + ((size_t)b * T + t) * LP1;
  cm[tid] = al;
  if (tid == 0) cm[256] = peos * inv;
  __syncthreads();

  // ctx[b][c] = sum_l alpha[l]*batch_H[b][c][l] + alpha[256]*eos_emb[c]
  int wave = tid >> 6, lane = tid & 63;
  const float* bh = batch_H + (size_t)b * CD * LS;
  float aeos = a_s[256];
  for (int c = wave; c < CD; c += 4) {
    float acc = 0.f;
    const float* row = bh + (size_t)c * LS;
    for (int l = lane; l < LS; l += 64) acc += a_s[l] * row[l];
    for (int off = 32; off > 0; off >>= 1) acc += __shfl_down(acc, off);
    if (lane == 0) ctx[(size_t)b * CD + c] = acc + aeos * eos_emb[c];
  }
}

// ---------------- LSTM pointwise ----------------------------------------------
__global__ void k_lstm(const float* __restrict__ gates, const float* __restrict__ cp,
                       float* __restrict__ hn, float* __restrict__ cn) {
  int i = blockIdx.x * 256 + threadIdx.x;   // over BB*HD
  int b = i >> 9, hh = i & 511;
  const float* g = gates + (size_t)b * G4;
  float ig = g[hh], fg = g[512 + hh], gg = g[1024 + hh], og = g[1536 + hh];
  float si = 1.f / (1.f + expf(-ig));
  float sf = 1.f / (1.f + expf(-fg));
  float so = 1.f / (1.f + expf(-og));
  float c  = sf * cp[i] + si * tanhf(gg);
  cn[i] = c;
  hn[i] = so * tanhf(c);
}

// ---------------- logits[b][t][n] = hn[b]·gen_w[n] + gen_b[n] ------------------
__global__ void k_logits(const float* __restrict__ hn, const float* __restrict__ gen_w,
                         const float* __restrict__ gen_b, float* __restrict__ out,
                         int t, int T) {
  int idx = blockIdx.x * blockDim.x + threadIdx.x;
  if (idx >= BB * NCLS) return;
  int b = idx / NCLS, n = idx % NCLS;
  const float* h = hn + (size_t)b * HD;
  const float* w = gen_w + (size_t)n * HD;
  float acc = gen_b[n];
  for (int k = 0; k < HD; ++k) acc += h[k] * w[k];
  out[((size_t)b * T + t) * NCLS + n] = acc;
}

extern "C" void kernel_launch(void* const* d_in, const int* in_sizes, int n_in,
                              void* d_out, int out_size, void* d_ws, size_t ws_size,
                              hipStream_t stream) {
  const float* batch_H = (const float*)d_in[0];
  const float* mask    = (const float*)d_in[1];
  const float* i2h_w   = (const float*)d_in[2];
  const float* h2h_w   = (const float*)d_in[3];
  const float* h2h_b   = (const float*)d_in[4];
  const float* score_w = (const float*)d_in[5];
  const float* w_ih    = (const float*)d_in[6];
  const float* w_hh    = (const float*)d_in[7];
  const float* b_ih    = (const float*)d_in[8];
  const float* b_hh    = (const float*)d_in[9];
  const float* gen_w   = (const float*)d_in[10];
  const float* gen_b   = (const float*)d_in[11];
  const float* eos_emb = (const float*)d_in[12];

  int T = out_size / (BB * (NCLS + LP1));   // 26 for the reference setup

  float* ws = (float*)d_ws;
  size_t off = 0;
  float* Hp    = ws + off; off += (size_t)BB * HD * LS;
  float* eos_p = ws + off; off += HD;
  float* h0    = ws + off; off += (size_t)BB * HD;
  float* h1    = ws + off; off += (size_t)BB * HD;
  float* c0    = ws + off; off += (size_t)BB * HD;
  float* c1    = ws + off; off += (size_t)BB * HD;
  float* qb    = ws + off; off += (size_t)BB * HD;
  float* ctx   = ws + off; off += (size_t)BB * CD;
  float* gates = ws + off; off += (size_t)BB * G4;

  float* logits    = (float*)d_out;
  float* char_maps = logits + (size_t)BB * T * NCLS;

  hipMemsetAsync(h0, 0, (size_t)BB * HD * sizeof(float), stream);
  hipMemsetAsync(c0, 0, (size_t)BB * HD * sizeof(float), stream);

  k_eos_p<<<2, 256, 0, stream>>>(i2h_w, eos_emb, eos_p);
  k_hp<<<dim3(LS / 64, HD / 64, BB), 256, 0, stream>>>(i2h_w, batch_H, Hp);

  float *hp = h0, *cp = c0, *hn = h1, *cnb = c1;
  for (int t = 0; t < T; ++t) {
    k_gemm_nt<<<dim3(HD / 64, BB / 64), 256, 0, stream>>>(
        hp, h2h_w, nullptr, nullptr, h2h_b, nullptr, qb, BB, HD, HD);
    k_att<<<BB, 256, 0, stream>>>(Hp, eos_p, qb, score_w, mask, batch_H, eos_emb,
                                  ctx, char_maps, t, T);
    k_gemm_nt<<<dim3(G4 / 64, BB / 64), 256, 0, stream>>>(
        ctx, w_ih, hp, w_hh, b_ih, b_hh, gates, BB, G4, CD);
    k_lstm<<<(BB * HD) / 256, 256, 0, stream>>>(gates, cp, hn, cnb);
    k_logits<<<(BB * NCLS + 255) / 256, 256, 0, stream>>>(hn, gen_w, gen_b, logits, t, T);
    float* tmp;
    tmp = hp; hp = hn;  hn  = tmp;
    tmp = cp; cp = cnb; cnb = tmp;
  }
}

// Round 2
// 7107.932 us; speedup vs baseline: 2.6372x; 2.6372x over previous
//
#include <hip/hip_runtime.h>
#include <math.h>

#define BB   512   // batch
#define CD   512   // channels c
#define HD   512   // hidden
#define LS   256   // spatial keys h*w
#define LP1  257   // keys + EOS
#define NCLS 38    // num classes
#define G4   2048  // 4*hid

// ---------------- eos_p[hh] = sum_c i2h_w[hh][c]*eos_emb[c] (once) -------------
__global__ void k_eos_p(const float* __restrict__ i2h_w, const float* __restrict__ eos_emb,
                        float* __restrict__ eos_p) {
  int hh = blockIdx.x * blockDim.x + threadIdx.x;
  if (hh >= HD) return;
  const float* row = i2h_w + (size_t)hh * CD;
  float acc = 0.f;
  for (int c = 0; c < CD; ++c) acc += row[c] * eos_emb[c];
  eos_p[hh] = acc;
}

// ---------------- Hp[b][m][n] = sum_k i2h_w[m][k] * batch_H[b][k][n] -----------
__global__ __launch_bounds__(256) void k_hp(const float* __restrict__ A,
                                            const float* __restrict__ Bh,
                                            float* __restrict__ Hp) {
  __shared__ float As[64][17];
  __shared__ float Bs[16][68];
  int b  = blockIdx.z;
  int m0 = blockIdx.y * 64;
  int n0 = blockIdx.x * 64;
  int tid = threadIdx.x;
  const float* Bb = Bh + (size_t)b * CD * LS;
  float acc[4][4] = {};
  int lr = tid >> 2, lk4 = (tid & 3) * 4;
  int bk = tid >> 4, bn4 = (tid & 15) * 4;
  int tr = (tid >> 4) * 4, tc = (tid & 15) * 4;
  for (int k0 = 0; k0 < CD; k0 += 16) {
    float4 av = *(const float4*)&A[(size_t)(m0 + lr) * CD + k0 + lk4];
    As[lr][lk4 + 0] = av.x; As[lr][lk4 + 1] = av.y;
    As[lr][lk4 + 2] = av.z; As[lr][lk4 + 3] = av.w;
    float4 bv = *(const float4*)&Bb[(size_t)(k0 + bk) * LS + n0 + bn4];
    Bs[bk][bn4 + 0] = bv.x; Bs[bk][bn4 + 1] = bv.y;
    Bs[bk][bn4 + 2] = bv.z; Bs[bk][bn4 + 3] = bv.w;
    __syncthreads();
#pragma unroll
    for (int kk = 0; kk < 16; ++kk) {
      float a0 = As[tr + 0][kk], a1 = As[tr + 1][kk], a2 = As[tr + 2][kk], a3 = As[tr + 3][kk];
      float b0 = Bs[kk][tc + 0], b1 = Bs[kk][tc + 1], b2 = Bs[kk][tc + 2], b3 = Bs[kk][tc + 3];
      acc[0][0] += a0 * b0; acc[0][1] += a0 * b1; acc[0][2] += a0 * b2; acc[0][3] += a0 * b3;
      acc[1][0] += a1 * b0; acc[1][1] += a1 * b1; acc[1][2] += a1 * b2; acc[1][3] += a1 * b3;
      acc[2][0] += a2 * b0; acc[2][1] += a2 * b1; acc[2][2] += a2 * b2; acc[2][3] += a2 * b3;
      acc[3][0] += a3 * b0; acc[3][1] += a3 * b1; acc[3][2] += a3 * b2; acc[3][3] += a3 * b3;
    }
    __syncthreads();
  }
#pragma unroll
  for (int i = 0; i < 4; ++i) {
    float4 v = make_float4(acc[i][0], acc[i][1], acc[i][2], acc[i][3]);
    *(float4*)&Hp[((size_t)b * HD + m0 + tr + i) * LS + n0 + tc] = v;
  }
}

// ---------------- NT GEMM (gates): C = A1*B1^T + A2*B2^T + biases --------------
__global__ __launch_bounds__(256) void k_gemm_nt(const float* __restrict__ A1,
                                                 const float* __restrict__ B1,
                                                 const float* __restrict__ A2,
                                                 const float* __restrict__ B2,
                                                 const float* __restrict__ bias1,
                                                 const float* __restrict__ bias2,
                                                 float* __restrict__ Cm,
                                                 int M, int N, int K) {
  __shared__ float As[64][17];
  __shared__ float Bs[64][17];
  int m0 = blockIdx.y * 64, n0 = blockIdx.x * 64;
  int tid = threadIdx.x;
  int lr = tid >> 2, lk4 = (tid & 3) * 4;
  int tr = (tid >> 4) * 4, tc = (tid & 15) * 4;
  float acc[4][4] = {};
  for (int pass = 0; pass < 2; ++pass) {
    const float* A = pass ? A2 : A1;
    const float* Bm = pass ? B2 : B1;
    if (!A) continue;
    for (int k0 = 0; k0 < K; k0 += 16) {
      float4 av = *(const float4*)&A[(size_t)(m0 + lr) * K + k0 + lk4];
      As[lr][lk4 + 0] = av.x; As[lr][lk4 + 1] = av.y;
      As[lr][lk4 + 2] = av.z; As[lr][lk4 + 3] = av.w;
      float4 bv = *(const float4*)&Bm[(size_t)(n0 + lr) * K + k0 + lk4];
      Bs[lr][lk4 + 0] = bv.x; Bs[lr][lk4 + 1] = bv.y;
      Bs[lr][lk4 + 2] = bv.z; Bs[lr][lk4 + 3] = bv.w;
      __syncthreads();
#pragma unroll
      for (int kk = 0; kk < 16; ++kk) {
        float a0 = As[tr + 0][kk], a1 = As[tr + 1][kk], a2 = As[tr + 2][kk], a3 = As[tr + 3][kk];
        float b0 = Bs[tc + 0][kk], b1 = Bs[tc + 1][kk], b2 = Bs[tc + 2][kk], b3 = Bs[tc + 3][kk];
        acc[0][0] += a0 * b0; acc[0][1] += a0 * b1; acc[0][2] += a0 * b2; acc[0][3] += a0 * b3;
        acc[1][0] += a1 * b0; acc[1][1] += a1 * b1; acc[1][2] += a1 * b2; acc[1][3] += a1 * b3;
        acc[2][0] += a2 * b0; acc[2][1] += a2 * b1; acc[2][2] += a2 * b2; acc[2][3] += a2 * b3;
        acc[3][0] += a3 * b0; acc[3][1] += a3 * b1; acc[3][2] += a3 * b2; acc[3][3] += a3 * b3;
      }
      __syncthreads();
    }
  }
  float bs[4];
#pragma unroll
  for (int j = 0; j < 4; ++j) {
    int n = n0 + tc + j;
    bs[j] = (bias1 ? bias1[n] : 0.f) + (bias2 ? bias2[n] : 0.f);
  }
#pragma unroll
  for (int i = 0; i < 4; ++i) {
    float4 v = make_float4(acc[i][0] + bs[0], acc[i][1] + bs[1],
                           acc[i][2] + bs[2], acc[i][3] + bs[3]);
    *(float4*)&Cm[(size_t)(m0 + tr + i) * N + n0 + tc] = v;
  }
}

// ---------------- fused: q-GEMM -> scores -> softmax -> alpha -> ctx -----------
// one block (1024 thr, 16 waves) per b.
__global__ __launch_bounds__(1024) void k_att(const float* __restrict__ Hp,
                                              const float* __restrict__ eos_p,
                                              const float* __restrict__ hprev,
                                              const float* __restrict__ h2h_w,
                                              const float* __restrict__ h2h_b,
                                              const float* __restrict__ score_w,
                                              const float* __restrict__ mask,
                                              const float* __restrict__ batch_H,
                                              const float* __restrict__ eos_emb,
                                              float* __restrict__ ctx,
                                              float* __restrict__ char_maps,
                                              int t, int T) {
  __shared__ float q_s[HD];
  __shared__ float hp_s[HD];
  __shared__ float sw_s[HD];
  __shared__ float part[16][260];
  __shared__ float a_s[260];
  __shared__ float wred[16];
  __shared__ float sget[4];   // [0]=max m, [1]=inv denom, [2]=e_eos

  int b = blockIdx.x, tid = threadIdx.x;
  int wid = tid >> 6, lane = tid & 63;
  int l4 = lane * 4;

  if (tid < HD) {
    hp_s[tid] = hprev[(size_t)b * HD + tid];
    sw_s[tid] = score_w[tid];
  }
  __syncthreads();

  // ---- q[r] = sum_k hprev[k]*h2h_w[r][k] + h2h_b[r]; wave per row, rows stride 16
  {
    const float4* hp4 = (const float4*)hp_s;
    float4 h0 = hp4[lane];
    float4 h1 = hp4[lane + 64];
    for (int r = wid; r < HD; r += 16) {
      const float4* wr = (const float4*)&h2h_w[(size_t)r * HD];
      float4 a0 = wr[lane];
      float4 a1 = wr[lane + 64];
      float acc = a0.x * h0.x + a0.y * h0.y + a0.z * h0.z + a0.w * h0.w
                + a1.x * h1.x + a1.y * h1.y + a1.z * h1.z + a1.w * h1.w;
#pragma unroll
      for (int off = 32; off > 0; off >>= 1) acc += __shfl_down(acc, off);
      if (lane == 0) q_s[r] = acc + h2h_b[r];
    }
  }
  __syncthreads();

  // ---- scores: e[l] = sum_hh tanh(Hp[hh][l]+q[hh])*sw[hh]; group wid owns hh%16==wid
  {
    const float* hpB = Hp + (size_t)b * HD * LS;
    float4 e4 = make_float4(0.f, 0.f, 0.f, 0.f);
#pragma unroll 4
    for (int hh = wid; hh < HD; hh += 16) {
      float4 v = *(const float4*)&hpB[(size_t)hh * LS + l4];
      float qv = q_s[hh], s = sw_s[hh];
      e4.x += tanhf(v.x + qv) * s;
      e4.y += tanhf(v.y + qv) * s;
      e4.z += tanhf(v.z + qv) * s;
      e4.w += tanhf(v.w + qv) * s;
    }
    *(float4*)&part[wid][l4] = e4;
  }
  // ---- eos score partials (threads 0..511), wave reduce -> wred
  {
    float ve = 0.f;
    if (tid < HD) ve = tanhf(eos_p[tid] + q_s[tid]) * sw_s[tid];
#pragma unroll
    for (int off = 32; off > 0; off >>= 1) ve += __shfl_down(ve, off);
    if (lane == 0) wred[wid] = ve;
  }
  __syncthreads();
  if (tid == 0) {
    float s = 0.f;
#pragma unroll
    for (int i = 0; i < 16; ++i) s += wred[i];
    sget[2] = s;
  }
  __syncthreads();

  // ---- per-l score combine + mask; block max
  float e = -INFINITY;
  if (tid < LS) {
    float s = 0.f;
#pragma unroll
    for (int g = 0; g < 16; ++g) s += part[g][tid];
    float pm = rintf(1.0f - mask[(size_t)b * LS + tid]);
    e = (pm >= 0.5f) ? -INFINITY : s;
  }
  {
    float mv = e;
#pragma unroll
    for (int off = 32; off > 0; off >>= 1) mv = fmaxf(mv, __shfl_down(mv, off));
    if (lane == 0) wred[wid] = mv;
  }
  __syncthreads();
  if (tid == 0) {
    float m = sget[2];
#pragma unroll
    for (int i = 0; i < 4; ++i) m = fmaxf(m, wred[i]);
    sget[0] = m;
  }
  __syncthreads();
  float m = sget[0];
  float p = (tid < LS) ? expf(e - m) : 0.f;
  {
    float sv = p;
#pragma unroll
    for (int off = 32; off > 0; off >>= 1) sv += __shfl_down(sv, off);
    if (lane == 0) wred[wid] = sv;
  }
  __syncthreads();
  if (tid == 0) {
    float s = expf(sget[2] - m);
#pragma unroll
    for (int i = 0; i < 4; ++i) s += wred[i];
    sget[1] = 1.0f / s;
  }
  __syncthreads();
  float inv = sget[1];
  float* cm = char_maps + ((size_t)b * T + t) * LP1;
  if (tid < LS) {
    float al = p * inv;
    a_s[tid] = al;
    cm[tid] = al;
  }
  if (tid == 0) {
    float ae = expf(sget[2] - m) * inv;
    a_s[256] = ae;
    cm[256] = ae;
  }
  __syncthreads();

  // ---- ctx[c] = sum_l a[l]*batch_H[c][l] + a_eos*eos_emb[c]; wave per c stride 16
  {
    float4 af = ((const float4*)a_s)[lane];
    float aeos = a_s[256];
    const float* bh = batch_H + (size_t)b * CD * LS;
    for (int c = wid; c < CD; c += 16) {
      float4 v = *(const float4*)&bh[(size_t)c * LS + l4];
      float acc = v.x * af.x + v.y * af.y + v.z * af.z + v.w * af.w;
#pragma unroll
      for (int off = 32; off > 0; off >>= 1) acc += __shfl_down(acc, off);
      if (lane == 0) ctx[(size_t)b * CD + c] = acc + aeos * eos_emb[c];
    }
  }
}

// ---------------- LSTM pointwise ----------------------------------------------
__global__ void k_lstm(const float* __restrict__ gates, const float* __restrict__ cp,
                       float* __restrict__ hn, float* __restrict__ cn) {
  int i = blockIdx.x * 256 + threadIdx.x;
  int b = i >> 9, hh = i & 511;
  const float* g = gates + (size_t)b * G4;
  float ig = g[hh], fg = g[512 + hh], gg = g[1024 + hh], og = g[1536 + hh];
  float si = 1.f / (1.f + expf(-ig));
  float sf = 1.f / (1.f + expf(-fg));
  float so = 1.f / (1.f + expf(-og));
  float c  = sf * cp[i] + si * tanhf(gg);
  cn[i] = c;
  hn[i] = so * tanhf(c);
}

// ---------------- logits: block per b, wave per class -------------------------
__global__ __launch_bounds__(256) void k_logits(const float* __restrict__ hn,
                                                const float* __restrict__ gen_w,
                                                const float* __restrict__ gen_b,
                                                float* __restrict__ out,
                                                int t, int T) {
  int b = blockIdx.x, tid = threadIdx.x;
  int wid = tid >> 6, lane = tid & 63;
  const float4* h4 = (const float4*)(hn + (size_t)b * HD);
  float4 h0 = h4[lane];
  float4 h1 = h4[lane + 64];
  for (int n = wid; n < NCLS; n += 4) {
    const float4* w4 = (const float4*)(gen_w + (size_t)n * HD);
    float4 a0 = w4[lane];
    float4 a1 = w4[lane + 64];
    float acc = a0.x * h0.x + a0.y * h0.y + a0.z * h0.z + a0.w * h0.w
              + a1.x * h1.x + a1.y * h1.y + a1.z * h1.z + a1.w * h1.w;
#pragma unroll
    for (int off = 32; off > 0; off >>= 1) acc += __shfl_down(acc, off);
    if (lane == 0) out[((size_t)b * T + t) * NCLS + n] = acc + gen_b[n];
  }
}

extern "C" void kernel_launch(void* const* d_in, const int* in_sizes, int n_in,
                              void* d_out, int out_size, void* d_ws, size_t ws_size,
                              hipStream_t stream) {
  const float* batch_H = (const float*)d_in[0];
  const float* mask    = (const float*)d_in[1];
  const float* i2h_w   = (const float*)d_in[2];
  const float* h2h_w   = (const float*)d_in[3];
  const float* h2h_b   = (const float*)d_in[4];
  const float* score_w = (const float*)d_in[5];
  const float* w_ih    = (const float*)d_in[6];
  const float* w_hh    = (const float*)d_in[7];
  const float* b_ih    = (const float*)d_in[8];
  const float* b_hh    = (const float*)d_in[9];
  const float* gen_w   = (const float*)d_in[10];
  const float* gen_b   = (const float*)d_in[11];
  const float* eos_emb = (const float*)d_in[12];

  int T = out_size / (BB * (NCLS + LP1));   // 26

  float* ws = (float*)d_ws;
  size_t off = 0;
  float* Hp    = ws + off; off += (size_t)BB * HD * LS;
  float* eos_p = ws + off; off += HD;
  float* h0    = ws + off; off += (size_t)BB * HD;
  float* h1    = ws + off; off += (size_t)BB * HD;
  float* c0    = ws + off; off += (size_t)BB * HD;
  float* c1    = ws + off; off += (size_t)BB * HD;
  float* ctx   = ws + off; off += (size_t)BB * CD;
  float* gates = ws + off; off += (size_t)BB * G4;

  float* logits    = (float*)d_out;
  float* char_maps = logits + (size_t)BB * T * NCLS;

  hipMemsetAsync(h0, 0, (size_t)BB * HD * sizeof(float), stream);
  hipMemsetAsync(c0, 0, (size_t)BB * HD * sizeof(float), stream);

  k_eos_p<<<2, 256, 0, stream>>>(i2h_w, eos_emb, eos_p);
  k_hp<<<dim3(LS / 64, HD / 64, BB), 256, 0, stream>>>(i2h_w, batch_H, Hp);

  float *hp = h0, *cp = c0, *hn = h1, *cnb = c1;
  for (int t = 0; t < T; ++t) {
    k_att<<<BB, 1024, 0, stream>>>(Hp, eos_p, hp, h2h_w, h2h_b, score_w, mask,
                                   batch_H, eos_emb, ctx, char_maps, t, T);
    k_gemm_nt<<<dim3(G4 / 64, BB / 64), 256, 0, stream>>>(
        ctx, w_ih, hp, w_hh, b_ih, b_hh, gates, BB, G4, CD);
    k_lstm<<<(BB * HD) / 256, 256, 0, stream>>>(gates, cp, hn, cnb);
    k_logits<<<BB, 256, 0, stream>>>(hn, gen_w, gen_b, logits, t, T);
    float* tmp;
    tmp = hp; hp = hn;  hn  = tmp;
    tmp = cp; cp = cnb; cnb = tmp;
  }
}

// Round 3
// 3603.686 us; speedup vs baseline: 5.2016x; 1.9724x over previous
//
#include <hip/hip_runtime.h>
#include <math.h>

#define BB   512   // batch
#define CD   512   // channels c
#define HD   512   // hidden
#define LS   256   // spatial keys h*w
#define LP1  257   // keys + EOS
#define NCLS 38    // num classes
#define G4   2048  // 4*hid

typedef unsigned short u16;
typedef __attribute__((ext_vector_type(8))) short short8;
typedef __attribute__((ext_vector_type(4))) float f32x4;

__device__ __forceinline__ u16 f2b(float f) {
  union { float f; unsigned u; } v; v.f = f;
  unsigned r = v.u + 0x7fffu + ((v.u >> 16) & 1u);
  return (u16)(r >> 16);
}
__device__ __forceinline__ float b2f(unsigned bits) {
  union { unsigned u; float f; } v; v.u = bits << 16;
  return v.f;
}
__device__ __forceinline__ void unpack8(uint4 r, float* o) {
  o[0] = b2f(r.x & 0xffffu); o[1] = b2f(r.x >> 16);
  o[2] = b2f(r.y & 0xffffu); o[3] = b2f(r.y >> 16);
  o[4] = b2f(r.z & 0xffffu); o[5] = b2f(r.z >> 16);
  o[6] = b2f(r.w & 0xffffu); o[7] = b2f(r.w >> 16);
}

// ---------------- f32 -> bf16 elementwise (weights, once) ----------------------
__global__ void k_cvt(const float* __restrict__ in, u16* __restrict__ out, int n4) {
  int i = blockIdx.x * 256 + threadIdx.x;
  if (i >= n4) return;
  float4 v = *(const float4*)&in[i * 4];
  ushort4 o;
  o.x = f2b(v.x); o.y = f2b(v.y); o.z = f2b(v.z); o.w = f2b(v.w);
  *(ushort4*)&out[i * 4] = o;
}

// ---------------- batch_H [b][c][l] f32 -> Hl16 [b][l][c] bf16 (once) ----------
__global__ __launch_bounds__(256) void k_tr16(const float* __restrict__ in,
                                              u16* __restrict__ out) {
  __shared__ float Ls[32][36];
  int b = blockIdx.z;
  int c0 = blockIdx.x * 32, l0 = blockIdx.y * 32;
  int tid = threadIdx.x;
  int r = tid >> 3, q4 = (tid & 7) * 4;
  float4 v = *(const float4*)&in[((size_t)b * CD + c0 + r) * LS + l0 + q4];
  Ls[r][q4] = v.x; Ls[r][q4 + 1] = v.y; Ls[r][q4 + 2] = v.z; Ls[r][q4 + 3] = v.w;
  __syncthreads();
  ushort4 o;
  o.x = f2b(Ls[q4 + 0][r]); o.y = f2b(Ls[q4 + 1][r]);
  o.z = f2b(Ls[q4 + 2][r]); o.w = f2b(Ls[q4 + 3][r]);
  *(ushort4*)&out[((size_t)b * LS + l0 + r) * CD + c0 + q4] = o;
}

// ---------------- eos_p[hh] = sum_c i2h_w[hh][c]*eos_emb[c] -> bf16 ------------
__global__ void k_eos_p(const float* __restrict__ i2h_w, const float* __restrict__ eos_emb,
                        u16* __restrict__ eos_p) {
  int hh = blockIdx.x * blockDim.x + threadIdx.x;
  if (hh >= HD) return;
  const float* row = i2h_w + (size_t)hh * CD;
  float acc = 0.f;
  for (int c = 0; c < CD; ++c) acc += row[c] * eos_emb[c];
  eos_p[hh] = f2b(acc);
}

// ---------------- MFMA bf16 NT GEMM: C[m][n] = sum_k A[m][k]*B[n][k] -----------
// BM=64, BN=128, BK=32; 256 thr = 4 waves (2x2); wave tile 32x64 (2x4 frags).
// Optional second (A2,B2) pair accumulated; f32 out (Cf) or bf16 out (Cb).
__global__ __launch_bounds__(256) void k_mfma_nt(
    const u16* __restrict__ A1, const u16* __restrict__ B1,
    const u16* __restrict__ A2, const u16* __restrict__ B2,
    const float* __restrict__ bias1, const float* __restrict__ bias2,
    float* __restrict__ Cf, u16* __restrict__ Cb,
    int M, int N, int K, size_t sAz, size_t sCz) {
  __shared__ u16 As[64][40];
  __shared__ u16 Bs[128][40];
  int z = blockIdx.z;
  int m0 = blockIdx.y * 64, n0 = blockIdx.x * 128;
  int tid = threadIdx.x;
  int wid = tid >> 6, lane = tid & 63;
  int wr = wid >> 1, wc = wid & 1;
  f32x4 acc[2][4];
#pragma unroll
  for (int i = 0; i < 2; ++i)
#pragma unroll
    for (int j = 0; j < 4; ++j) acc[i][j] = (f32x4){0.f, 0.f, 0.f, 0.f};

  int arow = tid >> 2, ak = (tid & 3) * 8;
  int brow = tid >> 1, bk = (tid & 1) * 16;
  int kof = (lane >> 4) * 8;
  int ar = wr * 32 + (lane & 15);
  int bc = wc * 64 + (lane & 15);

  for (int pass = 0; pass < 2; ++pass) {
    const u16* A = pass ? A2 : A1;
    const u16* B = pass ? B2 : B1;
    if (!A) break;
    const u16* Az = A + sAz * z;
    for (int k0 = 0; k0 < K; k0 += 32) {
      *(uint4*)&As[arow][ak] = *(const uint4*)&Az[(size_t)(m0 + arow) * K + k0 + ak];
      *(uint4*)&Bs[brow][bk] = *(const uint4*)&B[(size_t)(n0 + brow) * K + k0 + bk];
      *(uint4*)&Bs[brow][bk + 8] = *(const uint4*)&B[(size_t)(n0 + brow) * K + k0 + bk + 8];
      __syncthreads();
      short8 afr[2], bfr[4];
      afr[0] = *(const short8*)&As[ar][kof];
      afr[1] = *(const short8*)&As[ar + 16][kof];
#pragma unroll
      for (int fn = 0; fn < 4; ++fn) bfr[fn] = *(const short8*)&Bs[bc + fn * 16][kof];
#pragma unroll
      for (int fm = 0; fm < 2; ++fm)
#pragma unroll
        for (int fn = 0; fn < 4; ++fn)
          acc[fm][fn] = __builtin_amdgcn_mfma_f32_16x16x32_bf16(afr[fm], bfr[fn],
                                                                acc[fm][fn], 0, 0, 0);
      __syncthreads();
    }
  }

  int col0 = n0 + wc * 64 + (lane & 15);
  int row0 = m0 + wr * 32 + (lane >> 4) * 4;
#pragma unroll
  for (int fm = 0; fm < 2; ++fm) {
#pragma unroll
    for (int fn = 0; fn < 4; ++fn) {
      int c = col0 + fn * 16;
      float bv = (bias1 ? bias1[c] : 0.f) + (bias2 ? bias2[c] : 0.f);
#pragma unroll
      for (int j = 0; j < 4; ++j) {
        int r = row0 + fm * 16 + j;
        float v = acc[fm][fn][j] + bv;
        if (Cf) Cf[sCz * z + (size_t)r * N + c] = v;
        else    Cb[sCz * z + (size_t)r * N + c] = f2b(v);
      }
    }
  }
}

// ---------------- fused attention: q -> scores -> softmax -> ctx ---------------
// one block (1024 thr, 16 waves) per b. Hp16 [b][l][hh], Hl16 [b][l][c].
__global__ __launch_bounds__(1024) void k_att(
    const u16* __restrict__ Hp, const u16* __restrict__ eos_p,
    const u16* __restrict__ Hl,
    const float* __restrict__ hprev, const float* __restrict__ h2h_w,
    const float* __restrict__ h2h_b, const float* __restrict__ score_w,
    const float* __restrict__ mask, const float* __restrict__ eos_emb,
    u16* __restrict__ ctx16, float* __restrict__ char_maps, int t, int T) {
  __shared__ float q_s[HD];
  __shared__ float hp_s[HD];
  __shared__ float e_s[260];
  __shared__ float a_s[260];
  __shared__ float cpart[16][520];
  __shared__ float wred[16];
  __shared__ float sget[2];
  int b = blockIdx.x, tid = threadIdx.x;
  int wid = tid >> 6, lane = tid & 63;

  if (tid < HD) hp_s[tid] = hprev[(size_t)b * HD + tid];
  __syncthreads();

  // ---- q[r] = hprev . h2h_w[r] + h2h_b[r]; wave per row
  {
    const float4* hp4 = (const float4*)hp_s;
    float4 h0 = hp4[lane];
    float4 h1 = hp4[lane + 64];
    for (int r = wid; r < HD; r += 16) {
      const float4* wr4 = (const float4*)&h2h_w[(size_t)r * HD];
      float4 a0 = wr4[lane];
      float4 a1 = wr4[lane + 64];
      float acc = a0.x * h0.x + a0.y * h0.y + a0.z * h0.z + a0.w * h0.w
                + a1.x * h1.x + a1.y * h1.y + a1.z * h1.z + a1.w * h1.w;
#pragma unroll
      for (int off = 32; off > 0; off >>= 1) acc += __shfl_down(acc, off);
      if (lane == 0) q_s[r] = acc + h2h_b[r];
    }
  }
  __syncthreads();

  // ---- per-lane q/sw registers (hh = lane*8 + j)
  float q_r[8], sw_r[8];
#pragma unroll
  for (int j = 0; j < 8; ++j) {
    q_r[j]  = q_s[lane * 8 + j];
    sw_r[j] = score_w[lane * 8 + j];
  }

  // ---- scores: wave per key row; one bf16x8 load covers the 512-dim row
  const u16* hpB = Hp + (size_t)b * LS * HD;
  for (int l = wid; l < LP1; l += 16) {
    const u16* row = (l < LS) ? (hpB + (size_t)l * HD) : eos_p;
    uint4 rv = *(const uint4*)(row + lane * 8);
    float x[8]; unpack8(rv, x);
    float e = 0.f;
#pragma unroll
    for (int j = 0; j < 8; ++j) e += tanhf(x[j] + q_r[j]) * sw_r[j];
#pragma unroll
    for (int off = 32; off > 0; off >>= 1) e += __shfl_xor(e, off);
    if (lane == 0) e_s[l] = e;
  }
  __syncthreads();

  // ---- mask + softmax over 257 (threads 0..256 active)
  float e = -INFINITY;
  if (tid < LS) {
    e = e_s[tid];
    float pm = rintf(1.0f - mask[(size_t)b * LS + tid]);
    if (pm >= 0.5f) e = -INFINITY;
  } else if (tid == LS) {
    e = e_s[LS];
  }
  {
    float mv = e;
#pragma unroll
    for (int off = 32; off > 0; off >>= 1) mv = fmaxf(mv, __shfl_xor(mv, off));
    if (lane == 0) wred[wid] = mv;
  }
  __syncthreads();
  if (tid == 0) {
    float m = wred[0];
#pragma unroll
    for (int i = 1; i < 5; ++i) m = fmaxf(m, wred[i]);
    sget[0] = m;
  }
  __syncthreads();
  float m = sget[0];
  float p = (tid <= LS) ? expf(e - m) : 0.f;
  {
    float sv = p;
#pragma unroll
    for (int off = 32; off > 0; off >>= 1) sv += __shfl_xor(sv, off);
    if (lane == 0) wred[wid] = sv;
  }
  __syncthreads();
  if (tid == 0) {
    float s = 0.f;
#pragma unroll
    for (int i = 0; i < 5; ++i) s += wred[i];
    sget[1] = 1.0f / s;
  }
  __syncthreads();
  float inv = sget[1];
  float* cm = char_maps + ((size_t)b * T + t) * LP1;
  if (tid <= LS) {
    float al = p * inv;
    a_s[tid] = al;
    cm[tid] = al;
  }
  __syncthreads();

  // ---- ctx[c] = sum_l a[l]*Hl[l][c] + a_eos*eos_emb[c]
  float cacc[8] = {0.f, 0.f, 0.f, 0.f, 0.f, 0.f, 0.f, 0.f};
  const u16* HB = Hl + (size_t)b * LS * CD;
  for (int l = wid; l < LS; l += 16) {
    float al = a_s[l];
    uint4 rv = *(const uint4*)(HB + (size_t)l * CD + lane * 8);
    float x[8]; unpack8(rv, x);
#pragma unroll
    for (int j = 0; j < 8; ++j) cacc[j] += al * x[j];
  }
  if (wid == 0) {
    float ae = a_s[LS];
#pragma unroll
    for (int j = 0; j < 8; ++j) cacc[j] += ae * eos_emb[lane * 8 + j];
  }
  *(float4*)&cpart[wid][lane * 8]     = make_float4(cacc[0], cacc[1], cacc[2], cacc[3]);
  *(float4*)&cpart[wid][lane * 8 + 4] = make_float4(cacc[4], cacc[5], cacc[6], cacc[7]);
  __syncthreads();
  if (tid < CD) {
    float s = 0.f;
#pragma unroll
    for (int w = 0; w < 16; ++w) s += cpart[w][tid];
    ctx16[(size_t)b * CD + tid] = f2b(s);
  }
}

// ---------------- LSTM pointwise (h out in f32 + bf16) -------------------------
__global__ void k_lstm(const float* __restrict__ gates, const float* __restrict__ cp,
                       float* __restrict__ hn, float* __restrict__ cn,
                       u16* __restrict__ h16) {
  int i = blockIdx.x * 256 + threadIdx.x;
  int b = i >> 9, hh = i & 511;
  const float* g = gates + (size_t)b * G4;
  float ig = g[hh], fg = g[512 + hh], gg = g[1024 + hh], og = g[1536 + hh];
  float si = 1.f / (1.f + expf(-ig));
  float sf = 1.f / (1.f + expf(-fg));
  float so = 1.f / (1.f + expf(-og));
  float c  = sf * cp[i] + si * tanhf(gg);
  float h  = so * tanhf(c);
  cn[i] = c;
  hn[i] = h;
  h16[i] = f2b(h);
}

// ---------------- logits: block per b, wave per class --------------------------
__global__ __launch_bounds__(256) void k_logits(const float* __restrict__ hn,
                                                const float* __restrict__ gen_w,
                                                const float* __restrict__ gen_b,
                                                float* __restrict__ out,
                                                int t, int T) {
  int b = blockIdx.x, tid = threadIdx.x;
  int wid = tid >> 6, lane = tid & 63;
  const float4* h4 = (const float4*)(hn + (size_t)b * HD);
  float4 h0 = h4[lane];
  float4 h1 = h4[lane + 64];
  for (int n = wid; n < NCLS; n += 4) {
    const float4* w4 = (const float4*)(gen_w + (size_t)n * HD);
    float4 a0 = w4[lane];
    float4 a1 = w4[lane + 64];
    float acc = a0.x * h0.x + a0.y * h0.y + a0.z * h0.z + a0.w * h0.w
              + a1.x * h1.x + a1.y * h1.y + a1.z * h1.z + a1.w * h1.w;
#pragma unroll
    for (int off = 32; off > 0; off >>= 1) acc += __shfl_down(acc, off);
    if (lane == 0) out[((size_t)b * T + t) * NCLS + n] = acc + gen_b[n];
  }
}

extern "C" void kernel_launch(void* const* d_in, const int* in_sizes, int n_in,
                              void* d_out, int out_size, void* d_ws, size_t ws_size,
                              hipStream_t stream) {
  const float* batch_H = (const float*)d_in[0];
  const float* mask    = (const float*)d_in[1];
  const float* i2h_w   = (const float*)d_in[2];
  const float* h2h_w   = (const float*)d_in[3];
  const float* h2h_b   = (const float*)d_in[4];
  const float* score_w = (const float*)d_in[5];
  const float* w_ih    = (const float*)d_in[6];
  const float* w_hh    = (const float*)d_in[7];
  const float* b_ih    = (const float*)d_in[8];
  const float* b_hh    = (const float*)d_in[9];
  const float* gen_w   = (const float*)d_in[10];
  const float* gen_b   = (const float*)d_in[11];
  const float* eos_emb = (const float*)d_in[12];

  int T = out_size / (BB * (NCLS + LP1));   // 26

  char* p = (char*)d_ws;
  auto alloc = [&](size_t bytes) -> char* {
    char* r = p; p += (bytes + 255) & ~(size_t)255; return r;
  };
  u16*   Hl16  = (u16*)alloc((size_t)BB * LS * CD * 2);
  u16*   Hp16  = (u16*)alloc((size_t)BB * LS * HD * 2);
  u16*   i2h16 = (u16*)alloc((size_t)HD * CD * 2);
  u16*   wih16 = (u16*)alloc((size_t)G4 * CD * 2);
  u16*   whh16 = (u16*)alloc((size_t)G4 * HD * 2);
  u16*   eos16 = (u16*)alloc((size_t)HD * 2);
  u16*   ctx16 = (u16*)alloc((size_t)BB * CD * 2);
  u16*   h16a  = (u16*)alloc((size_t)BB * HD * 2);
  u16*   h16b  = (u16*)alloc((size_t)BB * HD * 2);
  float* h0    = (float*)alloc((size_t)BB * HD * 4);
  float* h1    = (float*)alloc((size_t)BB * HD * 4);
  float* c0    = (float*)alloc((size_t)BB * HD * 4);
  float* c1    = (float*)alloc((size_t)BB * HD * 4);
  float* gates = (float*)alloc((size_t)BB * G4 * 4);

  float* logits    = (float*)d_out;
  float* char_maps = logits + (size_t)BB * T * NCLS;

  hipMemsetAsync(h0, 0, (size_t)BB * HD * 4, stream);
  hipMemsetAsync(c0, 0, (size_t)BB * HD * 4, stream);
  hipMemsetAsync(h16a, 0, (size_t)BB * HD * 2, stream);

  // prologue: conversions + Hp GEMM
  k_cvt<<<(HD * CD / 4 + 255) / 256, 256, 0, stream>>>(i2h_w, i2h16, HD * CD / 4);
  k_cvt<<<(G4 * CD / 4 + 255) / 256, 256, 0, stream>>>(w_ih, wih16, G4 * CD / 4);
  k_cvt<<<(G4 * HD / 4 + 255) / 256, 256, 0, stream>>>(w_hh, whh16, G4 * HD / 4);
  k_eos_p<<<2, 256, 0, stream>>>(i2h_w, eos_emb, eos16);
  k_tr16<<<dim3(CD / 32, LS / 32, BB), 256, 0, stream>>>(batch_H, Hl16);
  // Hp16[b][l][hh] = Hl16[b] (256x512) . i2h16^T (512x512)
  k_mfma_nt<<<dim3(HD / 128, LS / 64, BB), 256, 0, stream>>>(
      Hl16, i2h16, nullptr, nullptr, nullptr, nullptr,
      nullptr, Hp16, LS, HD, CD, (size_t)LS * CD, (size_t)LS * HD);

  float *hp = h0, *cp = c0, *hn = h1, *cnb = c1;
  u16 *hcur = h16a, *hnext = h16b;
  for (int t = 0; t < T; ++t) {
    k_att<<<BB, 1024, 0, stream>>>(Hp16, eos16, Hl16, hp, h2h_w, h2h_b, score_w,
                                   mask, eos_emb, ctx16, char_maps, t, T);
    // gates = ctx16 . wih16^T + b_ih + hcur . whh16^T + b_hh
    k_mfma_nt<<<dim3(G4 / 128, BB / 64, 1), 256, 0, stream>>>(
        ctx16, wih16, hcur, whh16, b_ih, b_hh,
        gates, nullptr, BB, G4, CD, (size_t)0, (size_t)0);
    k_lstm<<<(BB * HD) / 256, 256, 0, stream>>>(gates, cp, hn, cnb, hnext);
    k_logits<<<BB, 256, 0, stream>>>(hn, gen_w, gen_b, logits, t, T);
    float* tmp;
    tmp = hp; hp = hn;  hn  = tmp;
    tmp = cp; cp = cnb; cnb = tmp;
    u16* tb = hcur; hcur = hnext; hnext = tb;
  }
}

// Round 4
// 3321.485 us; speedup vs baseline: 5.6436x; 1.0850x over previous
//
#include <hip/hip_runtime.h>
#include <math.h>

#define BB   512   // batch
#define CD   512   // channels c
#define HD   512   // hidden
#define LS   256   // spatial keys h*w
#define LP1  257   // keys + EOS
#define NCLS 38    // num classes
#define KC   1024  // concat K = CD + HD

typedef unsigned short u16;
typedef __attribute__((ext_vector_type(8))) short short8;
typedef __attribute__((ext_vector_type(4))) float f32x4;

__device__ __forceinline__ u16 f2b(float f) {
  union { float f; unsigned u; } v; v.f = f;
  unsigned r = v.u + 0x7fffu + ((v.u >> 16) & 1u);
  return (u16)(r >> 16);
}
__device__ __forceinline__ float b2f(unsigned bits) {
  union { unsigned u; float f; } v; v.u = bits << 16;
  return v.f;
}
__device__ __forceinline__ void unpack8(uint4 r, float* o) {
  o[0] = b2f(r.x & 0xffffu); o[1] = b2f(r.x >> 16);
  o[2] = b2f(r.y & 0xffffu); o[3] = b2f(r.y >> 16);
  o[4] = b2f(r.z & 0xffffu); o[5] = b2f(r.z >> 16);
  o[6] = b2f(r.w & 0xffffu); o[7] = b2f(r.w >> 16);
}
// swizzled LDS offset for BK=32 row-major u16 tile (8-elem chunks, XOR row&3)
__device__ __forceinline__ int swz(int row, int kchunk) {
  return row * 32 + (((kchunk ^ row) & 3) << 3);
}

// ---------------- f32 -> bf16 elementwise ------------------------------------
__global__ void k_cvt(const float* __restrict__ in, u16* __restrict__ out, int n4) {
  int i = blockIdx.x * 256 + threadIdx.x;
  if (i >= n4) return;
  float4 v = *(const float4*)&in[i * 4];
  ushort4 o;
  o.x = f2b(v.x); o.y = f2b(v.y); o.z = f2b(v.z); o.w = f2b(v.w);
  *(ushort4*)&out[i * 4] = o;
}

// ---------------- wcat[n][k]: n=4*hh+g -> w_ih/w_hh row (n&3)*512+(n>>2) -------
__global__ void k_wcat(const float* __restrict__ w_ih, const float* __restrict__ w_hh,
                       u16* __restrict__ wcat) {
  int idx = blockIdx.x * 256 + threadIdx.x;   // over 2048*1024/4
  int n = idx >> 8, kq = idx & 255;
  int k = kq * 4;
  int orig = (n & 3) * HD + (n >> 2);
  const float* src = (k < CD) ? (w_ih + (size_t)orig * CD + k)
                              : (w_hh + (size_t)orig * HD + (k - CD));
  float4 v = *(const float4*)src;
  ushort4 o;
  o.x = f2b(v.x); o.y = f2b(v.y); o.z = f2b(v.z); o.w = f2b(v.w);
  *(ushort4*)&wcat[(size_t)n * KC + k] = o;
}
__global__ void k_bcat(const float* __restrict__ b_ih, const float* __restrict__ b_hh,
                       float* __restrict__ bcat) {
  int n = blockIdx.x * 256 + threadIdx.x;
  if (n >= 4 * HD) return;
  int orig = (n & 3) * HD + (n >> 2);
  bcat[n] = b_ih[orig] + b_hh[orig];
}

// ---------------- batch_H [b][c][l] f32 -> Hl16 [b][l][c] bf16 (once) ----------
__global__ __launch_bounds__(256) void k_tr16(const float* __restrict__ in,
                                              u16* __restrict__ out) {
  __shared__ float Ls[32][36];
  int b = blockIdx.z;
  int c0 = blockIdx.x * 32, l0 = blockIdx.y * 32;
  int tid = threadIdx.x;
  int r = tid >> 3, q4 = (tid & 7) * 4;
  float4 v = *(const float4*)&in[((size_t)b * CD + c0 + r) * LS + l0 + q4];
  Ls[r][q4] = v.x; Ls[r][q4 + 1] = v.y; Ls[r][q4 + 2] = v.z; Ls[r][q4 + 3] = v.w;
  __syncthreads();
  ushort4 o;
  o.x = f2b(Ls[q4 + 0][r]); o.y = f2b(Ls[q4 + 1][r]);
  o.z = f2b(Ls[q4 + 2][r]); o.w = f2b(Ls[q4 + 3][r]);
  *(ushort4*)&out[((size_t)b * LS + l0 + r) * CD + c0 + q4] = o;
}

// ---------------- eos_p[hh] -> bf16 -------------------------------------------
__global__ void k_eos_p(const float* __restrict__ i2h_w, const float* __restrict__ eos_emb,
                        u16* __restrict__ eos_p) {
  int hh = blockIdx.x * blockDim.x + threadIdx.x;
  if (hh >= HD) return;
  const float* row = i2h_w + (size_t)hh * CD;
  float acc = 0.f;
  for (int c = 0; c < CD; ++c) acc += row[c] * eos_emb[c];
  eos_p[hh] = f2b(acc);
}

// ---------------- prologue MFMA: Hp16[b][l][hh] = Hl16[b] . i2h16^T ------------
// BM=64 (l), BN=128 (hh), BK=32; 1D grid 8192; bid = n*2048 + b*4 + m (XCD-local A reuse)
__global__ __launch_bounds__(256) void k_hp_mfma(const u16* __restrict__ A,
                                                 const u16* __restrict__ B,
                                                 u16* __restrict__ Hp) {
  __shared__ u16 As[64 * 32];
  __shared__ u16 Bs[128 * 32];
  int bid = blockIdx.x;
  int n0 = (bid >> 11) * 128;
  int rem = bid & 2047;
  int z = rem >> 2;
  int m0 = (rem & 3) * 64;
  int tid = threadIdx.x, wid = tid >> 6, lane = tid & 63;
  int wr = wid >> 1, wc = wid & 1;
  f32x4 acc[2][4];
#pragma unroll
  for (int i = 0; i < 2; ++i)
#pragma unroll
    for (int j = 0; j < 4; ++j) acc[i][j] = (f32x4){0.f, 0.f, 0.f, 0.f};

  const u16* Az = A + (size_t)z * LS * CD;
  int arow = tid >> 2, ack = tid & 3;
  int brow = tid >> 1;
  int kc = lane >> 4;
  int ar = wr * 32 + (lane & 15);
  int bc = wc * 64 + (lane & 15);

  for (int k0 = 0; k0 < CD; k0 += 32) {
    *(uint4*)&As[swz(arow, ack)] = *(const uint4*)&Az[(size_t)(m0 + arow) * CD + k0 + ack * 8];
#pragma unroll
    for (int j = 0; j < 2; ++j) {
      int ck = (tid & 1) * 2 + j;
      *(uint4*)&Bs[swz(brow, ck)] = *(const uint4*)&B[(size_t)(n0 + brow) * CD + k0 + ck * 8];
    }
    __syncthreads();
    short8 afr[2], bfr[4];
#pragma unroll
    for (int fm = 0; fm < 2; ++fm) afr[fm] = *(const short8*)&As[swz(ar + fm * 16, kc)];
#pragma unroll
    for (int fn = 0; fn < 4; ++fn) bfr[fn] = *(const short8*)&Bs[swz(bc + fn * 16, kc)];
#pragma unroll
    for (int fm = 0; fm < 2; ++fm)
#pragma unroll
      for (int fn = 0; fn < 4; ++fn)
        acc[fm][fn] = __builtin_amdgcn_mfma_f32_16x16x32_bf16(afr[fm], bfr[fn],
                                                              acc[fm][fn], 0, 0, 0);
    __syncthreads();
  }
  int col0 = n0 + wc * 64 + (lane & 15);
  int row0 = m0 + wr * 32 + (lane >> 4) * 4;
  u16* Hz = Hp + (size_t)z * LS * HD;
#pragma unroll
  for (int fm = 0; fm < 2; ++fm)
#pragma unroll
    for (int fn = 0; fn < 4; ++fn)
#pragma unroll
      for (int j = 0; j < 4; ++j)
        Hz[(size_t)(row0 + fm * 16 + j) * HD + col0 + fn * 16] = f2b(acc[fm][fn][j]);
}

// ---------------- gates GEMM + fused LSTM -------------------------------------
// C[b][n] = xcat[b] . wcat[n] + bcat[n]; n = 4*hh+g permuted layout.
// BM=32 (b), BN=64 (n -> 16 hh), BK=32, K=1024; 4 waves (2x2), wave tile 16x32.
// grid 512; bid = n*16 + m (same-m blocks share XCD -> A-tile L2 reuse).
__global__ __launch_bounds__(256) void k_gates(const u16* __restrict__ xcat,
                                               const u16* __restrict__ wcat,
                                               const float* __restrict__ bcat,
                                               const float* __restrict__ cprev,
                                               float* __restrict__ cnext,
                                               float* __restrict__ hnext,
                                               u16* __restrict__ xcat_next) {
  __shared__ u16 As[32 * 32];
  __shared__ u16 Bs[64 * 32];
  __shared__ float Ct[32][68];
  int bid = blockIdx.x;
  int n0 = (bid >> 4) * 64;
  int m0 = (bid & 15) * 32;
  int tid = threadIdx.x, wid = tid >> 6, lane = tid & 63;
  int wr = wid >> 1, wc = wid & 1;
  f32x4 acc[2];
  acc[0] = (f32x4){0.f, 0.f, 0.f, 0.f};
  acc[1] = (f32x4){0.f, 0.f, 0.f, 0.f};

  int arow = tid >> 2, ack = tid & 3;   // arow<32 guarded below
  int kc = lane >> 4;
  int ar = wr * 16 + (lane & 15);
  int bc = wc * 32 + (lane & 15);

  for (int k0 = 0; k0 < KC; k0 += 32) {
    if (tid < 128)
      *(uint4*)&As[swz(arow, ack)] = *(const uint4*)&xcat[(size_t)(m0 + arow) * KC + k0 + ack * 8];
    *(uint4*)&Bs[swz(arow & 63, ack)] =
        *(const uint4*)&wcat[(size_t)(n0 + (arow & 63)) * KC + k0 + ack * 8];
    __syncthreads();
    short8 afr = *(const short8*)&As[swz(ar, kc)];
    short8 bfr0 = *(const short8*)&Bs[swz(bc, kc)];
    short8 bfr1 = *(const short8*)&Bs[swz(bc + 16, kc)];
    acc[0] = __builtin_amdgcn_mfma_f32_16x16x32_bf16(afr, bfr0, acc[0], 0, 0, 0);
    acc[1] = __builtin_amdgcn_mfma_f32_16x16x32_bf16(afr, bfr1, acc[1], 0, 0, 0);
    __syncthreads();
  }

  // stage C tile (with bias) to LDS
  int col0 = wc * 32 + (lane & 15);
  int row0 = wr * 16 + (lane >> 4) * 4;
#pragma unroll
  for (int fn = 0; fn < 2; ++fn) {
    float bv = bcat[n0 + col0 + fn * 16];
#pragma unroll
    for (int j = 0; j < 4; ++j)
      Ct[row0 + j][col0 + fn * 16] = acc[fn][j] + bv;
  }
  __syncthreads();

  // fused LSTM: 32 b x 16 hh; gates i,f,g,o contiguous per hh (float4)
  int hh0 = n0 >> 2;
#pragma unroll
  for (int j = 0; j < 2; ++j) {
    int idx = j * 256 + tid;
    int b_loc = idx >> 4, hh_loc = idx & 15;
    float4 g4 = *(const float4*)&Ct[b_loc][hh_loc * 4];
    int b_g = m0 + b_loc, hh_g = hh0 + hh_loc;
    float cp = cprev[(size_t)b_g * HD + hh_g];
    float si = 1.f / (1.f + expf(-g4.x));
    float sf = 1.f / (1.f + expf(-g4.y));
    float so = 1.f / (1.f + expf(-g4.w));
    float c = sf * cp + si * tanhf(g4.z);
    float h = so * tanhf(c);
    cnext[(size_t)b_g * HD + hh_g] = c;
    hnext[(size_t)b_g * HD + hh_g] = h;
    xcat_next[(size_t)b_g * KC + CD + hh_g] = f2b(h);
  }
}

// ---------------- fused attention: q -> scores -> softmax -> ctx ---------------
__global__ __launch_bounds__(1024) void k_att(
    const u16* __restrict__ Hp, const u16* __restrict__ eos_p,
    const u16* __restrict__ Hl,
    const float* __restrict__ hprev, const u16* __restrict__ h2h16,
    const float* __restrict__ h2h_b, const float* __restrict__ score_w,
    const float* __restrict__ mask, const float* __restrict__ eos_emb,
    u16* __restrict__ xcat, float* __restrict__ char_maps, int t, int T) {
  __shared__ float q_s[HD];
  __shared__ float hp_s[HD];
  __shared__ float e_s[260];
  __shared__ float a_s[260];
  __shared__ float cpart[16][520];
  __shared__ float wred[16];
  __shared__ float sget[2];
  int b = blockIdx.x, tid = threadIdx.x;
  int wid = tid >> 6, lane = tid & 63;

  if (tid < HD) hp_s[tid] = hprev[(size_t)b * HD + tid];
  __syncthreads();

  // ---- q[r] = hprev . h2h16[r] + h2h_b[r]; wave per row (one uint4/lane = full row)
  {
    float hp8[8];
#pragma unroll
    for (int j = 0; j < 8; ++j) hp8[j] = hp_s[lane * 8 + j];
    for (int r = wid; r < HD; r += 16) {
      uint4 wv = *(const uint4*)&h2h16[(size_t)r * HD + lane * 8];
      float x[8]; unpack8(wv, x);
      float acc = x[0] * hp8[0] + x[1] * hp8[1] + x[2] * hp8[2] + x[3] * hp8[3]
                + x[4] * hp8[4] + x[5] * hp8[5] + x[6] * hp8[6] + x[7] * hp8[7];
#pragma unroll
      for (int off = 32; off > 0; off >>= 1) acc += __shfl_down(acc, off);
      if (lane == 0) q_s[r] = acc + h2h_b[r];
    }
  }
  __syncthreads();

  float q_r[8], sw_r[8];
#pragma unroll
  for (int j = 0; j < 8; ++j) {
    q_r[j]  = q_s[lane * 8 + j];
    sw_r[j] = score_w[lane * 8 + j];
  }

  // ---- scores: wave per key row
  const u16* hpB = Hp + (size_t)b * LS * HD;
  for (int l = wid; l < LP1; l += 16) {
    const u16* row = (l < LS) ? (hpB + (size_t)l * HD) : eos_p;
    uint4 rv = *(const uint4*)(row + lane * 8);
    float x[8]; unpack8(rv, x);
    float e = 0.f;
#pragma unroll
    for (int j = 0; j < 8; ++j) e += tanhf(x[j] + q_r[j]) * sw_r[j];
#pragma unroll
    for (int off = 32; off > 0; off >>= 1) e += __shfl_xor(e, off);
    if (lane == 0) e_s[l] = e;
  }
  __syncthreads();

  // ---- mask + softmax over 257
  float e = -INFINITY;
  if (tid < LS) {
    e = e_s[tid];
    float pm = rintf(1.0f - mask[(size_t)b * LS + tid]);
    if (pm >= 0.5f) e = -INFINITY;
  } else if (tid == LS) {
    e = e_s[LS];
  }
  {
    float mv = e;
#pragma unroll
    for (int off = 32; off > 0; off >>= 1) mv = fmaxf(mv, __shfl_xor(mv, off));
    if (lane == 0) wred[wid] = mv;
  }
  __syncthreads();
  if (tid == 0) {
    float m = wred[0];
#pragma unroll
    for (int i = 1; i < 5; ++i) m = fmaxf(m, wred[i]);
    sget[0] = m;
  }
  __syncthreads();
  float m = sget[0];
  float p = (tid <= LS) ? expf(e - m) : 0.f;
  {
    float sv = p;
#pragma unroll
    for (int off = 32; off > 0; off >>= 1) sv += __shfl_xor(sv, off);
    if (lane == 0) wred[wid] = sv;
  }
  __syncthreads();
  if (tid == 0) {
    float s = 0.f;
#pragma unroll
    for (int i = 0; i < 5; ++i) s += wred[i];
    sget[1] = 1.0f / s;
  }
  __syncthreads();
  float inv = sget[1];
  float* cm = char_maps + ((size_t)b * T + t) * LP1;
  if (tid <= LS) {
    float al = p * inv;
    a_s[tid] = al;
    cm[tid] = al;
  }
  __syncthreads();

  // ---- ctx[c] = sum_l a[l]*Hl[l][c] + a_eos*eos_emb[c] -> xcat[b][0:512] bf16
  float cacc[8] = {0.f, 0.f, 0.f, 0.f, 0.f, 0.f, 0.f, 0.f};
  const u16* HB = Hl + (size_t)b * LS * CD;
  for (int l = wid; l < LS; l += 16) {
    float al = a_s[l];
    uint4 rv = *(const uint4*)(HB + (size_t)l * CD + lane * 8);
    float x[8]; unpack8(rv, x);
#pragma unroll
    for (int j = 0; j < 8; ++j) cacc[j] += al * x[j];
  }
  if (wid == 0) {
    float ae = a_s[LS];
#pragma unroll
    for (int j = 0; j < 8; ++j) cacc[j] += ae * eos_emb[lane * 8 + j];
  }
  *(float4*)&cpart[wid][lane * 8]     = make_float4(cacc[0], cacc[1], cacc[2], cacc[3]);
  *(float4*)&cpart[wid][lane * 8 + 4] = make_float4(cacc[4], cacc[5], cacc[6], cacc[7]);
  __syncthreads();
  if (tid < CD) {
    float s = 0.f;
#pragma unroll
    for (int w = 0; w < 16; ++w) s += cpart[w][tid];
    xcat[(size_t)b * KC + tid] = f2b(s);
  }
}

// ---------------- logits: block per b, wave per class --------------------------
__global__ __launch_bounds__(256) void k_logits(const float* __restrict__ hn,
                                                const float* __restrict__ gen_w,
                                                const float* __restrict__ gen_b,
                                                float* __restrict__ out,
                                                int t, int T) {
  int b = blockIdx.x, tid = threadIdx.x;
  int wid = tid >> 6, lane = tid & 63;
  const float4* h4 = (const float4*)(hn + (size_t)b * HD);
  float4 h0 = h4[lane];
  float4 h1 = h4[lane + 64];
  for (int n = wid; n < NCLS; n += 4) {
    const float4* w4 = (const float4*)(gen_w + (size_t)n * HD);
    float4 a0 = w4[lane];
    float4 a1 = w4[lane + 64];
    float acc = a0.x * h0.x + a0.y * h0.y + a0.z * h0.z + a0.w * h0.w
              + a1.x * h1.x + a1.y * h1.y + a1.z * h1.z + a1.w * h1.w;
#pragma unroll
    for (int off = 32; off > 0; off >>= 1) acc += __shfl_down(acc, off);
    if (lane == 0) out[((size_t)b * T + t) * NCLS + n] = acc + gen_b[n];
  }
}

extern "C" void kernel_launch(void* const* d_in, const int* in_sizes, int n_in,
                              void* d_out, int out_size, void* d_ws, size_t ws_size,
                              hipStream_t stream) {
  const float* batch_H = (const float*)d_in[0];
  const float* mask    = (const float*)d_in[1];
  const float* i2h_w   = (const float*)d_in[2];
  const float* h2h_w   = (const float*)d_in[3];
  const float* h2h_b   = (const float*)d_in[4];
  const float* score_w = (const float*)d_in[5];
  const float* w_ih    = (const float*)d_in[6];
  const float* w_hh    = (const float*)d_in[7];
  const float* b_ih    = (const float*)d_in[8];
  const float* b_hh    = (const float*)d_in[9];
  const float* gen_w   = (const float*)d_in[10];
  const float* gen_b   = (const float*)d_in[11];
  const float* eos_emb = (const float*)d_in[12];

  int T = out_size / (BB * (NCLS + LP1));   // 26

  char* p = (char*)d_ws;
  auto alloc = [&](size_t bytes) -> char* {
    char* r = p; p += (bytes + 255) & ~(size_t)255; return r;
  };
  u16*   Hl16  = (u16*)alloc((size_t)BB * LS * CD * 2);
  u16*   Hp16  = (u16*)alloc((size_t)BB * LS * HD * 2);
  u16*   i2h16 = (u16*)alloc((size_t)HD * CD * 2);
  u16*   h2h16 = (u16*)alloc((size_t)HD * HD * 2);
  u16*   wcat  = (u16*)alloc((size_t)4 * HD * KC * 2);
  float* bcat  = (float*)alloc((size_t)4 * HD * 4);
  u16*   eos16 = (u16*)alloc((size_t)HD * 2);
  u16*   xcatA = (u16*)alloc((size_t)BB * KC * 2);
  u16*   xcatB = (u16*)alloc((size_t)BB * KC * 2);
  float* h0    = (float*)alloc((size_t)BB * HD * 4);
  float* h1    = (float*)alloc((size_t)BB * HD * 4);
  float* c0    = (float*)alloc((size_t)BB * HD * 4);
  float* c1    = (float*)alloc((size_t)BB * HD * 4);

  float* logits    = (float*)d_out;
  float* char_maps = logits + (size_t)BB * T * NCLS;

  hipMemsetAsync(h0, 0, (size_t)BB * HD * 4, stream);
  hipMemsetAsync(c0, 0, (size_t)BB * HD * 4, stream);
  hipMemsetAsync(xcatA, 0, (size_t)BB * KC * 2, stream);

  // prologue
  k_cvt<<<(HD * CD / 4 + 255) / 256, 256, 0, stream>>>(i2h_w, i2h16, HD * CD / 4);
  k_cvt<<<(HD * HD / 4 + 255) / 256, 256, 0, stream>>>(h2h_w, h2h16, HD * HD / 4);
  k_wcat<<<(4 * HD * KC / 4) / 256, 256, 0, stream>>>(w_ih, w_hh, wcat);
  k_bcat<<<(4 * HD + 255) / 256, 256, 0, stream>>>(b_ih, b_hh, bcat);
  k_eos_p<<<2, 256, 0, stream>>>(i2h_w, eos_emb, eos16);
  k_tr16<<<dim3(CD / 32, LS / 32, BB), 256, 0, stream>>>(batch_H, Hl16);
  k_hp_mfma<<<4 * 4 * BB, 256, 0, stream>>>(Hl16, i2h16, Hp16);

  float *hp = h0, *cp = c0, *hn = h1, *cnb = c1;
  u16 *xcur = xcatA, *xnext = xcatB;
  for (int t = 0; t < T; ++t) {
    k_att<<<BB, 1024, 0, stream>>>(Hp16, eos16, Hl16, hp, h2h16, h2h_b, score_w,
                                   mask, eos_emb, xcur, char_maps, t, T);
    k_gates<<<512, 256, 0, stream>>>(xcur, wcat, bcat, cp, cnb, hn, xnext);
    k_logits<<<BB, 256, 0, stream>>>(hn, gen_w, gen_b, logits, t, T);
    float* tmp;
    tmp = hp; hp = hn;  hn  = tmp;
    tmp = cp; cp = cnb; cnb = tmp;
    u16* tx = xcur; xcur = xnext; xnext = tx;
  }
}

// Round 5
// 3128.489 us; speedup vs baseline: 5.9917x; 1.0617x over previous
//
#include <hip/hip_runtime.h>
#include <math.h>

#define BB   512   // batch
#define CD   512   // channels c
#define HD   512   // hidden
#define LS   256   // spatial keys h*w
#define LP1  257   // keys + EOS
#define NCLS 38    // num classes
#define KC   1024  // concat K = CD + HD

typedef unsigned short u16;
typedef __attribute__((ext_vector_type(8))) short short8;
typedef __attribute__((ext_vector_type(4))) float f32x4;

__device__ __forceinline__ u16 f2b(float f) {
  union { float f; unsigned u; } v; v.f = f;
  unsigned r = v.u + 0x7fffu + ((v.u >> 16) & 1u);
  return (u16)(r >> 16);
}
__device__ __forceinline__ float b2f(unsigned bits) {
  union { unsigned u; float f; } v; v.u = bits << 16;
  return v.f;
}
__device__ __forceinline__ void unpack8(uint4 r, float* o) {
  o[0] = b2f(r.x & 0xffffu); o[1] = b2f(r.x >> 16);
  o[2] = b2f(r.y & 0xffffu); o[3] = b2f(r.y >> 16);
  o[4] = b2f(r.z & 0xffffu); o[5] = b2f(r.z >> 16);
  o[6] = b2f(r.w & 0xffffu); o[7] = b2f(r.w >> 16);
}
// LDS swizzle for BK=32 u16 tiles, 8-elem (16B) chunks.
// slot(row,kc) = 4*(row&1) + ((kc ^ (row>>1))&3): 8 distinct slots per 8 rows
// -> ds_read_b128 over 16 same-chunk rows is 2-way (free); writes 2-way too.
__device__ __forceinline__ int swz(int row, int kchunk) {
  return row * 32 + (((kchunk ^ (row >> 1)) & 3) << 3);
}

// ---------------- f32 -> bf16 elementwise ------------------------------------
__global__ void k_cvt(const float* __restrict__ in, u16* __restrict__ out, int n4) {
  int i = blockIdx.x * 256 + threadIdx.x;
  if (i >= n4) return;
  float4 v = *(const float4*)&in[i * 4];
  ushort4 o;
  o.x = f2b(v.x); o.y = f2b(v.y); o.z = f2b(v.z); o.w = f2b(v.w);
  *(ushort4*)&out[i * 4] = o;
}

// ---------------- wcat[n][k]: n=4*hh+g -> w_ih/w_hh row (n&3)*512+(n>>2) -------
__global__ void k_wcat(const float* __restrict__ w_ih, const float* __restrict__ w_hh,
                       u16* __restrict__ wcat) {
  int idx = blockIdx.x * 256 + threadIdx.x;   // over 2048*1024/4
  int n = idx >> 8, kq = idx & 255;
  int k = kq * 4;
  int orig = (n & 3) * HD + (n >> 2);
  const float* src = (k < CD) ? (w_ih + (size_t)orig * CD + k)
                              : (w_hh + (size_t)orig * HD + (k - CD));
  float4 v = *(const float4*)src;
  ushort4 o;
  o.x = f2b(v.x); o.y = f2b(v.y); o.z = f2b(v.z); o.w = f2b(v.w);
  *(ushort4*)&wcat[(size_t)n * KC + k] = o;
}
__global__ void k_bcat(const float* __restrict__ b_ih, const float* __restrict__ b_hh,
                       float* __restrict__ bcat) {
  int n = blockIdx.x * 256 + threadIdx.x;
  if (n >= 4 * HD) return;
  int orig = (n & 3) * HD + (n >> 2);
  bcat[n] = b_ih[orig] + b_hh[orig];
}

// ---------------- batch_H [b][c][l] f32 -> Hl16 [b][l][c] bf16 (once) ----------
__global__ __launch_bounds__(256) void k_tr16(const float* __restrict__ in,
                                              u16* __restrict__ out) {
  __shared__ float Ls[32][36];
  int b = blockIdx.z;
  int c0 = blockIdx.x * 32, l0 = blockIdx.y * 32;
  int tid = threadIdx.x;
  int r = tid >> 3, q4 = (tid & 7) * 4;
  float4 v = *(const float4*)&in[((size_t)b * CD + c0 + r) * LS + l0 + q4];
  Ls[r][q4] = v.x; Ls[r][q4 + 1] = v.y; Ls[r][q4 + 2] = v.z; Ls[r][q4 + 3] = v.w;
  __syncthreads();
  ushort4 o;
  o.x = f2b(Ls[q4 + 0][r]); o.y = f2b(Ls[q4 + 1][r]);
  o.z = f2b(Ls[q4 + 2][r]); o.w = f2b(Ls[q4 + 3][r]);
  *(ushort4*)&out[((size_t)b * LS + l0 + r) * CD + c0 + q4] = o;
}

// ---------------- eos_p[hh] -> bf16 -------------------------------------------
__global__ void k_eos_p(const float* __restrict__ i2h_w, const float* __restrict__ eos_emb,
                        u16* __restrict__ eos_p) {
  int hh = blockIdx.x * blockDim.x + threadIdx.x;
  if (hh >= HD) return;
  const float* row = i2h_w + (size_t)hh * CD;
  float acc = 0.f;
  for (int c = 0; c < CD; ++c) acc += row[c] * eos_emb[c];
  eos_p[hh] = f2b(acc);
}

// ---------------- prologue MFMA: Hp16[b][l][:] = Hl16[b][l][:] . i2h16^T -------
// BM=64 (l), BN=512 (ALL hh -> A fetched exactly once), BK=32; 512 thr = 8 waves.
// grid 2048: bid -> z=bid>>2, m0=(bid&3)*64.
__global__ __launch_bounds__(512) void k_hp_mfma(const u16* __restrict__ A,
                                                 const u16* __restrict__ B,
                                                 u16* __restrict__ Hp) {
  __shared__ u16 As[64 * 32];
  __shared__ u16 Bs[512 * 32];
  int bid = blockIdx.x;
  int z = bid >> 2, m0 = (bid & 3) * 64;
  int tid = threadIdx.x, wid = tid >> 6, lane = tid & 63;
  f32x4 acc[4][4];
#pragma unroll
  for (int i = 0; i < 4; ++i)
#pragma unroll
    for (int j = 0; j < 4; ++j) acc[i][j] = (f32x4){0.f, 0.f, 0.f, 0.f};

  const u16* Az = A + (size_t)z * LS * CD + (size_t)m0 * CD;
  int arow = tid >> 2, ack = tid & 3;   // tid<256 stages A
  int kc = lane >> 4;
  int ar = lane & 15;
  int bc = wid * 64 + (lane & 15);

  for (int k0 = 0; k0 < CD; k0 += 32) {
    if (tid < 256)
      *(uint4*)&As[swz(arow, ack)] = *(const uint4*)&Az[(size_t)arow * CD + k0 + ack * 8];
#pragma unroll
    for (int c = 0; c < 4; ++c)
      *(uint4*)&Bs[swz(tid, c)] = *(const uint4*)&B[(size_t)tid * CD + k0 + c * 8];
    __syncthreads();
    short8 afr[4], bfr[4];
#pragma unroll
    for (int fm = 0; fm < 4; ++fm) afr[fm] = *(const short8*)&As[swz(ar + fm * 16, kc)];
#pragma unroll
    for (int fn = 0; fn < 4; ++fn) bfr[fn] = *(const short8*)&Bs[swz(bc + fn * 16, kc)];
#pragma unroll
    for (int fm = 0; fm < 4; ++fm)
#pragma unroll
      for (int fn = 0; fn < 4; ++fn)
        acc[fm][fn] = __builtin_amdgcn_mfma_f32_16x16x32_bf16(afr[fm], bfr[fn],
                                                              acc[fm][fn], 0, 0, 0);
    __syncthreads();
  }
  int row0 = m0 + (lane >> 4) * 4;
  int col0 = wid * 64 + (lane & 15);
  u16* Hz = Hp + (size_t)z * LS * HD;
#pragma unroll
  for (int fm = 0; fm < 4; ++fm)
#pragma unroll
    for (int fn = 0; fn < 4; ++fn)
#pragma unroll
      for (int j = 0; j < 4; ++j)
        Hz[(size_t)(row0 + fm * 16 + j) * HD + col0 + fn * 16] = f2b(acc[fm][fn][j]);
}

// ---------------- gates GEMM + fused LSTM -------------------------------------
__global__ __launch_bounds__(256) void k_gates(const u16* __restrict__ xcat,
                                               const u16* __restrict__ wcat,
                                               const float* __restrict__ bcat,
                                               const float* __restrict__ cprev,
                                               float* __restrict__ cnext,
                                               float* __restrict__ hnext,
                                               u16* __restrict__ xcat_next) {
  __shared__ u16 As[32 * 32];
  __shared__ u16 Bs[64 * 32];
  __shared__ float Ct[32][68];
  int bid = blockIdx.x;
  int n0 = (bid >> 4) * 64;
  int m0 = (bid & 15) * 32;
  int tid = threadIdx.x, wid = tid >> 6, lane = tid & 63;
  int wr = wid >> 1, wc = wid & 1;
  f32x4 acc[2];
  acc[0] = (f32x4){0.f, 0.f, 0.f, 0.f};
  acc[1] = (f32x4){0.f, 0.f, 0.f, 0.f};

  int arow = tid >> 2, ack = tid & 3;
  int kc = lane >> 4;
  int ar = wr * 16 + (lane & 15);
  int bc = wc * 32 + (lane & 15);

  for (int k0 = 0; k0 < KC; k0 += 32) {
    if (tid < 128)
      *(uint4*)&As[swz(arow, ack)] = *(const uint4*)&xcat[(size_t)(m0 + arow) * KC + k0 + ack * 8];
    *(uint4*)&Bs[swz(arow & 63, ack)] =
        *(const uint4*)&wcat[(size_t)(n0 + (arow & 63)) * KC + k0 + ack * 8];
    __syncthreads();
    short8 afr = *(const short8*)&As[swz(ar, kc)];
    short8 bfr0 = *(const short8*)&Bs[swz(bc, kc)];
    short8 bfr1 = *(const short8*)&Bs[swz(bc + 16, kc)];
    acc[0] = __builtin_amdgcn_mfma_f32_16x16x32_bf16(afr, bfr0, acc[0], 0, 0, 0);
    acc[1] = __builtin_amdgcn_mfma_f32_16x16x32_bf16(afr, bfr1, acc[1], 0, 0, 0);
    __syncthreads();
  }

  int col0 = wc * 32 + (lane & 15);
  int row0 = wr * 16 + (lane >> 4) * 4;
#pragma unroll
  for (int fn = 0; fn < 2; ++fn) {
    float bv = bcat[n0 + col0 + fn * 16];
#pragma unroll
    for (int j = 0; j < 4; ++j)
      Ct[row0 + j][col0 + fn * 16] = acc[fn][j] + bv;
  }
  __syncthreads();

  int hh0 = n0 >> 2;
#pragma unroll
  for (int j = 0; j < 2; ++j) {
    int idx = j * 256 + tid;
    int b_loc = idx >> 4, hh_loc = idx & 15;
    float4 g4 = *(const float4*)&Ct[b_loc][hh_loc * 4];
    int b_g = m0 + b_loc, hh_g = hh0 + hh_loc;
    float cp = cprev[(size_t)b_g * HD + hh_g];
    float si = 1.f / (1.f + expf(-g4.x));
    float sf = 1.f / (1.f + expf(-g4.y));
    float so = 1.f / (1.f + expf(-g4.w));
    float c = sf * cp + si * tanhf(g4.z);
    float h = so * tanhf(c);
    cnext[(size_t)b_g * HD + hh_g] = c;
    hnext[(size_t)b_g * HD + hh_g] = h;
    xcat_next[(size_t)b_g * KC + CD + hh_g] = f2b(h);
  }
}

// ---------------- fused attention: prev-logits + q -> scores -> softmax -> ctx -
__global__ __launch_bounds__(1024) void k_att(
    const u16* __restrict__ Hp, const u16* __restrict__ eos_p,
    const u16* __restrict__ Hl,
    const float* __restrict__ hprev, const u16* __restrict__ h2h16,
    const float* __restrict__ h2h_b, const float* __restrict__ score_w,
    const float* __restrict__ mask, const float* __restrict__ eos_emb,
    const float* __restrict__ gen_w, const float* __restrict__ gen_b,
    float* __restrict__ logits,
    u16* __restrict__ xcat, float* __restrict__ char_maps, int t, int T) {
  __shared__ float q_s[HD];
  __shared__ float hp_s[HD];
  __shared__ float e_s[260];
  __shared__ float a_s[260];
  __shared__ float cpart[16][520];
  __shared__ float wred[16];
  __shared__ float sget[2];
  int b = blockIdx.x, tid = threadIdx.x;
  int wid = tid >> 6, lane = tid & 63;

  if (tid < HD) hp_s[tid] = hprev[(size_t)b * HD + tid];
  __syncthreads();

  float hp8[8];
#pragma unroll
  for (int j = 0; j < 8; ++j) hp8[j] = hp_s[lane * 8 + j];

  // ---- q[r] = hprev . h2h16[r] + h2h_b[r]; wave per row
#pragma unroll 2
  for (int r = wid; r < HD; r += 16) {
    uint4 wv = *(const uint4*)&h2h16[(size_t)r * HD + lane * 8];
    float x[8]; unpack8(wv, x);
    float acc = x[0] * hp8[0] + x[1] * hp8[1] + x[2] * hp8[2] + x[3] * hp8[3]
              + x[4] * hp8[4] + x[5] * hp8[5] + x[6] * hp8[6] + x[7] * hp8[7];
#pragma unroll
    for (int off = 32; off > 0; off >>= 1) acc += __shfl_down(acc, off);
    if (lane == 0) q_s[r] = acc + h2h_b[r];
  }

  // ---- logits for step t-1 (hiddens[t-1] == hprev), f32 weights
  if (t > 0) {
    float* lg = logits + ((size_t)b * T + (t - 1)) * NCLS;
    for (int n = wid; n < NCLS; n += 16) {
      const float4* w4 = (const float4*)(gen_w + (size_t)n * HD);
      float4 a0 = w4[lane * 2];
      float4 a1 = w4[lane * 2 + 1];
      float acc = a0.x * hp8[0] + a0.y * hp8[1] + a0.z * hp8[2] + a0.w * hp8[3]
                + a1.x * hp8[4] + a1.y * hp8[5] + a1.z * hp8[6] + a1.w * hp8[7];
#pragma unroll
      for (int off = 32; off > 0; off >>= 1) acc += __shfl_down(acc, off);
      if (lane == 0) lg[n] = acc + gen_b[n];
    }
  }
  __syncthreads();

  float q_r[8], sw_r[8];
#pragma unroll
  for (int j = 0; j < 8; ++j) {
    q_r[j]  = q_s[lane * 8 + j];
    sw_r[j] = score_w[lane * 8 + j];
  }

  // ---- scores: wave per key row
  const u16* hpB = Hp + (size_t)b * LS * HD;
#pragma unroll 2
  for (int l = wid; l < LP1; l += 16) {
    const u16* row = (l < LS) ? (hpB + (size_t)l * HD) : eos_p;
    uint4 rv = *(const uint4*)(row + lane * 8);
    float x[8]; unpack8(rv, x);
    float e = 0.f;
#pragma unroll
    for (int j = 0; j < 8; ++j) e += tanhf(x[j] + q_r[j]) * sw_r[j];
#pragma unroll
    for (int off = 32; off > 0; off >>= 1) e += __shfl_xor(e, off);
    if (lane == 0) e_s[l] = e;
  }
  __syncthreads();

  // ---- mask + softmax over 257
  float e = -INFINITY;
  if (tid < LS) {
    e = e_s[tid];
    float pm = rintf(1.0f - mask[(size_t)b * LS + tid]);
    if (pm >= 0.5f) e = -INFINITY;
  } else if (tid == LS) {
    e = e_s[LS];
  }
  {
    float mv = e;
#pragma unroll
    for (int off = 32; off > 0; off >>= 1) mv = fmaxf(mv, __shfl_xor(mv, off));
    if (lane == 0) wred[wid] = mv;
  }
  __syncthreads();
  if (tid == 0) {
    float m = wred[0];
#pragma unroll
    for (int i = 1; i < 5; ++i) m = fmaxf(m, wred[i]);
    sget[0] = m;
  }
  __syncthreads();
  float m = sget[0];
  float p = (tid <= LS) ? expf(e - m) : 0.f;
  {
    float sv = p;
#pragma unroll
    for (int off = 32; off > 0; off >>= 1) sv += __shfl_xor(sv, off);
    if (lane == 0) wred[wid] = sv;
  }
  __syncthreads();
  if (tid == 0) {
    float s = 0.f;
#pragma unroll
    for (int i = 0; i < 5; ++i) s += wred[i];
    sget[1] = 1.0f / s;
  }
  __syncthreads();
  float inv = sget[1];
  float* cm = char_maps + ((size_t)b * T + t) * LP1;
  if (tid <= LS) {
    float al = p * inv;
    a_s[tid] = al;
    cm[tid] = al;
  }
  __syncthreads();

  // ---- ctx[c] = sum_l a[l]*Hl[l][c] + a_eos*eos_emb[c] -> xcat[b][0:512] bf16
  float cacc[8] = {0.f, 0.f, 0.f, 0.f, 0.f, 0.f, 0.f, 0.f};
  const u16* HB = Hl + (size_t)b * LS * CD;
#pragma unroll 2
  for (int l = wid; l < LS; l += 16) {
    float al = a_s[l];
    uint4 rv = *(const uint4*)(HB + (size_t)l * CD + lane * 8);
    float x[8]; unpack8(rv, x);
#pragma unroll
    for (int j = 0; j < 8; ++j) cacc[j] += al * x[j];
  }
  if (wid == 0) {
    float ae = a_s[LS];
#pragma unroll
    for (int j = 0; j < 8; ++j) cacc[j] += ae * eos_emb[lane * 8 + j];
  }
  *(float4*)&cpart[wid][lane * 8]     = make_float4(cacc[0], cacc[1], cacc[2], cacc[3]);
  *(float4*)&cpart[wid][lane * 8 + 4] = make_float4(cacc[4], cacc[5], cacc[6], cacc[7]);
  __syncthreads();
  if (tid < CD) {
    float s = 0.f;
#pragma unroll
    for (int w = 0; w < 16; ++w) s += cpart[w][tid];
    xcat[(size_t)b * KC + tid] = f2b(s);
  }
}

// ---------------- logits (final step only) -------------------------------------
__global__ __launch_bounds__(256) void k_logits(const float* __restrict__ hn,
                                                const float* __restrict__ gen_w,
                                                const float* __restrict__ gen_b,
                                                float* __restrict__ out,
                                                int t, int T) {
  int b = blockIdx.x, tid = threadIdx.x;
  int wid = tid >> 6, lane = tid & 63;
  const float4* h4 = (const float4*)(hn + (size_t)b * HD);
  float4 h0 = h4[lane];
  float4 h1 = h4[lane + 64];
  for (int n = wid; n < NCLS; n += 4) {
    const float4* w4 = (const float4*)(gen_w + (size_t)n * HD);
    float4 a0 = w4[lane];
    float4 a1 = w4[lane + 64];
    float acc = a0.x * h0.x + a0.y * h0.y + a0.z * h0.z + a0.w * h0.w
              + a1.x * h1.x + a1.y * h1.y + a1.z * h1.z + a1.w * h1.w;
#pragma unroll
    for (int off = 32; off > 0; off >>= 1) acc += __shfl_down(acc, off);
    if (lane == 0) out[((size_t)b * T + t) * NCLS + n] = acc + gen_b[n];
  }
}

extern "C" void kernel_launch(void* const* d_in, const int* in_sizes, int n_in,
                              void* d_out, int out_size, void* d_ws, size_t ws_size,
                              hipStream_t stream) {
  const float* batch_H = (const float*)d_in[0];
  const float* mask    = (const float*)d_in[1];
  const float* i2h_w   = (const float*)d_in[2];
  const float* h2h_w   = (const float*)d_in[3];
  const float* h2h_b   = (const float*)d_in[4];
  const float* score_w = (const float*)d_in[5];
  const float* w_ih    = (const float*)d_in[6];
  const float* w_hh    = (const float*)d_in[7];
  const float* b_ih    = (const float*)d_in[8];
  const float* b_hh    = (const float*)d_in[9];
  const float* gen_w   = (const float*)d_in[10];
  const float* gen_b   = (const float*)d_in[11];
  const float* eos_emb = (const float*)d_in[12];

  int T = out_size / (BB * (NCLS + LP1));   // 26

  char* p = (char*)d_ws;
  auto alloc = [&](size_t bytes) -> char* {
    char* r = p; p += (bytes + 255) & ~(size_t)255; return r;
  };
  u16*   Hl16  = (u16*)alloc((size_t)BB * LS * CD * 2);
  u16*   Hp16  = (u16*)alloc((size_t)BB * LS * HD * 2);
  u16*   i2h16 = (u16*)alloc((size_t)HD * CD * 2);
  u16*   h2h16 = (u16*)alloc((size_t)HD * HD * 2);
  u16*   wcat  = (u16*)alloc((size_t)4 * HD * KC * 2);
  float* bcat  = (float*)alloc((size_t)4 * HD * 4);
  u16*   eos16 = (u16*)alloc((size_t)HD * 2);
  u16*   xcatA = (u16*)alloc((size_t)BB * KC * 2);
  u16*   xcatB = (u16*)alloc((size_t)BB * KC * 2);
  float* h0    = (float*)alloc((size_t)BB * HD * 4);
  float* h1    = (float*)alloc((size_t)BB * HD * 4);
  float* c0    = (float*)alloc((size_t)BB * HD * 4);
  float* c1    = (float*)alloc((size_t)BB * HD * 4);

  float* logits    = (float*)d_out;
  float* char_maps = logits + (size_t)BB * T * NCLS;

  hipMemsetAsync(h0, 0, (size_t)BB * HD * 4, stream);
  hipMemsetAsync(c0, 0, (size_t)BB * HD * 4, stream);
  hipMemsetAsync(xcatA, 0, (size_t)BB * KC * 2, stream);

  // prologue
  k_cvt<<<(HD * CD / 4 + 255) / 256, 256, 0, stream>>>(i2h_w, i2h16, HD * CD / 4);
  k_cvt<<<(HD * HD / 4 + 255) / 256, 256, 0, stream>>>(h2h_w, h2h16, HD * HD / 4);
  k_wcat<<<(4 * HD * KC / 4) / 256, 256, 0, stream>>>(w_ih, w_hh, wcat);
  k_bcat<<<(4 * HD + 255) / 256, 256, 0, stream>>>(b_ih, b_hh, bcat);
  k_eos_p<<<2, 256, 0, stream>>>(i2h_w, eos_emb, eos16);
  k_tr16<<<dim3(CD / 32, LS / 32, BB), 256, 0, stream>>>(batch_H, Hl16);
  k_hp_mfma<<<4 * BB, 512, 0, stream>>>(Hl16, i2h16, Hp16);

  float *hp = h0, *cp = c0, *hn = h1, *cnb = c1;
  u16 *xcur = xcatA, *xnext = xcatB;
  for (int t = 0; t < T; ++t) {
    k_att<<<BB, 1024, 0, stream>>>(Hp16, eos16, Hl16, hp, h2h16, h2h_b, score_w,
                                   mask, eos_emb, gen_w, gen_b, logits,
                                   xcur, char_maps, t, T);
    k_gates<<<512, 256, 0, stream>>>(xcur, wcat, bcat, cp, cnb, hn, xnext);
    float* tmp;
    tmp = hp; hp = hn;  hn  = tmp;
    tmp = cp; cp = cnb; cnb = tmp;
    u16* tx = xcur; xcur = xnext; xnext = tx;
  }
  k_logits<<<BB, 256, 0, stream>>>(hp, gen_w, gen_b, logits, T - 1, T);
}

// Round 6
// 2971.173 us; speedup vs baseline: 6.3090x; 1.0529x over previous
//
#include <hip/hip_runtime.h>
#include <math.h>

#define BB   512   // batch
#define CD   512   // channels c
#define HD   512   // hidden
#define LS   256   // spatial keys h*w
#define LP1  257   // keys + EOS
#define NCLS 38    // num classes
#define KC   1024  // concat K = CD + HD

typedef unsigned short u16;
typedef unsigned char u8;
typedef __attribute__((ext_vector_type(8))) short short8;
typedef __attribute__((ext_vector_type(4))) float f32x4;
typedef __attribute__((ext_vector_type(2))) float f32x2;

__device__ __forceinline__ u16 f2b(float f) {
  union { float f; unsigned u; } v; v.f = f;
  unsigned r = v.u + 0x7fffu + ((v.u >> 16) & 1u);
  return (u16)(r >> 16);
}
__device__ __forceinline__ float b2f(unsigned bits) {
  union { unsigned u; float f; } v; v.u = bits << 16;
  return v.f;
}
__device__ __forceinline__ void unpack8(uint4 r, float* o) {
  o[0] = b2f(r.x & 0xffffu); o[1] = b2f(r.x >> 16);
  o[2] = b2f(r.y & 0xffffu); o[3] = b2f(r.y >> 16);
  o[4] = b2f(r.z & 0xffffu); o[5] = b2f(r.z >> 16);
  o[6] = b2f(r.w & 0xffffu); o[7] = b2f(r.w >> 16);
}
// 8x fp8 e4m3 -> 8x f32 (HW cvt)
__device__ __forceinline__ void unpk8fp8(uint2 r, float* o) {
  f32x2 a = __builtin_amdgcn_cvt_pk_f32_fp8(r.x, false);
  f32x2 b = __builtin_amdgcn_cvt_pk_f32_fp8(r.x, true);
  f32x2 c = __builtin_amdgcn_cvt_pk_f32_fp8(r.y, false);
  f32x2 d = __builtin_amdgcn_cvt_pk_f32_fp8(r.y, true);
  o[0] = a[0]; o[1] = a[1]; o[2] = b[0]; o[3] = b[1];
  o[4] = c[0]; o[5] = c[1]; o[6] = d[0]; o[7] = d[1];
}
__device__ __forceinline__ u8 f2fp8(float f) {
  return (u8)(__builtin_amdgcn_cvt_pk_fp8_f32(f, f, 0u, false) & 0xffu);
}
// LDS swizzle for BK=32 u16 tiles, 8-elem (16B) chunks (verified: 0 conflicts)
__device__ __forceinline__ int swz(int row, int kchunk) {
  return row * 32 + (((kchunk ^ (row >> 1)) & 3) << 3);
}

// ---------------- f32 -> bf16 elementwise ------------------------------------
__global__ void k_cvt(const float* __restrict__ in, u16* __restrict__ out, int n4) {
  int i = blockIdx.x * 256 + threadIdx.x;
  if (i >= n4) return;
  float4 v = *(const float4*)&in[i * 4];
  ushort4 o;
  o.x = f2b(v.x); o.y = f2b(v.y); o.z = f2b(v.z); o.w = f2b(v.w);
  *(ushort4*)&out[i * 4] = o;
}

// ---------------- wcat[n][k]: n=4*hh+g -> w_ih/w_hh row (n&3)*512+(n>>2) -------
__global__ void k_wcat(const float* __restrict__ w_ih, const float* __restrict__ w_hh,
                       u16* __restrict__ wcat) {
  int idx = blockIdx.x * 256 + threadIdx.x;
  int n = idx >> 8, kq = idx & 255;
  int k = kq * 4;
  int orig = (n & 3) * HD + (n >> 2);
  const float* src = (k < CD) ? (w_ih + (size_t)orig * CD + k)
                              : (w_hh + (size_t)orig * HD + (k - CD));
  float4 v = *(const float4*)src;
  ushort4 o;
  o.x = f2b(v.x); o.y = f2b(v.y); o.z = f2b(v.z); o.w = f2b(v.w);
  *(ushort4*)&wcat[(size_t)n * KC + k] = o;
}
__global__ void k_bcat(const float* __restrict__ b_ih, const float* __restrict__ b_hh,
                       float* __restrict__ bcat) {
  int n = blockIdx.x * 256 + threadIdx.x;
  if (n >= 4 * HD) return;
  int orig = (n & 3) * HD + (n >> 2);
  bcat[n] = b_ih[orig] + b_hh[orig];
}

// ---------------- batch_H [b][c][l] f32 -> Hl16 [b][l][c] bf16 (once) ----------
__global__ __launch_bounds__(256) void k_tr16(const float* __restrict__ in,
                                              u16* __restrict__ out) {
  __shared__ float Ls[32][36];
  int b = blockIdx.z;
  int c0 = blockIdx.x * 32, l0 = blockIdx.y * 32;
  int tid = threadIdx.x;
  int r = tid >> 3, q4 = (tid & 7) * 4;
  float4 v = *(const float4*)&in[((size_t)b * CD + c0 + r) * LS + l0 + q4];
  Ls[r][q4] = v.x; Ls[r][q4 + 1] = v.y; Ls[r][q4 + 2] = v.z; Ls[r][q4 + 3] = v.w;
  __syncthreads();
  ushort4 o;
  o.x = f2b(Ls[q4 + 0][r]); o.y = f2b(Ls[q4 + 1][r]);
  o.z = f2b(Ls[q4 + 2][r]); o.w = f2b(Ls[q4 + 3][r]);
  *(ushort4*)&out[((size_t)b * LS + l0 + r) * CD + c0 + q4] = o;
}

// ---------------- eos_p[hh] -> bf16 -------------------------------------------
__global__ void k_eos_p(const float* __restrict__ i2h_w, const float* __restrict__ eos_emb,
                        u16* __restrict__ eos_p) {
  int hh = blockIdx.x * blockDim.x + threadIdx.x;
  if (hh >= HD) return;
  const float* row = i2h_w + (size_t)hh * CD;
  float acc = 0.f;
  for (int c = 0; c < CD; ++c) acc += row[c] * eos_emb[c];
  eos_p[hh] = f2b(acc);
}

// ---------------- prologue MFMA: Hp8[b][l][:] = (Hl16[b][l][:] . i2h16^T) fp8 --
// BM=64 (l), BN=512 (ALL hh -> A fetched once), BK=32; 512 thr = 8 waves.
__global__ __launch_bounds__(512) void k_hp_mfma(const u16* __restrict__ A,
                                                 const u16* __restrict__ B,
                                                 u8* __restrict__ Hp) {
  __shared__ u16 As[64 * 32];
  __shared__ u16 Bs[512 * 32];
  int bid = blockIdx.x;
  int z = bid >> 2, m0 = (bid & 3) * 64;
  int tid = threadIdx.x, wid = tid >> 6, lane = tid & 63;
  f32x4 acc[4][4];
#pragma unroll
  for (int i = 0; i < 4; ++i)
#pragma unroll
    for (int j = 0; j < 4; ++j) acc[i][j] = (f32x4){0.f, 0.f, 0.f, 0.f};

  const u16* Az = A + (size_t)z * LS * CD + (size_t)m0 * CD;
  int arow = tid >> 2, ack = tid & 3;
  int kc = lane >> 4;
  int ar = lane & 15;
  int bc = wid * 64 + (lane & 15);

  for (int k0 = 0; k0 < CD; k0 += 32) {
    if (tid < 256)
      *(uint4*)&As[swz(arow, ack)] = *(const uint4*)&Az[(size_t)arow * CD + k0 + ack * 8];
#pragma unroll
    for (int c = 0; c < 4; ++c)
      *(uint4*)&Bs[swz(tid, c)] = *(const uint4*)&B[(size_t)tid * CD + k0 + c * 8];
    __syncthreads();
    short8 afr[4], bfr[4];
#pragma unroll
    for (int fm = 0; fm < 4; ++fm) afr[fm] = *(const short8*)&As[swz(ar + fm * 16, kc)];
#pragma unroll
    for (int fn = 0; fn < 4; ++fn) bfr[fn] = *(const short8*)&Bs[swz(bc + fn * 16, kc)];
#pragma unroll
    for (int fm = 0; fm < 4; ++fm)
#pragma unroll
      for (int fn = 0; fn < 4; ++fn)
        acc[fm][fn] = __builtin_amdgcn_mfma_f32_16x16x32_bf16(afr[fm], bfr[fn],
                                                              acc[fm][fn], 0, 0, 0);
    __syncthreads();
  }
  int row0 = m0 + (lane >> 4) * 4;
  int col0 = wid * 64 + (lane & 15);
  u8* Hz = Hp + (size_t)z * LS * HD;
#pragma unroll
  for (int fm = 0; fm < 4; ++fm)
#pragma unroll
    for (int fn = 0; fn < 4; ++fn)
#pragma unroll
      for (int j = 0; j < 4; ++j)
        Hz[(size_t)(row0 + fm * 16 + j) * HD + col0 + fn * 16] = f2fp8(acc[fm][fn][j]);
}

// ---------------- gates GEMM + fused LSTM -------------------------------------
__global__ __launch_bounds__(256) void k_gates(const u16* __restrict__ xcat,
                                               const u16* __restrict__ wcat,
                                               const float* __restrict__ bcat,
                                               const float* __restrict__ cprev,
                                               float* __restrict__ cnext,
                                               float* __restrict__ hnext,
                                               u16* __restrict__ xcat_next) {
  __shared__ u16 As[32 * 32];
  __shared__ u16 Bs[64 * 32];
  __shared__ float Ct[32][68];
  int bid = blockIdx.x;
  int n0 = (bid >> 4) * 64;
  int m0 = (bid & 15) * 32;
  int tid = threadIdx.x, wid = tid >> 6, lane = tid & 63;
  int wr = wid >> 1, wc = wid & 1;
  f32x4 acc[2];
  acc[0] = (f32x4){0.f, 0.f, 0.f, 0.f};
  acc[1] = (f32x4){0.f, 0.f, 0.f, 0.f};

  int arow = tid >> 2, ack = tid & 3;
  int kc = lane >> 4;
  int ar = wr * 16 + (lane & 15);
  int bc = wc * 32 + (lane & 15);

  for (int k0 = 0; k0 < KC; k0 += 32) {
    if (tid < 128)
      *(uint4*)&As[swz(arow, ack)] = *(const uint4*)&xcat[(size_t)(m0 + arow) * KC + k0 + ack * 8];
    *(uint4*)&Bs[swz(arow & 63, ack)] =
        *(const uint4*)&wcat[(size_t)(n0 + (arow & 63)) * KC + k0 + ack * 8];
    __syncthreads();
    short8 afr = *(const short8*)&As[swz(ar, kc)];
    short8 bfr0 = *(const short8*)&Bs[swz(bc, kc)];
    short8 bfr1 = *(const short8*)&Bs[swz(bc + 16, kc)];
    acc[0] = __builtin_amdgcn_mfma_f32_16x16x32_bf16(afr, bfr0, acc[0], 0, 0, 0);
    acc[1] = __builtin_amdgcn_mfma_f32_16x16x32_bf16(afr, bfr1, acc[1], 0, 0, 0);
    __syncthreads();
  }

  int col0 = wc * 32 + (lane & 15);
  int row0 = wr * 16 + (lane >> 4) * 4;
#pragma unroll
  for (int fn = 0; fn < 2; ++fn) {
    float bv = bcat[n0 + col0 + fn * 16];
#pragma unroll
    for (int j = 0; j < 4; ++j)
      Ct[row0 + j][col0 + fn * 16] = acc[fn][j] + bv;
  }
  __syncthreads();

  int hh0 = n0 >> 2;
#pragma unroll
  for (int j = 0; j < 2; ++j) {
    int idx = j * 256 + tid;
    int b_loc = idx >> 4, hh_loc = idx & 15;
    float4 g4 = *(const float4*)&Ct[b_loc][hh_loc * 4];
    int b_g = m0 + b_loc, hh_g = hh0 + hh_loc;
    float cp = cprev[(size_t)b_g * HD + hh_g];
    float si = 1.f / (1.f + expf(-g4.x));
    float sf = 1.f / (1.f + expf(-g4.y));
    float so = 1.f / (1.f + expf(-g4.w));
    float c = sf * cp + si * tanhf(g4.z);
    float h = so * tanhf(c);
    cnext[(size_t)b_g * HD + hh_g] = c;
    hnext[(size_t)b_g * HD + hh_g] = h;
    xcat_next[(size_t)b_g * KC + CD + hh_g] = f2b(h);
  }
}

// ---------------- fused attention: prev-logits + q -> scores -> softmax -> ctx -
__global__ __launch_bounds__(1024) void k_att(
    const u8* __restrict__ Hp, const u16* __restrict__ eos_p,
    const u16* __restrict__ Hl,
    const float* __restrict__ hprev, const u16* __restrict__ h2h16,
    const float* __restrict__ h2h_b, const float* __restrict__ score_w,
    const float* __restrict__ mask, const float* __restrict__ eos_emb,
    const float* __restrict__ gen_w, const float* __restrict__ gen_b,
    float* __restrict__ logits,
    u16* __restrict__ xcat, float* __restrict__ char_maps, int t, int T) {
  __shared__ float q_s[HD];
  __shared__ float hp_s[HD];
  __shared__ float e_s[260];
  __shared__ float a_s[260];
  __shared__ float cpart[16][520];
  __shared__ float wred[16];
  __shared__ float sget[2];
  int b = blockIdx.x, tid = threadIdx.x;
  int wid = tid >> 6, lane = tid & 63;

  if (tid < HD) hp_s[tid] = hprev[(size_t)b * HD + tid];
  __syncthreads();

  float hp8[8];
#pragma unroll
  for (int j = 0; j < 8; ++j) hp8[j] = hp_s[lane * 8 + j];

  // ---- q[r] = hprev . h2h16[r] + h2h_b[r]; wave per row
#pragma unroll 2
  for (int r = wid; r < HD; r += 16) {
    uint4 wv = *(const uint4*)&h2h16[(size_t)r * HD + lane * 8];
    float x[8]; unpack8(wv, x);
    float acc = x[0] * hp8[0] + x[1] * hp8[1] + x[2] * hp8[2] + x[3] * hp8[3]
              + x[4] * hp8[4] + x[5] * hp8[5] + x[6] * hp8[6] + x[7] * hp8[7];
#pragma unroll
    for (int off = 32; off > 0; off >>= 1) acc += __shfl_down(acc, off);
    if (lane == 0) q_s[r] = acc + h2h_b[r];
  }

  // ---- logits for step t-1 (hiddens[t-1] == hprev), f32 weights
  if (t > 0) {
    float* lg = logits + ((size_t)b * T + (t - 1)) * NCLS;
    for (int n = wid; n < NCLS; n += 16) {
      const float4* w4 = (const float4*)(gen_w + (size_t)n * HD);
      float4 a0 = w4[lane * 2];
      float4 a1 = w4[lane * 2 + 1];
      float acc = a0.x * hp8[0] + a0.y * hp8[1] + a0.z * hp8[2] + a0.w * hp8[3]
                + a1.x * hp8[4] + a1.y * hp8[5] + a1.z * hp8[6] + a1.w * hp8[7];
#pragma unroll
      for (int off = 32; off > 0; off >>= 1) acc += __shfl_down(acc, off);
      if (lane == 0) lg[n] = acc + gen_b[n];
    }
  }
  __syncthreads();

  float q_r[8], sw_r[8];
#pragma unroll
  for (int j = 0; j < 8; ++j) {
    q_r[j]  = q_s[lane * 8 + j];
    sw_r[j] = score_w[lane * 8 + j];
  }

  // ---- scores: wave per key row (Hp fp8; EOS row bf16)
  const u8* hpB = Hp + (size_t)b * LS * HD;
#pragma unroll 2
  for (int l = wid; l < LP1; l += 16) {
    float x[8];
    if (l < LS) {
      uint2 rv = *(const uint2*)(hpB + (size_t)l * HD + lane * 8);
      unpk8fp8(rv, x);
    } else {
      uint4 rv = *(const uint4*)(eos_p + lane * 8);
      unpack8(rv, x);
    }
    float e = 0.f;
#pragma unroll
    for (int j = 0; j < 8; ++j) e += tanhf(x[j] + q_r[j]) * sw_r[j];
#pragma unroll
    for (int off = 32; off > 0; off >>= 1) e += __shfl_xor(e, off);
    if (lane == 0) e_s[l] = e;
  }
  __syncthreads();

  // ---- mask + softmax over 257
  float e = -INFINITY;
  if (tid < LS) {
    e = e_s[tid];
    float pm = rintf(1.0f - mask[(size_t)b * LS + tid]);
    if (pm >= 0.5f) e = -INFINITY;
  } else if (tid == LS) {
    e = e_s[LS];
  }
  {
    float mv = e;
#pragma unroll
    for (int off = 32; off > 0; off >>= 1) mv = fmaxf(mv, __shfl_xor(mv, off));
    if (lane == 0) wred[wid] = mv;
  }
  __syncthreads();
  if (tid == 0) {
    float m = wred[0];
#pragma unroll
    for (int i = 1; i < 5; ++i) m = fmaxf(m, wred[i]);
    sget[0] = m;
  }
  __syncthreads();
  float m = sget[0];
  float p = (tid <= LS) ? expf(e - m) : 0.f;
  {
    float sv = p;
#pragma unroll
    for (int off = 32; off > 0; off >>= 1) sv += __shfl_xor(sv, off);
    if (lane == 0) wred[wid] = sv;
  }
  __syncthreads();
  if (tid == 0) {
    float s = 0.f;
#pragma unroll
    for (int i = 0; i < 5; ++i) s += wred[i];
    sget[1] = 1.0f / s;
  }
  __syncthreads();
  float inv = sget[1];
  float* cm = char_maps + ((size_t)b * T + t) * LP1;
  if (tid <= LS) {
    float al = p * inv;
    a_s[tid] = al;
    cm[tid] = al;
  }
  __syncthreads();

  // ---- ctx[c] = sum_l a[l]*Hl[l][c] + a_eos*eos_emb[c] -> xcat[b][0:512] bf16
  float cacc[8] = {0.f, 0.f, 0.f, 0.f, 0.f, 0.f, 0.f, 0.f};
  const u16* HB = Hl + (size_t)b * LS * CD;
#pragma unroll 2
  for (int l = wid; l < LS; l += 16) {
    float al = a_s[l];
    uint4 rv = *(const uint4*)(HB + (size_t)l * CD + lane * 8);
    float x[8]; unpack8(rv, x);
#pragma unroll
    for (int j = 0; j < 8; ++j) cacc[j] += al * x[j];
  }
  if (wid == 0) {
    float ae = a_s[LS];
#pragma unroll
    for (int j = 0; j < 8; ++j) cacc[j] += ae * eos_emb[lane * 8 + j];
  }
  *(float4*)&cpart[wid][lane * 8]     = make_float4(cacc[0], cacc[1], cacc[2], cacc[3]);
  *(float4*)&cpart[wid][lane * 8 + 4] = make_float4(cacc[4], cacc[5], cacc[6], cacc[7]);
  __syncthreads();
  if (tid < CD) {
    float s = 0.f;
#pragma unroll
    for (int w = 0; w < 16; ++w) s += cpart[w][tid];
    xcat[(size_t)b * KC + tid] = f2b(s);
  }
}

// ---------------- logits (final step only) -------------------------------------
__global__ __launch_bounds__(256) void k_logits(const float* __restrict__ hn,
                                                const float* __restrict__ gen_w,
                                                const float* __restrict__ gen_b,
                                                float* __restrict__ out,
                                                int t, int T) {
  int b = blockIdx.x, tid = threadIdx.x;
  int wid = tid >> 6, lane = tid & 63;
  const float4* h4 = (const float4*)(hn + (size_t)b * HD);
  float4 h0 = h4[lane];
  float4 h1 = h4[lane + 64];
  for (int n = wid; n < NCLS; n += 4) {
    const float4* w4 = (const float4*)(gen_w + (size_t)n * HD);
    float4 a0 = w4[lane];
    float4 a1 = w4[lane + 64];
    float acc = a0.x * h0.x + a0.y * h0.y + a0.z * h0.z + a0.w * h0.w
              + a1.x * h1.x + a1.y * h1.y + a1.z * h1.z + a1.w * h1.w;
#pragma unroll
    for (int off = 32; off > 0; off >>= 1) acc += __shfl_down(acc, off);
    if (lane == 0) out[((size_t)b * T + t) * NCLS + n] = acc + gen_b[n];
  }
}

extern "C" void kernel_launch(void* const* d_in, const int* in_sizes, int n_in,
                              void* d_out, int out_size, void* d_ws, size_t ws_size,
                              hipStream_t stream) {
  const float* batch_H = (const float*)d_in[0];
  const float* mask    = (const float*)d_in[1];
  const float* i2h_w   = (const float*)d_in[2];
  const float* h2h_w   = (const float*)d_in[3];
  const float* h2h_b   = (const float*)d_in[4];
  const float* score_w = (const float*)d_in[5];
  const float* w_ih    = (const float*)d_in[6];
  const float* w_hh    = (const float*)d_in[7];
  const float* b_ih    = (const float*)d_in[8];
  const float* b_hh    = (const float*)d_in[9];
  const float* gen_w   = (const float*)d_in[10];
  const float* gen_b   = (const float*)d_in[11];
  const float* eos_emb = (const float*)d_in[12];

  int T = out_size / (BB * (NCLS + LP1));   // 26

  char* p = (char*)d_ws;
  auto alloc = [&](size_t bytes) -> char* {
    char* r = p; p += (bytes + 255) & ~(size_t)255; return r;
  };
  u16*   Hl16  = (u16*)alloc((size_t)BB * LS * CD * 2);
  u8*    Hp8   = (u8*) alloc((size_t)BB * LS * HD);
  u16*   i2h16 = (u16*)alloc((size_t)HD * CD * 2);
  u16*   h2h16 = (u16*)alloc((size_t)HD * HD * 2);
  u16*   wcat  = (u16*)alloc((size_t)4 * HD * KC * 2);
  float* bcat  = (float*)alloc((size_t)4 * HD * 4);
  u16*   eos16 = (u16*)alloc((size_t)HD * 2);
  u16*   xcatA = (u16*)alloc((size_t)BB * KC * 2);
  u16*   xcatB = (u16*)alloc((size_t)BB * KC * 2);
  float* h0    = (float*)alloc((size_t)BB * HD * 4);
  float* h1    = (float*)alloc((size_t)BB * HD * 4);
  float* c0    = (float*)alloc((size_t)BB * HD * 4);
  float* c1    = (float*)alloc((size_t)BB * HD * 4);

  float* logits    = (float*)d_out;
  float* char_maps = logits + (size_t)BB * T * NCLS;

  hipMemsetAsync(h0, 0, (size_t)BB * HD * 4, stream);
  hipMemsetAsync(c0, 0, (size_t)BB * HD * 4, stream);
  hipMemsetAsync(xcatA, 0, (size_t)BB * KC * 2, stream);

  // prologue
  k_cvt<<<(HD * CD / 4 + 255) / 256, 256, 0, stream>>>(i2h_w, i2h16, HD * CD / 4);
  k_cvt<<<(HD * HD / 4 + 255) / 256, 256, 0, stream>>>(h2h_w, h2h16, HD * HD / 4);
  k_wcat<<<(4 * HD * KC / 4) / 256, 256, 0, stream>>>(w_ih, w_hh, wcat);
  k_bcat<<<(4 * HD + 255) / 256, 256, 0, stream>>>(b_ih, b_hh, bcat);
  k_eos_p<<<2, 256, 0, stream>>>(i2h_w, eos_emb, eos16);
  k_tr16<<<dim3(CD / 32, LS / 32, BB), 256, 0, stream>>>(batch_H, Hl16);
  k_hp_mfma<<<4 * BB, 512, 0, stream>>>(Hl16, i2h16, Hp8);

  float *hp = h0, *cp = c0, *hn = h1, *cnb = c1;
  u16 *xcur = xcatA, *xnext = xcatB;
  for (int t = 0; t < T; ++t) {
    k_att<<<BB, 1024, 0, stream>>>(Hp8, eos16, Hl16, hp, h2h16, h2h_b, score_w,
                                   mask, eos_emb, gen_w, gen_b, logits,
                                   xcur, char_maps, t, T);
    k_gates<<<512, 256, 0, stream>>>(xcur, wcat, bcat, cp, cnb, hn, xnext);
    float* tmp;
    tmp = hp; hp = hn;  hn  = tmp;
    tmp = cp; cp = cnb; cnb = tmp;
    u16* tx = xcur; xcur = xnext; xnext = tx;
  }
  k_logits<<<BB, 256, 0, stream>>>(hp, gen_w, gen_b, logits, T - 1, T);
}

// Round 7
// 2702.988 us; speedup vs baseline: 6.9350x; 1.0992x over previous
//
#include <hip/hip_runtime.h>
#include <math.h>

#define BB   512   // batch
#define CD   512   // channels c
#define HD   512   // hidden
#define LS   256   // spatial keys h*w
#define LP1  257   // keys + EOS
#define NCLS 38    // num classes
#define KC   1024  // concat K = CD + HD
#define NQ   576   // q rows (512) + logits rows (38) padded to 64

typedef unsigned short u16;
typedef unsigned char u8;
typedef __attribute__((ext_vector_type(8))) short short8;
typedef __attribute__((ext_vector_type(4))) float f32x4;
typedef __attribute__((ext_vector_type(2))) float f32x2;

__device__ __forceinline__ u16 f2b(float f) {
  union { float f; unsigned u; } v; v.f = f;
  unsigned r = v.u + 0x7fffu + ((v.u >> 16) & 1u);
  return (u16)(r >> 16);
}
__device__ __forceinline__ float b2f(unsigned bits) {
  union { unsigned u; float f; } v; v.u = bits << 16;
  return v.f;
}
__device__ __forceinline__ void unpack8(uint4 r, float* o) {
  o[0] = b2f(r.x & 0xffffu); o[1] = b2f(r.x >> 16);
  o[2] = b2f(r.y & 0xffffu); o[3] = b2f(r.y >> 16);
  o[4] = b2f(r.z & 0xffffu); o[5] = b2f(r.z >> 16);
  o[6] = b2f(r.w & 0xffffu); o[7] = b2f(r.w >> 16);
}
// 8x fp8 e4m3 -> 8x f32 (HW cvt)
__device__ __forceinline__ void unpk8fp8(uint2 r, float* o) {
  f32x2 a = __builtin_amdgcn_cvt_pk_f32_fp8(r.x, false);
  f32x2 b = __builtin_amdgcn_cvt_pk_f32_fp8(r.x, true);
  f32x2 c = __builtin_amdgcn_cvt_pk_f32_fp8(r.y, false);
  f32x2 d = __builtin_amdgcn_cvt_pk_f32_fp8(r.y, true);
  o[0] = a[0]; o[1] = a[1]; o[2] = b[0]; o[3] = b[1];
  o[4] = c[0]; o[5] = c[1]; o[6] = d[0]; o[7] = d[1];
}
__device__ __forceinline__ u8 f2fp8(float f) {
  return (u8)(__builtin_amdgcn_cvt_pk_fp8_f32(f, f, 0u, false) & 0xffu);
}
// LDS swizzle for BK=32 u16 tiles, 8-elem (16B) chunks (verified: 0 conflicts)
__device__ __forceinline__ int swz(int row, int kchunk) {
  return row * 32 + (((kchunk ^ (row >> 1)) & 3) << 3);
}

// ---------------- f32 -> bf16 elementwise ------------------------------------
__global__ void k_cvt(const float* __restrict__ in, u16* __restrict__ out, int n4) {
  int i = blockIdx.x * 256 + threadIdx.x;
  if (i >= n4) return;
  float4 v = *(const float4*)&in[i * 4];
  ushort4 o;
  o.x = f2b(v.x); o.y = f2b(v.y); o.z = f2b(v.z); o.w = f2b(v.w);
  *(ushort4*)&out[i * 4] = o;
}

// ---------------- B16[576][512] = [h2h_w ; gen_w ; 0] bf16 ---------------------
__global__ void k_b16(const float* __restrict__ h2h_w, const float* __restrict__ gen_w,
                      u16* __restrict__ B16) {
  int idx = blockIdx.x * 256 + threadIdx.x;   // over 576*128
  int n = idx >> 7, k4 = (idx & 127) * 4;
  ushort4 o = {0, 0, 0, 0};
  if (n < HD) {
    float4 v = *(const float4*)&h2h_w[(size_t)n * HD + k4];
    o.x = f2b(v.x); o.y = f2b(v.y); o.z = f2b(v.z); o.w = f2b(v.w);
  } else if (n < HD + NCLS) {
    float4 v = *(const float4*)&gen_w[(size_t)(n - HD) * HD + k4];
    o.x = f2b(v.x); o.y = f2b(v.y); o.z = f2b(v.z); o.w = f2b(v.w);
  }
  *(ushort4*)&B16[(size_t)n * HD + k4] = o;
}
__global__ void k_bq(const float* __restrict__ h2h_b, const float* __restrict__ gen_b,
                     float* __restrict__ bq) {
  int n = blockIdx.x * 256 + threadIdx.x;
  if (n >= NQ) return;
  bq[n] = (n < HD) ? h2h_b[n] : ((n < HD + NCLS) ? gen_b[n - HD] : 0.f);
}

// ---------------- wcat[n][k]: n=4*hh+g -> w_ih/w_hh row (n&3)*512+(n>>2) -------
__global__ void k_wcat(const float* __restrict__ w_ih, const float* __restrict__ w_hh,
                       u16* __restrict__ wcat) {
  int idx = blockIdx.x * 256 + threadIdx.x;
  int n = idx >> 8, kq = idx & 255;
  int k = kq * 4;
  int orig = (n & 3) * HD + (n >> 2);
  const float* src = (k < CD) ? (w_ih + (size_t)orig * CD + k)
                              : (w_hh + (size_t)orig * HD + (k - CD));
  float4 v = *(const float4*)src;
  ushort4 o;
  o.x = f2b(v.x); o.y = f2b(v.y); o.z = f2b(v.z); o.w = f2b(v.w);
  *(ushort4*)&wcat[(size_t)n * KC + k] = o;
}
__global__ void k_bcat(const float* __restrict__ b_ih, const float* __restrict__ b_hh,
                       float* __restrict__ bcat) {
  int n = blockIdx.x * 256 + threadIdx.x;
  if (n >= 4 * HD) return;
  int orig = (n & 3) * HD + (n >> 2);
  bcat[n] = b_ih[orig] + b_hh[orig];
}

// ---------------- batch_H [b][c][l] f32 -> Hl16 [b][l][c] bf16 (once) ----------
__global__ __launch_bounds__(256) void k_tr16(const float* __restrict__ in,
                                              u16* __restrict__ out) {
  __shared__ float Ls[32][36];
  int b = blockIdx.z;
  int c0 = blockIdx.x * 32, l0 = blockIdx.y * 32;
  int tid = threadIdx.x;
  int r = tid >> 3, q4 = (tid & 7) * 4;
  float4 v = *(const float4*)&in[((size_t)b * CD + c0 + r) * LS + l0 + q4];
  Ls[r][q4] = v.x; Ls[r][q4 + 1] = v.y; Ls[r][q4 + 2] = v.z; Ls[r][q4 + 3] = v.w;
  __syncthreads();
  ushort4 o;
  o.x = f2b(Ls[q4 + 0][r]); o.y = f2b(Ls[q4 + 1][r]);
  o.z = f2b(Ls[q4 + 2][r]); o.w = f2b(Ls[q4 + 3][r]);
  *(ushort4*)&out[((size_t)b * LS + l0 + r) * CD + c0 + q4] = o;
}

// ---------------- eos_p[hh] -> bf16 -------------------------------------------
__global__ void k_eos_p(const float* __restrict__ i2h_w, const float* __restrict__ eos_emb,
                        u16* __restrict__ eos_p) {
  int hh = blockIdx.x * blockDim.x + threadIdx.x;
  if (hh >= HD) return;
  const float* row = i2h_w + (size_t)hh * CD;
  float acc = 0.f;
  for (int c = 0; c < CD; ++c) acc += row[c] * eos_emb[c];
  eos_p[hh] = f2b(acc);
}

// ---------------- prologue MFMA: Hp8[b][l][:] = (Hl16[b][l][:] . i2h16^T) fp8 --
// BM=64 (l), BN=512 (all hh), BK=32; 512 thr = 8 waves; reg-prefetch pipeline.
__global__ __launch_bounds__(512) void k_hp_mfma(const u16* __restrict__ A,
                                                 const u16* __restrict__ B,
                                                 u8* __restrict__ Hp) {
  __shared__ u16 As[64 * 32];
  __shared__ u16 Bs[512 * 32];
  int bid = blockIdx.x;
  int z = bid >> 2, m0 = (bid & 3) * 64;
  int tid = threadIdx.x, wid = tid >> 6, lane = tid & 63;
  f32x4 acc[4][4];
#pragma unroll
  for (int i = 0; i < 4; ++i)
#pragma unroll
    for (int j = 0; j < 4; ++j) acc[i][j] = (f32x4){0.f, 0.f, 0.f, 0.f};

  const u16* Az = A + (size_t)z * LS * CD + (size_t)m0 * CD;
  int arow = tid >> 2, ack = tid & 3;
  int kc = lane >> 4;
  int ar = lane & 15;
  int bc = wid * 64 + (lane & 15);

  uint4 pa; uint4 pb[4];
  if (tid < 256) pa = *(const uint4*)&Az[(size_t)arow * CD + ack * 8];
#pragma unroll
  for (int c = 0; c < 4; ++c) pb[c] = *(const uint4*)&B[(size_t)tid * CD + c * 8];

  for (int k0 = 0; k0 < CD; k0 += 32) {
    if (tid < 256) *(uint4*)&As[swz(arow, ack)] = pa;
#pragma unroll
    for (int c = 0; c < 4; ++c) *(uint4*)&Bs[swz(tid, c)] = pb[c];
    __syncthreads();
    int k1 = k0 + 32;
    if (k1 < CD) {
      if (tid < 256) pa = *(const uint4*)&Az[(size_t)arow * CD + k1 + ack * 8];
#pragma unroll
      for (int c = 0; c < 4; ++c)
        pb[c] = *(const uint4*)&B[(size_t)tid * CD + k1 + c * 8];
    }
    short8 afr[4], bfr[4];
#pragma unroll
    for (int fm = 0; fm < 4; ++fm) afr[fm] = *(const short8*)&As[swz(ar + fm * 16, kc)];
#pragma unroll
    for (int fn = 0; fn < 4; ++fn) bfr[fn] = *(const short8*)&Bs[swz(bc + fn * 16, kc)];
#pragma unroll
    for (int fm = 0; fm < 4; ++fm)
#pragma unroll
      for (int fn = 0; fn < 4; ++fn)
        acc[fm][fn] = __builtin_amdgcn_mfma_f32_16x16x32_bf16(afr[fm], bfr[fn],
                                                              acc[fm][fn], 0, 0, 0);
    __syncthreads();
  }
  int row0 = m0 + (lane >> 4) * 4;
  int col0 = wid * 64 + (lane & 15);
  u8* Hz = Hp + (size_t)z * LS * HD;
#pragma unroll
  for (int fm = 0; fm < 4; ++fm)
#pragma unroll
    for (int fn = 0; fn < 4; ++fn)
#pragma unroll
      for (int j = 0; j < 4; ++j)
        Hz[(size_t)(row0 + fm * 16 + j) * HD + col0 + fn * 16] = f2fp8(acc[fm][fn][j]);
}

// ---------------- q GEMM: [q | logits] = h16 . [h2h;gen]^T + bias --------------
// A = h bf16 rows (stride KC), B16 [576][512]. BM=32 (b), BN=64, BK=32.
// grid 144: n0=(bid>>4)*64, m0=(bid&15)*32. Also emits logits for step tprev.
__global__ __launch_bounds__(256) void k_q(const u16* __restrict__ Ah,
                                           const u16* __restrict__ B16,
                                           const float* __restrict__ bq,
                                           float* __restrict__ qb,
                                           float* __restrict__ logits,
                                           int tprev, int T) {
  __shared__ u16 As[32 * 32];
  __shared__ u16 Bs[64 * 32];
  int bid = blockIdx.x;
  int n0 = (bid >> 4) * 64;
  int m0 = (bid & 15) * 32;
  int tid = threadIdx.x, wid = tid >> 6, lane = tid & 63;
  int wr = wid >> 1, wc = wid & 1;
  f32x4 acc[2];
  acc[0] = (f32x4){0.f, 0.f, 0.f, 0.f};
  acc[1] = (f32x4){0.f, 0.f, 0.f, 0.f};

  int arow = tid >> 2, ack = tid & 3;
  int kc = lane >> 4;
  int ar = wr * 16 + (lane & 15);
  int bc = wc * 32 + (lane & 15);

  uint4 pa, pb;
  if (tid < 128) pa = *(const uint4*)&Ah[(size_t)(m0 + arow) * KC + ack * 8];
  pb = *(const uint4*)&B16[(size_t)(n0 + (arow & 63)) * HD + ack * 8];

  for (int k0 = 0; k0 < HD; k0 += 32) {
    if (tid < 128) *(uint4*)&As[swz(arow, ack)] = pa;
    *(uint4*)&Bs[swz(arow & 63, ack)] = pb;
    __syncthreads();
    int k1 = k0 + 32;
    if (k1 < HD) {
      if (tid < 128) pa = *(const uint4*)&Ah[(size_t)(m0 + arow) * KC + k1 + ack * 8];
      pb = *(const uint4*)&B16[(size_t)(n0 + (arow & 63)) * HD + k1 + ack * 8];
    }
    short8 afr = *(const short8*)&As[swz(ar, kc)];
    short8 bfr0 = *(const short8*)&Bs[swz(bc, kc)];
    short8 bfr1 = *(const short8*)&Bs[swz(bc + 16, kc)];
    acc[0] = __builtin_amdgcn_mfma_f32_16x16x32_bf16(afr, bfr0, acc[0], 0, 0, 0);
    acc[1] = __builtin_amdgcn_mfma_f32_16x16x32_bf16(afr, bfr1, acc[1], 0, 0, 0);
    __syncthreads();
  }

  int col0 = n0 + wc * 32 + (lane & 15);
  int row0 = m0 + wr * 16 + (lane >> 4) * 4;
#pragma unroll
  for (int fn = 0; fn < 2; ++fn) {
    int c = col0 + fn * 16;
    float bv = bq[c];
#pragma unroll
    for (int j = 0; j < 4; ++j) {
      int b = row0 + j;
      float v = acc[fn][j] + bv;
      if (c < HD) qb[(size_t)b * HD + c] = v;
      else if (c < HD + NCLS && tprev >= 0)
        logits[((size_t)b * T + tprev) * NCLS + (c - HD)] = v;
    }
  }
}

// ---------------- gates GEMM + fused LSTM (reg-prefetch) -----------------------
__global__ __launch_bounds__(256) void k_gates(const u16* __restrict__ xcat,
                                               const u16* __restrict__ wcat,
                                               const float* __restrict__ bcat,
                                               const float* __restrict__ cprev,
                                               float* __restrict__ cnext,
                                               u16* __restrict__ xcat_next) {
  __shared__ u16 As[32 * 32];
  __shared__ u16 Bs[64 * 32];
  __shared__ float Ct[32][68];
  int bid = blockIdx.x;
  int n0 = (bid >> 4) * 64;
  int m0 = (bid & 15) * 32;
  int tid = threadIdx.x, wid = tid >> 6, lane = tid & 63;
  int wr = wid >> 1, wc = wid & 1;
  f32x4 acc[2];
  acc[0] = (f32x4){0.f, 0.f, 0.f, 0.f};
  acc[1] = (f32x4){0.f, 0.f, 0.f, 0.f};

  int arow = tid >> 2, ack = tid & 3;
  int kc = lane >> 4;
  int ar = wr * 16 + (lane & 15);
  int bc = wc * 32 + (lane & 15);

  uint4 pa, pb;
  if (tid < 128) pa = *(const uint4*)&xcat[(size_t)(m0 + arow) * KC + ack * 8];
  pb = *(const uint4*)&wcat[(size_t)(n0 + (arow & 63)) * KC + ack * 8];

  for (int k0 = 0; k0 < KC; k0 += 32) {
    if (tid < 128) *(uint4*)&As[swz(arow, ack)] = pa;
    *(uint4*)&Bs[swz(arow & 63, ack)] = pb;
    __syncthreads();
    int k1 = k0 + 32;
    if (k1 < KC) {
      if (tid < 128) pa = *(const uint4*)&xcat[(size_t)(m0 + arow) * KC + k1 + ack * 8];
      pb = *(const uint4*)&wcat[(size_t)(n0 + (arow & 63)) * KC + k1 + ack * 8];
    }
    short8 afr = *(const short8*)&As[swz(ar, kc)];
    short8 bfr0 = *(const short8*)&Bs[swz(bc, kc)];
    short8 bfr1 = *(const short8*)&Bs[swz(bc + 16, kc)];
    acc[0] = __builtin_amdgcn_mfma_f32_16x16x32_bf16(afr, bfr0, acc[0], 0, 0, 0);
    acc[1] = __builtin_amdgcn_mfma_f32_16x16x32_bf16(afr, bfr1, acc[1], 0, 0, 0);
    __syncthreads();
  }

  int col0 = wc * 32 + (lane & 15);
  int row0 = wr * 16 + (lane >> 4) * 4;
#pragma unroll
  for (int fn = 0; fn < 2; ++fn) {
    float bv = bcat[n0 + col0 + fn * 16];
#pragma unroll
    for (int j = 0; j < 4; ++j)
      Ct[row0 + j][col0 + fn * 16] = acc[fn][j] + bv;
  }
  __syncthreads();

  int hh0 = n0 >> 2;
#pragma unroll
  for (int j = 0; j < 2; ++j) {
    int idx = j * 256 + tid;
    int b_loc = idx >> 4, hh_loc = idx & 15;
    float4 g4 = *(const float4*)&Ct[b_loc][hh_loc * 4];
    int b_g = m0 + b_loc, hh_g = hh0 + hh_loc;
    float cp = cprev[(size_t)b_g * HD + hh_g];
    float si = 1.f / (1.f + expf(-g4.x));
    float sf = 1.f / (1.f + expf(-g4.y));
    float so = 1.f / (1.f + expf(-g4.w));
    float c = sf * cp + si * tanhf(g4.z);
    float h = so * tanhf(c);
    cnext[(size_t)b_g * HD + hh_g] = c;
    xcat_next[(size_t)b_g * KC + CD + hh_g] = f2b(h);
  }
}

// ---------------- fused attention: scores -> softmax -> ctx --------------------
__global__ __launch_bounds__(1024) void k_att(
    const u8* __restrict__ Hp, const u16* __restrict__ eos_p,
    const u16* __restrict__ Hl,
    const float* __restrict__ qb, const float* __restrict__ score_w,
    const float* __restrict__ mask, const float* __restrict__ eos_emb,
    u16* __restrict__ xcat, float* __restrict__ char_maps, int t, int T) {
  __shared__ float e_s[260];
  __shared__ float a_s[260];
  __shared__ float cpart[16][520];
  __shared__ float wred[16];
  __shared__ float sget[2];
  int b = blockIdx.x, tid = threadIdx.x;
  int wid = tid >> 6, lane = tid & 63;

  // per-lane q/sw registers (hh = lane*8 + j), straight from global (L1-shared)
  float q_r[8], sw_r[8];
  {
    const float4* q4 = (const float4*)(qb + (size_t)b * HD);
    float4 a0 = q4[lane * 2], a1 = q4[lane * 2 + 1];
    q_r[0] = a0.x; q_r[1] = a0.y; q_r[2] = a0.z; q_r[3] = a0.w;
    q_r[4] = a1.x; q_r[5] = a1.y; q_r[6] = a1.z; q_r[7] = a1.w;
    const float4* s4 = (const float4*)score_w;
    float4 s0 = s4[lane * 2], s1 = s4[lane * 2 + 1];
    sw_r[0] = s0.x; sw_r[1] = s0.y; sw_r[2] = s0.z; sw_r[3] = s0.w;
    sw_r[4] = s1.x; sw_r[5] = s1.y; sw_r[6] = s1.z; sw_r[7] = s1.w;
  }

  // ---- scores: wave per key row (Hp fp8; EOS row bf16)
  const u8* hpB = Hp + (size_t)b * LS * HD;
#pragma unroll 4
  for (int l = wid; l < LP1; l += 16) {
    float x[8];
    if (l < LS) {
      uint2 rv = *(const uint2*)(hpB + (size_t)l * HD + lane * 8);
      unpk8fp8(rv, x);
    } else {
      uint4 rv = *(const uint4*)(eos_p + lane * 8);
      unpack8(rv, x);
    }
    float e = 0.f;
#pragma unroll
    for (int j = 0; j < 8; ++j) e += tanhf(x[j] + q_r[j]) * sw_r[j];
#pragma unroll
    for (int off = 32; off > 0; off >>= 1) e += __shfl_xor(e, off);
    if (lane == 0) e_s[l] = e;
  }
  __syncthreads();

  // ---- mask + softmax over 257
  float e = -INFINITY;
  if (tid < LS) {
    e = e_s[tid];
    float pm = rintf(1.0f - mask[(size_t)b * LS + tid]);
    if (pm >= 0.5f) e = -INFINITY;
  } else if (tid == LS) {
    e = e_s[LS];
  }
  {
    float mv = e;
#pragma unroll
    for (int off = 32; off > 0; off >>= 1) mv = fmaxf(mv, __shfl_xor(mv, off));
    if (lane == 0) wred[wid] = mv;
  }
  __syncthreads();
  if (tid == 0) {
    float m = wred[0];
#pragma unroll
    for (int i = 1; i < 5; ++i) m = fmaxf(m, wred[i]);
    sget[0] = m;
  }
  __syncthreads();
  float m = sget[0];
  float p = (tid <= LS) ? expf(e - m) : 0.f;
  {
    float sv = p;
#pragma unroll
    for (int off = 32; off > 0; off >>= 1) sv += __shfl_xor(sv, off);
    if (lane == 0) wred[wid] = sv;
  }
  __syncthreads();
  if (tid == 0) {
    float s = 0.f;
#pragma unroll
    for (int i = 0; i < 5; ++i) s += wred[i];
    sget[1] = 1.0f / s;
  }
  __syncthreads();
  float inv = sget[1];
  float* cm = char_maps + ((size_t)b * T + t) * LP1;
  if (tid <= LS) {
    float al = p * inv;
    a_s[tid] = al;
    cm[tid] = al;
  }
  __syncthreads();

  // ---- ctx[c] = sum_l a[l]*Hl[l][c] + a_eos*eos_emb[c] -> xcat[b][0:512] bf16
  float cacc[8] = {0.f, 0.f, 0.f, 0.f, 0.f, 0.f, 0.f, 0.f};
  const u16* HB = Hl + (size_t)b * LS * CD;
#pragma unroll 4
  for (int l = wid; l < LS; l += 16) {
    float al = a_s[l];
    uint4 rv = *(const uint4*)(HB + (size_t)l * CD + lane * 8);
    float x[8]; unpack8(rv, x);
#pragma unroll
    for (int j = 0; j < 8; ++j) cacc[j] += al * x[j];
  }
  if (wid == 0) {
    float ae = a_s[LS];
#pragma unroll
    for (int j = 0; j < 8; ++j) cacc[j] += ae * eos_emb[lane * 8 + j];
  }
  *(float4*)&cpart[wid][lane * 8]     = make_float4(cacc[0], cacc[1], cacc[2], cacc[3]);
  *(float4*)&cpart[wid][lane * 8 + 4] = make_float4(cacc[4], cacc[5], cacc[6], cacc[7]);
  __syncthreads();
  if (tid < CD) {
    float s = 0.f;
#pragma unroll
    for (int w = 0; w < 16; ++w) s += cpart[w][tid];
    xcat[(size_t)b * KC + tid] = f2b(s);
  }
}

extern "C" void kernel_launch(void* const* d_in, const int* in_sizes, int n_in,
                              void* d_out, int out_size, void* d_ws, size_t ws_size,
                              hipStream_t stream) {
  const float* batch_H = (const float*)d_in[0];
  const float* mask    = (const float*)d_in[1];
  const float* i2h_w   = (const float*)d_in[2];
  const float* h2h_w   = (const float*)d_in[3];
  const float* h2h_b   = (const float*)d_in[4];
  const float* score_w = (const float*)d_in[5];
  const float* w_ih    = (const float*)d_in[6];
  const float* w_hh    = (const float*)d_in[7];
  const float* b_ih    = (const float*)d_in[8];
  const float* b_hh    = (const float*)d_in[9];
  const float* gen_w   = (const float*)d_in[10];
  const float* gen_b   = (const float*)d_in[11];
  const float* eos_emb = (const float*)d_in[12];

  int T = out_size / (BB * (NCLS + LP1));   // 26

  char* p = (char*)d_ws;
  auto alloc = [&](size_t bytes) -> char* {
    char* r = p; p += (bytes + 255) & ~(size_t)255; return r;
  };
  u16*   Hl16  = (u16*)alloc((size_t)BB * LS * CD * 2);
  u8*    Hp8   = (u8*) alloc((size_t)BB * LS * HD);
  u16*   i2h16 = (u16*)alloc((size_t)HD * CD * 2);
  u16*   B16   = (u16*)alloc((size_t)NQ * HD * 2);
  float* bq    = (float*)alloc((size_t)NQ * 4);
  u16*   wcat  = (u16*)alloc((size_t)4 * HD * KC * 2);
  float* bcat  = (float*)alloc((size_t)4 * HD * 4);
  u16*   eos16 = (u16*)alloc((size_t)HD * 2);
  u16*   xcatA = (u16*)alloc((size_t)BB * KC * 2);
  u16*   xcatB = (u16*)alloc((size_t)BB * KC * 2);
  float* qb    = (float*)alloc((size_t)BB * HD * 4);
  float* c0    = (float*)alloc((size_t)BB * HD * 4);
  float* c1    = (float*)alloc((size_t)BB * HD * 4);

  float* logits    = (float*)d_out;
  float* char_maps = logits + (size_t)BB * T * NCLS;

  hipMemsetAsync(c0, 0, (size_t)BB * HD * 4, stream);
  hipMemsetAsync(xcatA, 0, (size_t)BB * KC * 2, stream);

  // prologue
  k_cvt<<<(HD * CD / 4 + 255) / 256, 256, 0, stream>>>(i2h_w, i2h16, HD * CD / 4);
  k_b16<<<(NQ * HD / 4) / 256, 256, 0, stream>>>(h2h_w, gen_w, B16);
  k_bq<<<(NQ + 255) / 256, 256, 0, stream>>>(h2h_b, gen_b, bq);
  k_wcat<<<(4 * HD * KC / 4) / 256, 256, 0, stream>>>(w_ih, w_hh, wcat);
  k_bcat<<<(4 * HD + 255) / 256, 256, 0, stream>>>(b_ih, b_hh, bcat);
  k_eos_p<<<2, 256, 0, stream>>>(i2h_w, eos_emb, eos16);
  k_tr16<<<dim3(CD / 32, LS / 32, BB), 256, 0, stream>>>(batch_H, Hl16);
  k_hp_mfma<<<4 * BB, 512, 0, stream>>>(Hl16, i2h16, Hp8);

  float *cp = c0, *cnb = c1;
  u16 *xcur = xcatA, *xnext = xcatB;
  for (int t = 0; t < T; ++t) {
    k_q<<<144, 256, 0, stream>>>(xcur + CD, B16, bq, qb, logits, t - 1, T);
    k_att<<<BB, 1024, 0, stream>>>(Hp8, eos16, Hl16, qb, score_w,
                                   mask, eos_emb, xcur, char_maps, t, T);
    k_gates<<<512, 256, 0, stream>>>(xcur, wcat, bcat, cp, cnb, xnext);
    float* tmp = cp; cp = cnb; cnb = tmp;
    u16* tx = xcur; xcur = xnext; xnext = tx;
  }
  // final logits from h_T (q output unused)
  k_q<<<144, 256, 0, stream>>>(xcur + CD, B16, bq, qb, logits, T - 1, T);
}

// Round 12
// 1896.473 us; speedup vs baseline: 9.8842x; 1.4253x over previous
//
#include <hip/hip_runtime.h>
#include <math.h>

#define BB   512   // batch
#define CD   512   // channels c
#define HD   512   // hidden
#define LS   256   // spatial keys h*w
#define LP1  257   // keys + EOS
#define NCLS 38    // num classes
#define KC   1024  // concat K = CD + HD
#define NQ   576   // q rows (512) + logits rows (38) padded to 64

typedef unsigned short u16;
typedef unsigned char u8;
typedef __attribute__((ext_vector_type(8))) short short8;
typedef __attribute__((ext_vector_type(4))) float f32x4;
typedef __attribute__((ext_vector_type(2))) float f32x2;

#define LOG2E  1.4426950408889634f
#define LOG2E2 2.8853900817779268f

__device__ __forceinline__ u16 f2b(float f) {
  union { float f; unsigned u; } v; v.f = f;
  unsigned r = v.u + 0x7fffu + ((v.u >> 16) & 1u);
  return (u16)(r >> 16);
}
__device__ __forceinline__ float b2f(unsigned bits) {
  union { unsigned u; float f; } v; v.u = bits << 16;
  return v.f;
}
__device__ __forceinline__ void unpack8(uint4 r, float* o) {
  o[0] = b2f(r.x & 0xffffu); o[1] = b2f(r.x >> 16);
  o[2] = b2f(r.y & 0xffffu); o[3] = b2f(r.y >> 16);
  o[4] = b2f(r.z & 0xffffu); o[5] = b2f(r.z >> 16);
  o[6] = b2f(r.w & 0xffffu); o[7] = b2f(r.w >> 16);
}
// 8x fp8 e4m3 -> 8x f32 (HW cvt)
__device__ __forceinline__ void unpk8fp8(uint2 r, float* o) {
  f32x2 a = __builtin_amdgcn_cvt_pk_f32_fp8(r.x, false);
  f32x2 b = __builtin_amdgcn_cvt_pk_f32_fp8(r.x, true);
  f32x2 c = __builtin_amdgcn_cvt_pk_f32_fp8(r.y, false);
  f32x2 d = __builtin_amdgcn_cvt_pk_f32_fp8(r.y, true);
  o[0] = a[0]; o[1] = a[1]; o[2] = b[0]; o[3] = b[1];
  o[4] = c[0]; o[5] = c[1]; o[6] = d[0]; o[7] = d[1];
}
__device__ __forceinline__ u8 f2fp8(float f) {
  return (u8)(__builtin_amdgcn_cvt_pk_fp8_f32(f, f, 0u, false) & 0xffu);
}
// fast tanh / sigmoid / exp via native v_exp_f32 (=exp2) / v_rcp_f32.
// branch-free; saturates correctly at +/-inf.
__device__ __forceinline__ float tanh_f(float x) {
  float t = __builtin_amdgcn_exp2f(x * LOG2E2);     // e^{2x}
  return 1.0f - 2.0f * __builtin_amdgcn_rcpf(t + 1.0f);
}
__device__ __forceinline__ float sigm_f(float x) {
  float t = __builtin_amdgcn_exp2f(-x * LOG2E);     // e^{-x}
  return __builtin_amdgcn_rcpf(1.0f + t);
}
__device__ __forceinline__ float exp_f(float x) {   // e^x
  return __builtin_amdgcn_exp2f(x * LOG2E);
}
// LDS swizzle for BK=32 u16 tiles, 8-elem (16B) chunks (verified: 0 conflicts)
__device__ __forceinline__ int swz(int row, int kchunk) {
  return row * 32 + (((kchunk ^ (row >> 1)) & 3) << 3);
}

// ---------------- f32 -> bf16 elementwise ------------------------------------
__global__ void k_cvt(const float* __restrict__ in, u16* __restrict__ out, int n4) {
  int i = blockIdx.x * 256 + threadIdx.x;
  if (i >= n4) return;
  float4 v = *(const float4*)&in[i * 4];
  ushort4 o;
  o.x = f2b(v.x); o.y = f2b(v.y); o.z = f2b(v.z); o.w = f2b(v.w);
  *(ushort4*)&out[i * 4] = o;
}

// ---------------- B16[576][512] = [h2h_w ; gen_w ; 0] bf16 ---------------------
__global__ void k_b16(const float* __restrict__ h2h_w, const float* __restrict__ gen_w,
                      u16* __restrict__ B16) {
  int idx = blockIdx.x * 256 + threadIdx.x;   // over 576*128
  int n = idx >> 7, k4 = (idx & 127) * 4;
  ushort4 o = {0, 0, 0, 0};
  if (n < HD) {
    float4 v = *(const float4*)&h2h_w[(size_t)n * HD + k4];
    o.x = f2b(v.x); o.y = f2b(v.y); o.z = f2b(v.z); o.w = f2b(v.w);
  } else if (n < HD + NCLS) {
    float4 v = *(const float4*)&gen_w[(size_t)(n - HD) * HD + k4];
    o.x = f2b(v.x); o.y = f2b(v.y); o.z = f2b(v.z); o.w = f2b(v.w);
  }
  *(ushort4*)&B16[(size_t)n * HD + k4] = o;
}
__global__ void k_bq(const float* __restrict__ h2h_b, const float* __restrict__ gen_b,
                     float* __restrict__ bq) {
  int n = blockIdx.x * 256 + threadIdx.x;
  if (n >= NQ) return;
  bq[n] = (n < HD) ? h2h_b[n] : ((n < HD + NCLS) ? gen_b[n - HD] : 0.f);
}

// ---------------- wcat[n][k]: n=4*hh+g -> w_ih/w_hh row (n&3)*512+(n>>2) -------
__global__ void k_wcat(const float* __restrict__ w_ih, const float* __restrict__ w_hh,
                       u16* __restrict__ wcat) {
  int idx = blockIdx.x * 256 + threadIdx.x;
  int n = idx >> 8, kq = idx & 255;
  int k = kq * 4;
  int orig = (n & 3) * HD + (n >> 2);
  const float* src = (k < CD) ? (w_ih + (size_t)orig * CD + k)
                              : (w_hh + (size_t)orig * HD + (k - CD));
  float4 v = *(const float4*)src;
  ushort4 o;
  o.x = f2b(v.x); o.y = f2b(v.y); o.z = f2b(v.z); o.w = f2b(v.w);
  *(ushort4*)&wcat[(size_t)n * KC + k] = o;
}
__global__ void k_bcat(const float* __restrict__ b_ih, const float* __restrict__ b_hh,
                       float* __restrict__ bcat) {
  int n = blockIdx.x * 256 + threadIdx.x;
  if (n >= 4 * HD) return;
  int orig = (n & 3) * HD + (n >> 2);
  bcat[n] = b_ih[orig] + b_hh[orig];
}

// ---------------- batch_H [b][c][l] f32 -> Hl16 [b][l][c] bf16 (once) ----------
__global__ __launch_bounds__(256) void k_tr16(const float* __restrict__ in,
                                              u16* __restrict__ out) {
  __shared__ float Ls[32][36];
  int b = blockIdx.z;
  int c0 = blockIdx.x * 32, l0 = blockIdx.y * 32;
  int tid = threadIdx.x;
  int r = tid >> 3, q4 = (tid & 7) * 4;
  float4 v = *(const float4*)&in[((size_t)b * CD + c0 + r) * LS + l0 + q4];
  Ls[r][q4] = v.x; Ls[r][q4 + 1] = v.y; Ls[r][q4 + 2] = v.z; Ls[r][q4 + 3] = v.w;
  __syncthreads();
  ushort4 o;
  o.x = f2b(Ls[q4 + 0][r]); o.y = f2b(Ls[q4 + 1][r]);
  o.z = f2b(Ls[q4 + 2][r]); o.w = f2b(Ls[q4 + 3][r]);
  *(ushort4*)&out[((size_t)b * LS + l0 + r) * CD + c0 + q4] = o;
}

// ---------------- eos_p[hh] -> bf16 -------------------------------------------
__global__ void k_eos_p(const float* __restrict__ i2h_w, const float* __restrict__ eos_emb,
                        u16* __restrict__ eos_p) {
  int hh = blockIdx.x * blockDim.x + threadIdx.x;
  if (hh >= HD) return;
  const float* row = i2h_w + (size_t)hh * CD;
  float acc = 0.f;
  for (int c = 0; c < CD; ++c) acc += row[c] * eos_emb[c];
  eos_p[hh] = f2b(acc);
}

// ---------------- prologue MFMA: Hp8[b][l][:] = (Hl16[b][l][:] . i2h16^T) fp8 --
// BM=64 (l), BN=512 (all hh -> A fetched once), BK=32; 512 thr = 8 waves.
// NOTE: NO reg-prefetch here — acc[4][4] uses 64 VGPRs; holding staged tiles
// across the barrier spilled to scratch (R7: WRITE 65->569MB, 166->390us).
__global__ __launch_bounds__(512) void k_hp_mfma(const u16* __restrict__ A,
                                                 const u16* __restrict__ B,
                                                 u8* __restrict__ Hp) {
  __shared__ u16 As[64 * 32];
  __shared__ u16 Bs[512 * 32];
  int bid = blockIdx.x;
  int z = bid >> 2, m0 = (bid & 3) * 64;
  int tid = threadIdx.x, wid = tid >> 6, lane = tid & 63;
  f32x4 acc[4][4];
#pragma unroll
  for (int i = 0; i < 4; ++i)
#pragma unroll
    for (int j = 0; j < 4; ++j) acc[i][j] = (f32x4){0.f, 0.f, 0.f, 0.f};

  const u16* Az = A + (size_t)z * LS * CD + (size_t)m0 * CD;
  int arow = tid >> 2, ack = tid & 3;
  int kc = lane >> 4;
  int ar = lane & 15;
  int bc = wid * 64 + (lane & 15);

  for (int k0 = 0; k0 < CD; k0 += 32) {
    if (tid < 256)
      *(uint4*)&As[swz(arow, ack)] = *(const uint4*)&Az[(size_t)arow * CD + k0 + ack * 8];
#pragma unroll
    for (int c = 0; c < 4; ++c)
      *(uint4*)&Bs[swz(tid, c)] = *(const uint4*)&B[(size_t)tid * CD + k0 + c * 8];
    __syncthreads();
    short8 afr[4], bfr[4];
#pragma unroll
    for (int fm = 0; fm < 4; ++fm) afr[fm] = *(const short8*)&As[swz(ar + fm * 16, kc)];
#pragma unroll
    for (int fn = 0; fn < 4; ++fn) bfr[fn] = *(const short8*)&Bs[swz(bc + fn * 16, kc)];
#pragma unroll
    for (int fm = 0; fm < 4; ++fm)
#pragma unroll
      for (int fn = 0; fn < 4; ++fn)
        acc[fm][fn] = __builtin_amdgcn_mfma_f32_16x16x32_bf16(afr[fm], bfr[fn],
                                                              acc[fm][fn], 0, 0, 0);
    __syncthreads();
  }
  int row0 = m0 + (lane >> 4) * 4;
  int col0 = wid * 64 + (lane & 15);
  u8* Hz = Hp + (size_t)z * LS * HD;
#pragma unroll
  for (int fm = 0; fm < 4; ++fm)
#pragma unroll
    for (int fn = 0; fn < 4; ++fn)
#pragma unroll
      for (int j = 0; j < 4; ++j)
        Hz[(size_t)(row0 + fm * 16 + j) * HD + col0 + fn * 16] = f2fp8(acc[fm][fn][j]);
}

// ---------------- q GEMM: [q | logits] = h16 . [h2h;gen]^T + bias --------------
__global__ __launch_bounds__(256) void k_q(const u16* __restrict__ Ah,
                                           const u16* __restrict__ B16,
                                           const float* __restrict__ bq,
                                           float* __restrict__ qb,
                                           float* __restrict__ logits,
                                           int tprev, int T) {
  __shared__ u16 As[32 * 32];
  __shared__ u16 Bs[64 * 32];
  int bid = blockIdx.x;
  int n0 = (bid >> 4) * 64;
  int m0 = (bid & 15) * 32;
  int tid = threadIdx.x, wid = tid >> 6, lane = tid & 63;
  int wr = wid >> 1, wc = wid & 1;
  f32x4 acc[2];
  acc[0] = (f32x4){0.f, 0.f, 0.f, 0.f};
  acc[1] = (f32x4){0.f, 0.f, 0.f, 0.f};

  int arow = tid >> 2, ack = tid & 3;
  int kc = lane >> 4;
  int ar = wr * 16 + (lane & 15);
  int bc = wc * 32 + (lane & 15);

  uint4 pa, pb;
  if (tid < 128) pa = *(const uint4*)&Ah[(size_t)(m0 + arow) * KC + ack * 8];
  pb = *(const uint4*)&B16[(size_t)(n0 + (arow & 63)) * HD + ack * 8];

  for (int k0 = 0; k0 < HD; k0 += 32) {
    if (tid < 128) *(uint4*)&As[swz(arow, ack)] = pa;
    *(uint4*)&Bs[swz(arow & 63, ack)] = pb;
    __syncthreads();
    int k1 = k0 + 32;
    if (k1 < HD) {
      if (tid < 128) pa = *(const uint4*)&Ah[(size_t)(m0 + arow) * KC + k1 + ack * 8];
      pb = *(const uint4*)&B16[(size_t)(n0 + (arow & 63)) * HD + k1 + ack * 8];
    }
    short8 afr = *(const short8*)&As[swz(ar, kc)];
    short8 bfr0 = *(const short8*)&Bs[swz(bc, kc)];
    short8 bfr1 = *(const short8*)&Bs[swz(bc + 16, kc)];
    acc[0] = __builtin_amdgcn_mfma_f32_16x16x32_bf16(afr, bfr0, acc[0], 0, 0, 0);
    acc[1] = __builtin_amdgcn_mfma_f32_16x16x32_bf16(afr, bfr1, acc[1], 0, 0, 0);
    __syncthreads();
  }

  int col0 = n0 + wc * 32 + (lane & 15);
  int row0 = m0 + wr * 16 + (lane >> 4) * 4;
#pragma unroll
  for (int fn = 0; fn < 2; ++fn) {
    int c = col0 + fn * 16;
    float bv = bq[c];
#pragma unroll
    for (int j = 0; j < 4; ++j) {
      int b = row0 + j;
      float v = acc[fn][j] + bv;
      if (c < HD) qb[(size_t)b * HD + c] = v;
      else if (c < HD + NCLS && tprev >= 0)
        logits[((size_t)b * T + tprev) * NCLS + (c - HD)] = v;
    }
  }
}

// ---------------- gates GEMM + fused LSTM (2-reg prefetch) ---------------------
__global__ __launch_bounds__(256) void k_gates(const u16* __restrict__ xcat,
                                               const u16* __restrict__ wcat,
                                               const float* __restrict__ bcat,
                                               const float* __restrict__ cprev,
                                               float* __restrict__ cnext,
                                               u16* __restrict__ xcat_next) {
  __shared__ u16 As[32 * 32];
  __shared__ u16 Bs[64 * 32];
  __shared__ float Ct[32][68];
  int bid = blockIdx.x;
  int n0 = (bid >> 4) * 64;
  int m0 = (bid & 15) * 32;
  int tid = threadIdx.x, wid = tid >> 6, lane = tid & 63;
  int wr = wid >> 1, wc = wid & 1;
  f32x4 acc[2];
  acc[0] = (f32x4){0.f, 0.f, 0.f, 0.f};
  acc[1] = (f32x4){0.f, 0.f, 0.f, 0.f};

  int arow = tid >> 2, ack = tid & 3;
  int kc = lane >> 4;
  int ar = wr * 16 + (lane & 15);
  int bc = wc * 32 + (lane & 15);

  uint4 pa, pb;
  if (tid < 128) pa = *(const uint4*)&xcat[(size_t)(m0 + arow) * KC + ack * 8];
  pb = *(const uint4*)&wcat[(size_t)(n0 + (arow & 63)) * KC + ack * 8];

  for (int k0 = 0; k0 < KC; k0 += 32) {
    if (tid < 128) *(uint4*)&As[swz(arow, ack)] = pa;
    *(uint4*)&Bs[swz(arow & 63, ack)] = pb;
    __syncthreads();
    int k1 = k0 + 32;
    if (k1 < KC) {
      if (tid < 128) pa = *(const uint4*)&xcat[(size_t)(m0 + arow) * KC + k1 + ack * 8];
      pb = *(const uint4*)&wcat[(size_t)(n0 + (arow & 63)) * KC + k1 + ack * 8];
    }
    short8 afr = *(const short8*)&As[swz(ar, kc)];
    short8 bfr0 = *(const short8*)&Bs[swz(bc, kc)];
    short8 bfr1 = *(const short8*)&Bs[swz(bc + 16, kc)];
    acc[0] = __builtin_amdgcn_mfma_f32_16x16x32_bf16(afr, bfr0, acc[0], 0, 0, 0);
    acc[1] = __builtin_amdgcn_mfma_f32_16x16x32_bf16(afr, bfr1, acc[1], 0, 0, 0);
    __syncthreads();
  }

  int col0 = wc * 32 + (lane & 15);
  int row0 = wr * 16 + (lane >> 4) * 4;
#pragma unroll
  for (int fn = 0; fn < 2; ++fn) {
    float bv = bcat[n0 + col0 + fn * 16];
#pragma unroll
    for (int j = 0; j < 4; ++j)
      Ct[row0 + j][col0 + fn * 16] = acc[fn][j] + bv;
  }
  __syncthreads();

  int hh0 = n0 >> 2;
#pragma unroll
  for (int j = 0; j < 2; ++j) {
    int idx = j * 256 + tid;
    int b_loc = idx >> 4, hh_loc = idx & 15;
    float4 g4 = *(const float4*)&Ct[b_loc][hh_loc * 4];
    int b_g = m0 + b_loc, hh_g = hh0 + hh_loc;
    float cp = cprev[(size_t)b_g * HD + hh_g];
    float si = sigm_f(g4.x);
    float sf = sigm_f(g4.y);
    float so = sigm_f(g4.w);
    float c = sf * cp + si * tanh_f(g4.z);
    float h = so * tanh_f(c);
    cnext[(size_t)b_g * HD + hh_g] = c;
    xcat_next[(size_t)b_g * KC + CD + hh_g] = f2b(h);
  }
}

// ---------------- fused attention: scores -> softmax -> ctx --------------------
__global__ __launch_bounds__(1024) void k_att(
    const u8* __restrict__ Hp, const u16* __restrict__ eos_p,
    const u16* __restrict__ Hl,
    const float* __restrict__ qb, const float* __restrict__ score_w,
    const float* __restrict__ mask, const float* __restrict__ eos_emb,
    u16* __restrict__ xcat, float* __restrict__ char_maps, int t, int T) {
  __shared__ float e_s[260];
  __shared__ float a_s[260];
  __shared__ float cpart[16][520];
  __shared__ float wred[16];
  __shared__ float sget[2];
  int b = blockIdx.x, tid = threadIdx.x;
  int wid = tid >> 6, lane = tid & 63;

  float q_r[8], sw_r[8];
  {
    const float4* q4 = (const float4*)(qb + (size_t)b * HD);
    float4 a0 = q4[lane * 2], a1 = q4[lane * 2 + 1];
    q_r[0] = a0.x; q_r[1] = a0.y; q_r[2] = a0.z; q_r[3] = a0.w;
    q_r[4] = a1.x; q_r[5] = a1.y; q_r[6] = a1.z; q_r[7] = a1.w;
    const float4* s4 = (const float4*)score_w;
    float4 s0 = s4[lane * 2], s1 = s4[lane * 2 + 1];
    sw_r[0] = s0.x; sw_r[1] = s0.y; sw_r[2] = s0.z; sw_r[3] = s0.w;
    sw_r[4] = s1.x; sw_r[5] = s1.y; sw_r[6] = s1.z; sw_r[7] = s1.w;
  }

  // ---- scores: wave per key row (Hp fp8; EOS row bf16)
  const u8* hpB = Hp + (size_t)b * LS * HD;
#pragma unroll 4
  for (int l = wid; l < LP1; l += 16) {
    float x[8];
    if (l < LS) {
      uint2 rv = *(const uint2*)(hpB + (size_t)l * HD + lane * 8);
      unpk8fp8(rv, x);
    } else {
      uint4 rv = *(const uint4*)(eos_p + lane * 8);
      unpack8(rv, x);
    }
    float e = 0.f;
#pragma unroll
    for (int j = 0; j < 8; ++j) e += tanh_f(x[j] + q_r[j]) * sw_r[j];
#pragma unroll
    for (int off = 32; off > 0; off >>= 1) e += __shfl_xor(e, off);
    if (lane == 0) e_s[l] = e;
  }
  __syncthreads();

  // ---- mask + softmax over 257
  float e = -INFINITY;
  if (tid < LS) {
    e = e_s[tid];
    float pm = rintf(1.0f - mask[(size_t)b * LS + tid]);
    if (pm >= 0.5f) e = -INFINITY;
  } else if (tid == LS) {
    e = e_s[LS];
  }
  {
    float mv = e;
#pragma unroll
    for (int off = 32; off > 0; off >>= 1) mv = fmaxf(mv, __shfl_xor(mv, off));
    if (lane == 0) wred[wid] = mv;
  }
  __syncthreads();
  if (tid == 0) {
    float m = wred[0];
#pragma unroll
    for (int i = 1; i < 5; ++i) m = fmaxf(m, wred[i]);
    sget[0] = m;
  }
  __syncthreads();
  float m = sget[0];
  float p = (tid <= LS) ? exp_f(e - m) : 0.f;
  {
    float sv = p;
#pragma unroll
    for (int off = 32; off > 0; off >>= 1) sv += __shfl_xor(sv, off);
    if (lane == 0) wred[wid] = sv;
  }
  __syncthreads();
  if (tid == 0) {
    float s = 0.f;
#pragma unroll
    for (int i = 0; i < 5; ++i) s += wred[i];
    sget[1] = 1.0f / s;
  }
  __syncthreads();
  float inv = sget[1];
  float* cm = char_maps + ((size_t)b * T + t) * LP1;
  if (tid <= LS) {
    float al = p * inv;
    a_s[tid] = al;
    cm[tid] = al;
  }
  __syncthreads();

  // ---- ctx[c] = sum_l a[l]*Hl[l][c] + a_eos*eos_emb[c] -> xcat[b][0:512] bf16
  float cacc[8] = {0.f, 0.f, 0.f, 0.f, 0.f, 0.f, 0.f, 0.f};
  const u16* HB = Hl + (size_t)b * LS * CD;
#pragma unroll 4
  for (int l = wid; l < LS; l += 16) {
    float al = a_s[l];
    uint4 rv = *(const uint4*)(HB + (size_t)l * CD + lane * 8);
    float x[8]; unpack8(rv, x);
#pragma unroll
    for (int j = 0; j < 8; ++j) cacc[j] += al * x[j];
  }
  if (wid == 0) {
    float ae = a_s[LS];
#pragma unroll
    for (int j = 0; j < 8; ++j) cacc[j] += ae * eos_emb[lane * 8 + j];
  }
  *(float4*)&cpart[wid][lane * 8]     = make_float4(cacc[0], cacc[1], cacc[2], cacc[3]);
  *(float4*)&cpart[wid][lane * 8 + 4] = make_float4(cacc[4], cacc[5], cacc[6], cacc[7]);
  __syncthreads();
  if (tid < CD) {
    float s = 0.f;
#pragma unroll
    for (int w = 0; w < 16; ++w) s += cpart[w][tid];
    xcat[(size_t)b * KC + tid] = f2b(s);
  }
}

extern "C" void kernel_launch(void* const* d_in, const int* in_sizes, int n_in,
                              void* d_out, int out_size, void* d_ws, size_t ws_size,
                              hipStream_t stream) {
  const float* batch_H = (const float*)d_in[0];
  const float* mask    = (const float*)d_in[1];
  const float* i2h_w   = (const float*)d_in[2];
  const float* h2h_w   = (const float*)d_in[3];
  const float* h2h_b   = (const float*)d_in[4];
  const float* score_w = (const float*)d_in[5];
  const float* w_ih    = (const float*)d_in[6];
  const float* w_hh    = (const float*)d_in[7];
  const float* b_ih    = (const float*)d_in[8];
  const float* b_hh    = (const float*)d_in[9];
  const float* gen_w   = (const float*)d_in[10];
  const float* gen_b   = (const float*)d_in[11];
  const float* eos_emb = (const float*)d_in[12];

  int T = out_size / (BB * (NCLS + LP1));   // 26

  char* p = (char*)d_ws;
  auto alloc = [&](size_t bytes) -> char* {
    char* r = p; p += (bytes + 255) & ~(size_t)255; return r;
  };
  u16*   Hl16  = (u16*)alloc((size_t)BB * LS * CD * 2);
  u8*    Hp8   = (u8*) alloc((size_t)BB * LS * HD);
  u16*   i2h16 = (u16*)alloc((size_t)HD * CD * 2);
  u16*   B16   = (u16*)alloc((size_t)NQ * HD * 2);
  float* bq    = (float*)alloc((size_t)NQ * 4);
  u16*   wcat  = (u16*)alloc((size_t)4 * HD * KC * 2);
  float* bcat  = (float*)alloc((size_t)4 * HD * 4);
  u16*   eos16 = (u16*)alloc((size_t)HD * 2);
  u16*   xcatA = (u16*)alloc((size_t)BB * KC * 2);
  u16*   xcatB = (u16*)alloc((size_t)BB * KC * 2);
  float* qb    = (float*)alloc((size_t)BB * HD * 4);
  float* c0    = (float*)alloc((size_t)BB * HD * 4);
  float* c1    = (float*)alloc((size_t)BB * HD * 4);

  float* logits    = (float*)d_out;
  float* char_maps = logits + (size_t)BB * T * NCLS;

  hipMemsetAsync(c0, 0, (size_t)BB * HD * 4, stream);
  hipMemsetAsync(xcatA, 0, (size_t)BB * KC * 2, stream);

  // prologue
  k_cvt<<<(HD * CD / 4 + 255) / 256, 256, 0, stream>>>(i2h_w, i2h16, HD * CD / 4);
  k_b16<<<(NQ * HD / 4) / 256, 256, 0, stream>>>(h2h_w, gen_w, B16);
  k_bq<<<(NQ + 255) / 256, 256, 0, stream>>>(h2h_b, gen_b, bq);
  k_wcat<<<(4 * HD * KC / 4) / 256, 256, 0, stream>>>(w_ih, w_hh, wcat);
  k_bcat<<<(4 * HD + 255) / 256, 256, 0, stream>>>(b_ih, b_hh, bcat);
  k_eos_p<<<2, 256, 0, stream>>>(i2h_w, eos_emb, eos16);
  k_tr16<<<dim3(CD / 32, LS / 32, BB), 256, 0, stream>>>(batch_H, Hl16);
  k_hp_mfma<<<4 * BB, 512, 0, stream>>>(Hl16, i2h16, Hp8);

  float *cp = c0, *cnb = c1;
  u16 *xcur = xcatA, *xnext = xcatB;
  for (int t = 0; t < T; ++t) {
    k_q<<<144, 256, 0, stream>>>(xcur + CD, B16, bq, qb, logits, t - 1, T);
    k_att<<<BB, 1024, 0, stream>>>(Hp8, eos16, Hl16, qb, score_w,
                                   mask, eos_emb, xcur, char_maps, t, T);
    k_gates<<<512, 256, 0, stream>>>(xcur, wcat, bcat, cp, cnb, xnext);
    float* tmp = cp; cp = cnb; cnb = tmp;
    u16* tx = xcur; xcur = xnext; xnext = tx;
  }
  // final logits from h_T (q output unused)
  k_q<<<144, 256, 0, stream>>>(xcur + CD, B16, bq, qb, logits, T - 1, T);
}

// Round 16
// 1848.728 us; speedup vs baseline: 10.1395x; 1.0258x over previous
//
#include <hip/hip_runtime.h>
#include <math.h>

#define BB   512   // batch
#define CD   512   // channels c
#define HD   512   // hidden
#define LS   256   // spatial keys h*w
#define LP1  257   // keys + EOS
#define NCLS 38    // num classes
#define KC   1024  // concat K = CD + HD
#define NQ   576   // q rows (512) + logits rows (38) padded to 64

typedef unsigned short u16;
typedef unsigned char u8;
typedef __attribute__((ext_vector_type(8))) short short8;
typedef __attribute__((ext_vector_type(4))) float f32x4;
typedef __attribute__((ext_vector_type(2))) float f32x2;

#define LOG2E  1.4426950408889634f
#define LOG2E2 2.8853900817779268f

#if defined(__has_builtin)
#if __has_builtin(__builtin_amdgcn_global_load_lds)
#define HAS_GLL 1
#endif
#endif

__device__ __forceinline__ u16 f2b(float f) {
  union { float f; unsigned u; } v; v.f = f;
  unsigned r = v.u + 0x7fffu + ((v.u >> 16) & 1u);
  return (u16)(r >> 16);
}
__device__ __forceinline__ float b2f(unsigned bits) {
  union { unsigned u; float f; } v; v.u = bits << 16;
  return v.f;
}
__device__ __forceinline__ void unpack8(uint4 r, float* o) {
  o[0] = b2f(r.x & 0xffffu); o[1] = b2f(r.x >> 16);
  o[2] = b2f(r.y & 0xffffu); o[3] = b2f(r.y >> 16);
  o[4] = b2f(r.z & 0xffffu); o[5] = b2f(r.z >> 16);
  o[6] = b2f(r.w & 0xffffu); o[7] = b2f(r.w >> 16);
}
// 8x fp8 e4m3 -> 8x f32 (HW cvt)
__device__ __forceinline__ void unpk8fp8(uint2 r, float* o) {
  f32x2 a = __builtin_amdgcn_cvt_pk_f32_fp8(r.x, false);
  f32x2 b = __builtin_amdgcn_cvt_pk_f32_fp8(r.x, true);
  f32x2 c = __builtin_amdgcn_cvt_pk_f32_fp8(r.y, false);
  f32x2 d = __builtin_amdgcn_cvt_pk_f32_fp8(r.y, true);
  o[0] = a[0]; o[1] = a[1]; o[2] = b[0]; o[3] = b[1];
  o[4] = c[0]; o[5] = c[1]; o[6] = d[0]; o[7] = d[1];
}
__device__ __forceinline__ u8 f2fp8(float f) {
  return (u8)(__builtin_amdgcn_cvt_pk_fp8_f32(f, f, 0u, false) & 0xffu);
}
// fast tanh / sigmoid / exp via native v_exp_f32 (=exp2) / v_rcp_f32.
__device__ __forceinline__ float tanh_f(float x) {
  float t = __builtin_amdgcn_exp2f(x * LOG2E2);     // e^{2x}
  return 1.0f - 2.0f * __builtin_amdgcn_rcpf(t + 1.0f);
}
__device__ __forceinline__ float sigm_f(float x) {
  float t = __builtin_amdgcn_exp2f(-x * LOG2E);     // e^{-x}
  return __builtin_amdgcn_rcpf(1.0f + t);
}
__device__ __forceinline__ float exp_f(float x) {   // e^x
  return __builtin_amdgcn_exp2f(x * LOG2E);
}
// LDS swizzle for BK=32 u16 tiles, 8-elem (16B) chunks (verified: 0 conflicts)
__device__ __forceinline__ int swz(int row, int kchunk) {
  return row * 32 + (((kchunk ^ (row >> 1)) & 3) << 3);
}

// ---------------- f32 -> bf16 elementwise ------------------------------------
__global__ void k_cvt(const float* __restrict__ in, u16* __restrict__ out, int n4) {
  int i = blockIdx.x * 256 + threadIdx.x;
  if (i >= n4) return;
  float4 v = *(const float4*)&in[i * 4];
  ushort4 o;
  o.x = f2b(v.x); o.y = f2b(v.y); o.z = f2b(v.z); o.w = f2b(v.w);
  *(ushort4*)&out[i * 4] = o;
}

// ---------------- B16[576][512] = [h2h_w ; gen_w ; 0] bf16 ---------------------
__global__ void k_b16(const float* __restrict__ h2h_w, const float* __restrict__ gen_w,
                      u16* __restrict__ B16) {
  int idx = blockIdx.x * 256 + threadIdx.x;   // over 576*128
  int n = idx >> 7, k4 = (idx & 127) * 4;
  ushort4 o = {0, 0, 0, 0};
  if (n < HD) {
    float4 v = *(const float4*)&h2h_w[(size_t)n * HD + k4];
    o.x = f2b(v.x); o.y = f2b(v.y); o.z = f2b(v.z); o.w = f2b(v.w);
  } else if (n < HD + NCLS) {
    float4 v = *(const float4*)&gen_w[(size_t)(n - HD) * HD + k4];
    o.x = f2b(v.x); o.y = f2b(v.y); o.z = f2b(v.z); o.w = f2b(v.w);
  }
  *(ushort4*)&B16[(size_t)n * HD + k4] = o;
}
__global__ void k_bq(const float* __restrict__ h2h_b, const float* __restrict__ gen_b,
                     float* __restrict__ bq) {
  int n = blockIdx.x * 256 + threadIdx.x;
  if (n >= NQ) return;
  bq[n] = (n < HD) ? h2h_b[n] : ((n < HD + NCLS) ? gen_b[n - HD] : 0.f);
}

// ---------------- wcat[n][k]: n=4*hh+g -> w_ih/w_hh row (n&3)*512+(n>>2) -------
__global__ void k_wcat(const float* __restrict__ w_ih, const float* __restrict__ w_hh,
                       u16* __restrict__ wcat) {
  int idx = blockIdx.x * 256 + threadIdx.x;
  int n = idx >> 8, kq = idx & 255;
  int k = kq * 4;
  int orig = (n & 3) * HD + (n >> 2);
  const float* src = (k < CD) ? (w_ih + (size_t)orig * CD + k)
                              : (w_hh + (size_t)orig * HD + (k - CD));
  float4 v = *(const float4*)src;
  ushort4 o;
  o.x = f2b(v.x); o.y = f2b(v.y); o.z = f2b(v.z); o.w = f2b(v.w);
  *(ushort4*)&wcat[(size_t)n * KC + k] = o;
}
__global__ void k_bcat(const float* __restrict__ b_ih, const float* __restrict__ b_hh,
                       float* __restrict__ bcat) {
  int n = blockIdx.x * 256 + threadIdx.x;
  if (n >= 4 * HD) return;
  int orig = (n & 3) * HD + (n >> 2);
  bcat[n] = b_ih[orig] + b_hh[orig];
}

// ---------------- batch_H [b][c][l] f32 -> Hl16 [b][l][c] bf16 (once) ----------
__global__ __launch_bounds__(256) void k_tr16(const float* __restrict__ in,
                                              u16* __restrict__ out) {
  __shared__ float Ls[32][36];
  int b = blockIdx.z;
  int c0 = blockIdx.x * 32, l0 = blockIdx.y * 32;
  int tid = threadIdx.x;
  int r = tid >> 3, q4 = (tid & 7) * 4;
  float4 v = *(const float4*)&in[((size_t)b * CD + c0 + r) * LS + l0 + q4];
  Ls[r][q4] = v.x; Ls[r][q4 + 1] = v.y; Ls[r][q4 + 2] = v.z; Ls[r][q4 + 3] = v.w;
  __syncthreads();
  ushort4 o;
  o.x = f2b(Ls[q4 + 0][r]); o.y = f2b(Ls[q4 + 1][r]);
  o.z = f2b(Ls[q4 + 2][r]); o.w = f2b(Ls[q4 + 3][r]);
  *(ushort4*)&out[((size_t)b * LS + l0 + r) * CD + c0 + q4] = o;
}

// ---------------- eos_p[hh] -> bf16 -------------------------------------------
__global__ void k_eos_p(const float* __restrict__ i2h_w, const float* __restrict__ eos_emb,
                        u16* __restrict__ eos_p) {
  int hh = blockIdx.x * blockDim.x + threadIdx.x;
  if (hh >= HD) return;
  const float* row = i2h_w + (size_t)hh * CD;
  float acc = 0.f;
  for (int c = 0; c < CD; ++c) acc += row[c] * eos_emb[c];
  eos_p[hh] = f2b(acc);
}

// ---------------- prologue MFMA: Hp8[b][l][:] = (Hl16[b][l][:] . i2h16^T) fp8 --
// BM=64 (l), BN=512 (all hh -> A fetched once), BK=32; 512 thr = 8 waves.
// Staging via global_load_lds: LINEAR LDS dest (wave base + lane*16), swizzle
// achieved by pre-swizzling the per-lane GLOBAL source chunk (rule #21 /
// m173 pattern). ds_read side unchanged (swz()). R15 run showed only ~5e-3
// absmax (fp8-ctx induced) -> this staging path is numerically sound.
__global__ __launch_bounds__(512) void k_hp_mfma(const u16* __restrict__ A,
                                                 const u16* __restrict__ B,
                                                 u8* __restrict__ Hp) {
  __shared__ u16 As[64 * 32];
  __shared__ u16 Bs[512 * 32];
  int bid = blockIdx.x;
  int z = bid >> 2, m0 = (bid & 3) * 64;
  int tid = threadIdx.x, wid = tid >> 6, lane = tid & 63;
  f32x4 acc[4][4];
#pragma unroll
  for (int i = 0; i < 4; ++i)
#pragma unroll
    for (int j = 0; j < 4; ++j) acc[i][j] = (f32x4){0.f, 0.f, 0.f, 0.f};

  const u16* Az = A + (size_t)z * LS * CD + (size_t)m0 * CD;
  int kc = lane >> 4;
  int ar = lane & 15;
  int bc = wid * 64 + (lane & 15);

#ifdef HAS_GLL
  int arow_g = wid * 16 + (lane >> 2);                    // A rows (wid<4)
  int akc_g  = (lane & 3) ^ ((arow_g >> 1) & 3);
#else
  int arow = tid >> 2, ack = tid & 3;
#endif

  for (int k0 = 0; k0 < CD; k0 += 32) {
#ifdef HAS_GLL
    if (wid < 4) {
      __builtin_amdgcn_global_load_lds(
          (const __attribute__((address_space(1))) void*)(Az + (size_t)arow_g * CD + k0 + akc_g * 8),
          (__attribute__((address_space(3))) void*)&As[wid * 16 * 32],
          16, 0, 0);
    }
#pragma unroll
    for (int g = 0; g < 4; ++g) {
      int r0b  = wid * 64 + g * 16;
      int rowb = r0b + (lane >> 2);
      int kcb  = (lane & 3) ^ ((rowb >> 1) & 3);
      __builtin_amdgcn_global_load_lds(
          (const __attribute__((address_space(1))) void*)(B + (size_t)rowb * CD + k0 + kcb * 8),
          (__attribute__((address_space(3))) void*)&Bs[r0b * 32],
          16, 0, 0);
    }
#else
    if (tid < 256)
      *(uint4*)&As[swz(arow, ack)] = *(const uint4*)&Az[(size_t)arow * CD + k0 + ack * 8];
#pragma unroll
    for (int c = 0; c < 4; ++c)
      *(uint4*)&Bs[swz(tid, c)] = *(const uint4*)&B[(size_t)tid * CD + k0 + c * 8];
#endif
    __syncthreads();
    short8 afr[4], bfr[4];
#pragma unroll
    for (int fm = 0; fm < 4; ++fm) afr[fm] = *(const short8*)&As[swz(ar + fm * 16, kc)];
#pragma unroll
    for (int fn = 0; fn < 4; ++fn) bfr[fn] = *(const short8*)&Bs[swz(bc + fn * 16, kc)];
#pragma unroll
    for (int fm = 0; fm < 4; ++fm)
#pragma unroll
      for (int fn = 0; fn < 4; ++fn)
        acc[fm][fn] = __builtin_amdgcn_mfma_f32_16x16x32_bf16(afr[fm], bfr[fn],
                                                              acc[fm][fn], 0, 0, 0);
    __syncthreads();
  }
  int row0 = m0 + (lane >> 4) * 4;
  int col0 = wid * 64 + (lane & 15);
  u8* Hz = Hp + (size_t)z * LS * HD;
#pragma unroll
  for (int fm = 0; fm < 4; ++fm)
#pragma unroll
    for (int fn = 0; fn < 4; ++fn)
#pragma unroll
      for (int j = 0; j < 4; ++j)
        Hz[(size_t)(row0 + fm * 16 + j) * HD + col0 + fn * 16] = f2fp8(acc[fm][fn][j]);
}

// ---------------- q GEMM: [q | logits] = h16 . [h2h;gen]^T + bias --------------
__global__ __launch_bounds__(256) void k_q(const u16* __restrict__ Ah,
                                           const u16* __restrict__ B16,
                                           const float* __restrict__ bq,
                                           float* __restrict__ qb,
                                           float* __restrict__ logits,
                                           int tprev, int T) {
  __shared__ u16 As[32 * 32];
  __shared__ u16 Bs[64 * 32];
  int bid = blockIdx.x;
  int n0 = (bid >> 4) * 64;
  int m0 = (bid & 15) * 32;
  int tid = threadIdx.x, wid = tid >> 6, lane = tid & 63;
  int wr = wid >> 1, wc = wid & 1;
  f32x4 acc[2];
  acc[0] = (f32x4){0.f, 0.f, 0.f, 0.f};
  acc[1] = (f32x4){0.f, 0.f, 0.f, 0.f};

  int arow = tid >> 2, ack = tid & 3;
  int kc = lane >> 4;
  int ar = wr * 16 + (lane & 15);
  int bc = wc * 32 + (lane & 15);

  uint4 pa, pb;
  if (tid < 128) pa = *(const uint4*)&Ah[(size_t)(m0 + arow) * KC + ack * 8];
  pb = *(const uint4*)&B16[(size_t)(n0 + (arow & 63)) * HD + ack * 8];

  for (int k0 = 0; k0 < HD; k0 += 32) {
    if (tid < 128) *(uint4*)&As[swz(arow, ack)] = pa;
    *(uint4*)&Bs[swz(arow & 63, ack)] = pb;
    __syncthreads();
    int k1 = k0 + 32;
    if (k1 < HD) {
      if (tid < 128) pa = *(const uint4*)&Ah[(size_t)(m0 + arow) * KC + k1 + ack * 8];
      pb = *(const uint4*)&B16[(size_t)(n0 + (arow & 63)) * HD + k1 + ack * 8];
    }
    short8 afr = *(const short8*)&As[swz(ar, kc)];
    short8 bfr0 = *(const short8*)&Bs[swz(bc, kc)];
    short8 bfr1 = *(const short8*)&Bs[swz(bc + 16, kc)];
    acc[0] = __builtin_amdgcn_mfma_f32_16x16x32_bf16(afr, bfr0, acc[0], 0, 0, 0);
    acc[1] = __builtin_amdgcn_mfma_f32_16x16x32_bf16(afr, bfr1, acc[1], 0, 0, 0);
    __syncthreads();
  }

  int col0 = n0 + wc * 32 + (lane & 15);
  int row0 = m0 + wr * 16 + (lane >> 4) * 4;
#pragma unroll
  for (int fn = 0; fn < 2; ++fn) {
    int c = col0 + fn * 16;
    float bv = bq[c];
#pragma unroll
    for (int j = 0; j < 4; ++j) {
      int b = row0 + j;
      float v = acc[fn][j] + bv;
      if (c < HD) qb[(size_t)b * HD + c] = v;
      else if (c < HD + NCLS && tprev >= 0)
        logits[((size_t)b * T + tprev) * NCLS + (c - HD)] = v;
    }
  }
}

// ---------------- gates GEMM + fused LSTM (2-reg prefetch) ---------------------
__global__ __launch_bounds__(256) void k_gates(const u16* __restrict__ xcat,
                                               const u16* __restrict__ wcat,
                                               const float* __restrict__ bcat,
                                               const float* __restrict__ cprev,
                                               float* __restrict__ cnext,
                                               u16* __restrict__ xcat_next) {
  __shared__ u16 As[32 * 32];
  __shared__ u16 Bs[64 * 32];
  __shared__ float Ct[32][68];
  int bid = blockIdx.x;
  int n0 = (bid >> 4) * 64;
  int m0 = (bid & 15) * 32;
  int tid = threadIdx.x, wid = tid >> 6, lane = tid & 63;
  int wr = wid >> 1, wc = wid & 1;
  f32x4 acc[2];
  acc[0] = (f32x4){0.f, 0.f, 0.f, 0.f};
  acc[1] = (f32x4){0.f, 0.f, 0.f, 0.f};

  int arow = tid >> 2, ack = tid & 3;
  int kc = lane >> 4;
  int ar = wr * 16 + (lane & 15);
  int bc = wc * 32 + (lane & 15);

  uint4 pa, pb;
  if (tid < 128) pa = *(const uint4*)&xcat[(size_t)(m0 + arow) * KC + ack * 8];
  pb = *(const uint4*)&wcat[(size_t)(n0 + (arow & 63)) * KC + ack * 8];

  for (int k0 = 0; k0 < KC; k0 += 32) {
    if (tid < 128) *(uint4*)&As[swz(arow, ack)] = pa;
    *(uint4*)&Bs[swz(arow & 63, ack)] = pb;
    __syncthreads();
    int k1 = k0 + 32;
    if (k1 < KC) {
      if (tid < 128) pa = *(const uint4*)&xcat[(size_t)(m0 + arow) * KC + k1 + ack * 8];
      pb = *(const uint4*)&wcat[(size_t)(n0 + (arow & 63)) * KC + k1 + ack * 8];
    }
    short8 afr = *(const short8*)&As[swz(ar, kc)];
    short8 bfr0 = *(const short8*)&Bs[swz(bc, kc)];
    short8 bfr1 = *(const short8*)&Bs[swz(bc + 16, kc)];
    acc[0] = __builtin_amdgcn_mfma_f32_16x16x32_bf16(afr, bfr0, acc[0], 0, 0, 0);
    acc[1] = __builtin_amdgcn_mfma_f32_16x16x32_bf16(afr, bfr1, acc[1], 0, 0, 0);
    __syncthreads();
  }

  int col0 = wc * 32 + (lane & 15);
  int row0 = wr * 16 + (lane >> 4) * 4;
#pragma unroll
  for (int fn = 0; fn < 2; ++fn) {
    float bv = bcat[n0 + col0 + fn * 16];
#pragma unroll
    for (int j = 0; j < 4; ++j)
      Ct[row0 + j][col0 + fn * 16] = acc[fn][j] + bv;
  }
  __syncthreads();

  int hh0 = n0 >> 2;
#pragma unroll
  for (int j = 0; j < 2; ++j) {
    int idx = j * 256 + tid;
    int b_loc = idx >> 4, hh_loc = idx & 15;
    float4 g4 = *(const float4*)&Ct[b_loc][hh_loc * 4];
    int b_g = m0 + b_loc, hh_g = hh0 + hh_loc;
    float cp = cprev[(size_t)b_g * HD + hh_g];
    float si = sigm_f(g4.x);
    float sf = sigm_f(g4.y);
    float so = sigm_f(g4.w);
    float c = sf * cp + si * tanh_f(g4.z);
    float h = so * tanh_f(c);
    cnext[(size_t)b_g * HD + hh_g] = c;
    xcat_next[(size_t)b_g * KC + CD + hh_g] = f2b(h);
  }
}

// ---------------- fused attention: scores -> softmax -> ctx --------------------
__global__ __launch_bounds__(1024) void k_att(
    const u8* __restrict__ Hp, const u16* __restrict__ eos_p,
    const u16* __restrict__ Hl,
    const float* __restrict__ qb, const float* __restrict__ score_w,
    const float* __restrict__ mask, const float* __restrict__ eos_emb,
    u16* __restrict__ xcat, float* __restrict__ char_maps, int t, int T) {
  __shared__ float e_s[260];
  __shared__ float a_s[260];
  __shared__ float cpart[16][520];
  __shared__ float wred[16];
  __shared__ float sget[2];
  int b = blockIdx.x, tid = threadIdx.x;
  int wid = tid >> 6, lane = tid & 63;

  float q_r[8], sw_r[8];
  {
    const float4* q4 = (const float4*)(qb + (size_t)b * HD);
    float4 a0 = q4[lane * 2], a1 = q4[lane * 2 + 1];
    q_r[0] = a0.x; q_r[1] = a0.y; q_r[2] = a0.z; q_r[3] = a0.w;
    q_r[4] = a1.x; q_r[5] = a1.y; q_r[6] = a1.z; q_r[7] = a1.w;
    const float4* s4 = (const float4*)score_w;
    float4 s0 = s4[lane * 2], s1 = s4[lane * 2 + 1];
    sw_r[0] = s0.x; sw_r[1] = s0.y; sw_r[2] = s0.z; sw_r[3] = s0.w;
    sw_r[4] = s1.x; sw_r[5] = s1.y; sw_r[6] = s1.z; sw_r[7] = s1.w;
  }

  // ---- scores: wave per key row (Hp fp8; EOS row bf16)
  const u8* hpB = Hp + (size_t)b * LS * HD;
#pragma unroll 4
  for (int l = wid; l < LP1; l += 16) {
    float x[8];
    if (l < LS) {
      uint2 rv = *(const uint2*)(hpB + (size_t)l * HD + lane * 8);
      unpk8fp8(rv, x);
    } else {
      uint4 rv = *(const uint4*)(eos_p + lane * 8);
      unpack8(rv, x);
    }
    float e = 0.f;
#pragma unroll
    for (int j = 0; j < 8; ++j) e += tanh_f(x[j] + q_r[j]) * sw_r[j];
#pragma unroll
    for (int off = 32; off > 0; off >>= 1) e += __shfl_xor(e, off);
    if (lane == 0) e_s[l] = e;
  }
  __syncthreads();

  // ---- mask + softmax over 257
  float e = -INFINITY;
  if (tid < LS) {
    e = e_s[tid];
    float pm = rintf(1.0f - mask[(size_t)b * LS + tid]);
    if (pm >= 0.5f) e = -INFINITY;
  } else if (tid == LS) {
    e = e_s[LS];
  }
  {
    float mv = e;
#pragma unroll
    for (int off = 32; off > 0; off >>= 1) mv = fmaxf(mv, __shfl_xor(mv, off));
    if (lane == 0) wred[wid] = mv;
  }
  __syncthreads();
  if (tid == 0) {
    float m = wred[0];
#pragma unroll
    for (int i = 1; i < 5; ++i) m = fmaxf(m, wred[i]);
    sget[0] = m;
  }
  __syncthreads();
  float m = sget[0];
  float p = (tid <= LS) ? exp_f(e - m) : 0.f;
  {
    float sv = p;
#pragma unroll
    for (int off = 32; off > 0; off >>= 1) sv += __shfl_xor(sv, off);
    if (lane == 0) wred[wid] = sv;
  }
  __syncthreads();
  if (tid == 0) {
    float s = 0.f;
#pragma unroll
    for (int i = 0; i < 5; ++i) s += wred[i];
    sget[1] = 1.0f / s;
  }
  __syncthreads();
  float inv = sget[1];
  float* cm = char_maps + ((size_t)b * T + t) * LP1;
  if (tid <= LS) {
    float al = p * inv;
    a_s[tid] = al;
    cm[tid] = al;
  }
  __syncthreads();

  // ---- ctx[c] = sum_l a[l]*Hl[l][c] + a_eos*eos_emb[c] -> xcat[b][0:512] bf16
  float cacc[8] = {0.f, 0.f, 0.f, 0.f, 0.f, 0.f, 0.f, 0.f};
  const u16* HB = Hl + (size_t)b * LS * CD;
#pragma unroll 4
  for (int l = wid; l < LS; l += 16) {
    float al = a_s[l];
    uint4 rv = *(const uint4*)(HB + (size_t)l * CD + lane * 8);
    float x[8]; unpack8(rv, x);
#pragma unroll
    for (int j = 0; j < 8; ++j) cacc[j] += al * x[j];
  }
  if (wid == 0) {
    float ae = a_s[LS];
#pragma unroll
    for (int j = 0; j < 8; ++j) cacc[j] += ae * eos_emb[lane * 8 + j];
  }
  *(float4*)&cpart[wid][lane * 8]     = make_float4(cacc[0], cacc[1], cacc[2], cacc[3]);
  *(float4*)&cpart[wid][lane * 8 + 4] = make_float4(cacc[4], cacc[5], cacc[6], cacc[7]);
  __syncthreads();
  if (tid < CD) {
    float s = 0.f;
#pragma unroll
    for (int w = 0; w < 16; ++w) s += cpart[w][tid];
    xcat[(size_t)b * KC + tid] = f2b(s);
  }
}

extern "C" void kernel_launch(void* const* d_in, const int* in_sizes, int n_in,
                              void* d_out, int out_size, void* d_ws, size_t ws_size,
                              hipStream_t stream) {
  const float* batch_H = (const float*)d_in[0];
  const float* mask    = (const float*)d_in[1];
  const float* i2h_w   = (const float*)d_in[2];
  const float* h2h_w   = (const float*)d_in[3];
  const float* h2h_b   = (const float*)d_in[4];
  const float* score_w = (const float*)d_in[5];
  const float* w_ih    = (const float*)d_in[6];
  const float* w_hh    = (const float*)d_in[7];
  const float* b_ih    = (const float*)d_in[8];
  const float* b_hh    = (const float*)d_in[9];
  const float* gen_w   = (const float*)d_in[10];
  const float* gen_b   = (const float*)d_in[11];
  const float* eos_emb = (const float*)d_in[12];

  int T = out_size / (BB * (NCLS + LP1));   // 26

  char* p = (char*)d_ws;
  auto alloc = [&](size_t bytes) -> char* {
    char* r = p; p += (bytes + 255) & ~(size_t)255; return r;
  };
  u16*   Hl16  = (u16*)alloc((size_t)BB * LS * CD * 2);
  u8*    Hp8   = (u8*) alloc((size_t)BB * LS * HD);
  u16*   i2h16 = (u16*)alloc((size_t)HD * CD * 2);
  u16*   B16   = (u16*)alloc((size_t)NQ * HD * 2);
  float* bq    = (float*)alloc((size_t)NQ * 4);
  u16*   wcat  = (u16*)alloc((size_t)4 * HD * KC * 2);
  float* bcat  = (float*)alloc((size_t)4 * HD * 4);
  u16*   eos16 = (u16*)alloc((size_t)HD * 2);
  u16*   xcatA = (u16*)alloc((size_t)BB * KC * 2);
  u16*   xcatB = (u16*)alloc((size_t)BB * KC * 2);
  float* qb    = (float*)alloc((size_t)BB * HD * 4);
  float* c0    = (float*)alloc((size_t)BB * HD * 4);
  float* c1    = (float*)alloc((size_t)BB * HD * 4);

  float* logits    = (float*)d_out;
  float* char_maps = logits + (size_t)BB * T * NCLS;

  hipMemsetAsync(c0, 0, (size_t)BB * HD * 4, stream);
  hipMemsetAsync(xcatA, 0, (size_t)BB * KC * 2, stream);

  // prologue
  k_cvt<<<(HD * CD / 4 + 255) / 256, 256, 0, stream>>>(i2h_w, i2h16, HD * CD / 4);
  k_b16<<<(NQ * HD / 4) / 256, 256, 0, stream>>>(h2h_w, gen_w, B16);
  k_bq<<<(NQ + 255) / 256, 256, 0, stream>>>(h2h_b, gen_b, bq);
  k_wcat<<<(4 * HD * KC / 4) / 256, 256, 0, stream>>>(w_ih, w_hh, wcat);
  k_bcat<<<(4 * HD + 255) / 256, 256, 0, stream>>>(b_ih, b_hh, bcat);
  k_eos_p<<<2, 256, 0, stream>>>(i2h_w, eos_emb, eos16);
  k_tr16<<<dim3(CD / 32, LS / 32, BB), 256, 0, stream>>>(batch_H, Hl16);
  k_hp_mfma<<<4 * BB, 512, 0, stream>>>(Hl16, i2h16, Hp8);

  float *cp = c0, *cnb = c1;
  u16 *xcur = xcatA, *xnext = xcatB;
  for (int t = 0; t < T; ++t) {
    k_q<<<144, 256, 0, stream>>>(xcur + CD, B16, bq, qb, logits, t - 1, T);
    k_att<<<BB, 1024, 0, stream>>>(Hp8, eos16, Hl16, qb, score_w,
                                   mask, eos_emb, xcur, char_maps, t, T);
    k_gates<<<512, 256, 0, stream>>>(xcur, wcat, bcat, cp, cnb, xnext);
    float* tmp = cp; cp = cnb; cnb = tmp;
    u16* tx = xcur; xcur = xnext; xnext = tx;
  }
  // final logits from h_T (q output unused)
  k_q<<<144, 256, 0, stream>>>(xcur + CD, B16, bq, qb, logits, T - 1, T);
}

// Round 17
// 1827.492 us; speedup vs baseline: 10.2573x; 1.0116x over previous
//
#include <hip/hip_runtime.h>
#include <math.h>

#define BB   512   // batch
#define CD   512   // channels c
#define HD   512   // hidden
#define LS   256   // spatial keys h*w
#define LP1  257   // keys + EOS
#define NCLS 38    // num classes
#define KC   1024  // concat K = CD + HD
#define NQ   576   // q rows (512) + logits rows (38) padded to 64

typedef unsigned short u16;
typedef unsigned char u8;
typedef __attribute__((ext_vector_type(8))) short short8;
typedef __attribute__((ext_vector_type(4))) float f32x4;
typedef __attribute__((ext_vector_type(2))) float f32x2;

#define LOG2E  1.4426950408889634f
#define LOG2E2 2.8853900817779268f

#if defined(__has_builtin)
#if __has_builtin(__builtin_amdgcn_global_load_lds)
#define HAS_GLL 1
#endif
#endif

__device__ __forceinline__ u16 f2b(float f) {
  union { float f; unsigned u; } v; v.f = f;
  unsigned r = v.u + 0x7fffu + ((v.u >> 16) & 1u);
  return (u16)(r >> 16);
}
__device__ __forceinline__ float b2f(unsigned bits) {
  union { unsigned u; float f; } v; v.u = bits << 16;
  return v.f;
}
__device__ __forceinline__ void unpack8(uint4 r, float* o) {
  o[0] = b2f(r.x & 0xffffu); o[1] = b2f(r.x >> 16);
  o[2] = b2f(r.y & 0xffffu); o[3] = b2f(r.y >> 16);
  o[4] = b2f(r.z & 0xffffu); o[5] = b2f(r.z >> 16);
  o[6] = b2f(r.w & 0xffffu); o[7] = b2f(r.w >> 16);
}
// 8x fp8 e4m3 -> 8x f32 (HW cvt)
__device__ __forceinline__ void unpk8fp8(uint2 r, float* o) {
  f32x2 a = __builtin_amdgcn_cvt_pk_f32_fp8(r.x, false);
  f32x2 b = __builtin_amdgcn_cvt_pk_f32_fp8(r.x, true);
  f32x2 c = __builtin_amdgcn_cvt_pk_f32_fp8(r.y, false);
  f32x2 d = __builtin_amdgcn_cvt_pk_f32_fp8(r.y, true);
  o[0] = a[0]; o[1] = a[1]; o[2] = b[0]; o[3] = b[1];
  o[4] = c[0]; o[5] = c[1]; o[6] = d[0]; o[7] = d[1];
}
__device__ __forceinline__ u8 f2fp8(float f) {
  return (u8)(__builtin_amdgcn_cvt_pk_fp8_f32(f, f, 0u, false) & 0xffu);
}
// fast tanh / sigmoid / exp via native v_exp_f32 (=exp2) / v_rcp_f32.
__device__ __forceinline__ float tanh_f(float x) {
  float t = __builtin_amdgcn_exp2f(x * LOG2E2);     // e^{2x}
  return 1.0f - 2.0f * __builtin_amdgcn_rcpf(t + 1.0f);
}
__device__ __forceinline__ float sigm_f(float x) {
  float t = __builtin_amdgcn_exp2f(-x * LOG2E);     // e^{-x}
  return __builtin_amdgcn_rcpf(1.0f + t);
}
__device__ __forceinline__ float exp_f(float x) {   // e^x
  return __builtin_amdgcn_exp2f(x * LOG2E);
}
// LDS swizzle for BK=32 u16 tiles, 8-elem (16B) chunks (verified: 0 conflicts)
__device__ __forceinline__ int swz(int row, int kchunk) {
  return row * 32 + (((kchunk ^ (row >> 1)) & 3) << 3);
}

// ---------------- f32 -> bf16 elementwise ------------------------------------
__global__ void k_cvt(const float* __restrict__ in, u16* __restrict__ out, int n4) {
  int i = blockIdx.x * 256 + threadIdx.x;
  if (i >= n4) return;
  float4 v = *(const float4*)&in[i * 4];
  ushort4 o;
  o.x = f2b(v.x); o.y = f2b(v.y); o.z = f2b(v.z); o.w = f2b(v.w);
  *(ushort4*)&out[i * 4] = o;
}

// ---------------- B16[576][512] = [h2h_w ; gen_w ; 0] bf16 ---------------------
__global__ void k_b16(const float* __restrict__ h2h_w, const float* __restrict__ gen_w,
                      u16* __restrict__ B16) {
  int idx = blockIdx.x * 256 + threadIdx.x;   // over 576*128
  int n = idx >> 7, k4 = (idx & 127) * 4;
  ushort4 o = {0, 0, 0, 0};
  if (n < HD) {
    float4 v = *(const float4*)&h2h_w[(size_t)n * HD + k4];
    o.x = f2b(v.x); o.y = f2b(v.y); o.z = f2b(v.z); o.w = f2b(v.w);
  } else if (n < HD + NCLS) {
    float4 v = *(const float4*)&gen_w[(size_t)(n - HD) * HD + k4];
    o.x = f2b(v.x); o.y = f2b(v.y); o.z = f2b(v.z); o.w = f2b(v.w);
  }
  *(ushort4*)&B16[(size_t)n * HD + k4] = o;
}
__global__ void k_bq(const float* __restrict__ h2h_b, const float* __restrict__ gen_b,
                     float* __restrict__ bq) {
  int n = blockIdx.x * 256 + threadIdx.x;
  if (n >= NQ) return;
  bq[n] = (n < HD) ? h2h_b[n] : ((n < HD + NCLS) ? gen_b[n - HD] : 0.f);
}

// ---------------- wcat[n][k]: n=4*hh+g -> w_ih/w_hh row (n&3)*512+(n>>2) -------
__global__ void k_wcat(const float* __restrict__ w_ih, const float* __restrict__ w_hh,
                       u16* __restrict__ wcat) {
  int idx = blockIdx.x * 256 + threadIdx.x;
  int n = idx >> 8, kq = idx & 255;
  int k = kq * 4;
  int orig = (n & 3) * HD + (n >> 2);
  const float* src = (k < CD) ? (w_ih + (size_t)orig * CD + k)
                              : (w_hh + (size_t)orig * HD + (k - CD));
  float4 v = *(const float4*)src;
  ushort4 o;
  o.x = f2b(v.x); o.y = f2b(v.y); o.z = f2b(v.z); o.w = f2b(v.w);
  *(ushort4*)&wcat[(size_t)n * KC + k] = o;
}
__global__ void k_bcat(const float* __restrict__ b_ih, const float* __restrict__ b_hh,
                       float* __restrict__ bcat) {
  int n = blockIdx.x * 256 + threadIdx.x;
  if (n >= 4 * HD) return;
  int orig = (n & 3) * HD + (n >> 2);
  bcat[n] = b_ih[orig] + b_hh[orig];
}

// ---------------- batch_H [b][c][l] f32 -> Hl16 [b][l][c] bf16 (once) ----------
__global__ __launch_bounds__(256) void k_tr16(const float* __restrict__ in,
                                              u16* __restrict__ out) {
  __shared__ float Ls[32][36];
  int b = blockIdx.z;
  int c0 = blockIdx.x * 32, l0 = blockIdx.y * 32;
  int tid = threadIdx.x;
  int r = tid >> 3, q4 = (tid & 7) * 4;
  float4 v = *(const float4*)&in[((size_t)b * CD + c0 + r) * LS + l0 + q4];
  Ls[r][q4] = v.x; Ls[r][q4 + 1] = v.y; Ls[r][q4 + 2] = v.z; Ls[r][q4 + 3] = v.w;
  __syncthreads();
  ushort4 o;
  o.x = f2b(Ls[q4 + 0][r]); o.y = f2b(Ls[q4 + 1][r]);
  o.z = f2b(Ls[q4 + 2][r]); o.w = f2b(Ls[q4 + 3][r]);
  *(ushort4*)&out[((size_t)b * LS + l0 + r) * CD + c0 + q4] = o;
}

// ---------------- eos_p[hh] -> bf16 -------------------------------------------
__global__ void k_eos_p(const float* __restrict__ i2h_w, const float* __restrict__ eos_emb,
                        u16* __restrict__ eos_p) {
  int hh = blockIdx.x * blockDim.x + threadIdx.x;
  if (hh >= HD) return;
  const float* row = i2h_w + (size_t)hh * CD;
  float acc = 0.f;
  for (int c = 0; c < CD; ++c) acc += row[c] * eos_emb[c];
  eos_p[hh] = f2b(acc);
}

// ---------------- prologue MFMA: Hp8[b][l][:] = (Hl16[b][l][:] . i2h16^T) fp8 --
// BM=64 (l), BN=512 (all hh), BK=32; 512 thr = 8 waves; gload_lds staging with
// linear LDS dest + pre-swizzled global source (rule #21). R16: -48us vs R12.
__global__ __launch_bounds__(512) void k_hp_mfma(const u16* __restrict__ A,
                                                 const u16* __restrict__ B,
                                                 u8* __restrict__ Hp) {
  __shared__ u16 As[64 * 32];
  __shared__ u16 Bs[512 * 32];
  int bid = blockIdx.x;
  int z = bid >> 2, m0 = (bid & 3) * 64;
  int tid = threadIdx.x, wid = tid >> 6, lane = tid & 63;
  f32x4 acc[4][4];
#pragma unroll
  for (int i = 0; i < 4; ++i)
#pragma unroll
    for (int j = 0; j < 4; ++j) acc[i][j] = (f32x4){0.f, 0.f, 0.f, 0.f};

  const u16* Az = A + (size_t)z * LS * CD + (size_t)m0 * CD;
  int kc = lane >> 4;
  int ar = lane & 15;
  int bc = wid * 64 + (lane & 15);

#ifdef HAS_GLL
  int arow_g = wid * 16 + (lane >> 2);                    // A rows (wid<4)
  int akc_g  = (lane & 3) ^ ((arow_g >> 1) & 3);
#else
  int arow = tid >> 2, ack = tid & 3;
#endif

  for (int k0 = 0; k0 < CD; k0 += 32) {
#ifdef HAS_GLL
    if (wid < 4) {
      __builtin_amdgcn_global_load_lds(
          (const __attribute__((address_space(1))) void*)(Az + (size_t)arow_g * CD + k0 + akc_g * 8),
          (__attribute__((address_space(3))) void*)&As[wid * 16 * 32],
          16, 0, 0);
    }
#pragma unroll
    for (int g = 0; g < 4; ++g) {
      int r0b  = wid * 64 + g * 16;
      int rowb = r0b + (lane >> 2);
      int kcb  = (lane & 3) ^ ((rowb >> 1) & 3);
      __builtin_amdgcn_global_load_lds(
          (const __attribute__((address_space(1))) void*)(B + (size_t)rowb * CD + k0 + kcb * 8),
          (__attribute__((address_space(3))) void*)&Bs[r0b * 32],
          16, 0, 0);
    }
#else
    if (tid < 256)
      *(uint4*)&As[swz(arow, ack)] = *(const uint4*)&Az[(size_t)arow * CD + k0 + ack * 8];
#pragma unroll
    for (int c = 0; c < 4; ++c)
      *(uint4*)&Bs[swz(tid, c)] = *(const uint4*)&B[(size_t)tid * CD + k0 + c * 8];
#endif
    __syncthreads();
    short8 afr[4], bfr[4];
#pragma unroll
    for (int fm = 0; fm < 4; ++fm) afr[fm] = *(const short8*)&As[swz(ar + fm * 16, kc)];
#pragma unroll
    for (int fn = 0; fn < 4; ++fn) bfr[fn] = *(const short8*)&Bs[swz(bc + fn * 16, kc)];
#pragma unroll
    for (int fm = 0; fm < 4; ++fm)
#pragma unroll
      for (int fn = 0; fn < 4; ++fn)
        acc[fm][fn] = __builtin_amdgcn_mfma_f32_16x16x32_bf16(afr[fm], bfr[fn],
                                                              acc[fm][fn], 0, 0, 0);
    __syncthreads();
  }
  int row0 = m0 + (lane >> 4) * 4;
  int col0 = wid * 64 + (lane & 15);
  u8* Hz = Hp + (size_t)z * LS * HD;
#pragma unroll
  for (int fm = 0; fm < 4; ++fm)
#pragma unroll
    for (int fn = 0; fn < 4; ++fn)
#pragma unroll
      for (int j = 0; j < 4; ++j)
        Hz[(size_t)(row0 + fm * 16 + j) * HD + col0 + fn * 16] = f2fp8(acc[fm][fn][j]);
}

// ---------------- q GEMM: 32x32 tiles, grid 288 (18n x 16m) --------------------
// waves 0-1 stage A (rows of h), waves 2-3 stage B; 2x2 waves of 16x16 MFMA.
__global__ __launch_bounds__(256) void k_q(const u16* __restrict__ Ah,
                                           const u16* __restrict__ B16,
                                           const float* __restrict__ bq,
                                           float* __restrict__ qb,
                                           float* __restrict__ logits,
                                           int tprev, int T) {
  __shared__ u16 As[32 * 32];
  __shared__ u16 Bs[32 * 32];
  int bid = blockIdx.x;
  int n0 = (bid >> 4) * 32;
  int m0 = (bid & 15) * 32;
  int tid = threadIdx.x, wid = tid >> 6, lane = tid & 63;
  int wr = wid >> 1, wc = wid & 1;
  f32x4 acc = (f32x4){0.f, 0.f, 0.f, 0.f};

  int t2 = tid & 127;
  int srow = t2 >> 2, sck = t2 & 3;
  bool isA = tid < 128;
  int kc = lane >> 4;
  int ar = wr * 16 + (lane & 15);
  int bc = wc * 16 + (lane & 15);

  uint4 pv;
  if (isA) pv = *(const uint4*)&Ah[(size_t)(m0 + srow) * KC + sck * 8];
  else     pv = *(const uint4*)&B16[(size_t)(n0 + srow) * HD + sck * 8];

  for (int k0 = 0; k0 < HD; k0 += 32) {
    if (isA) *(uint4*)&As[swz(srow, sck)] = pv;
    else     *(uint4*)&Bs[swz(srow, sck)] = pv;
    __syncthreads();
    int k1 = k0 + 32;
    if (k1 < HD) {
      if (isA) pv = *(const uint4*)&Ah[(size_t)(m0 + srow) * KC + k1 + sck * 8];
      else     pv = *(const uint4*)&B16[(size_t)(n0 + srow) * HD + k1 + sck * 8];
    }
    short8 afr = *(const short8*)&As[swz(ar, kc)];
    short8 bfr = *(const short8*)&Bs[swz(bc, kc)];
    acc = __builtin_amdgcn_mfma_f32_16x16x32_bf16(afr, bfr, acc, 0, 0, 0);
    __syncthreads();
  }

  int c = n0 + wc * 16 + (lane & 15);
  int row0 = m0 + wr * 16 + (lane >> 4) * 4;
  float bv = bq[c];
#pragma unroll
  for (int j = 0; j < 4; ++j) {
    int b = row0 + j;
    float v = acc[j] + bv;
    if (c < HD) qb[(size_t)b * HD + c] = v;
    else if (c < HD + NCLS && tprev >= 0)
      logits[((size_t)b * T + tprev) * NCLS + (c - HD)] = v;
  }
}

// ---------------- gates GEMM + fused LSTM: 32x32 tiles, grid 1024 --------------
__global__ __launch_bounds__(256) void k_gates(const u16* __restrict__ xcat,
                                               const u16* __restrict__ wcat,
                                               const float* __restrict__ bcat,
                                               const float* __restrict__ cprev,
                                               float* __restrict__ cnext,
                                               u16* __restrict__ xcat_next) {
  __shared__ u16 As[32 * 32];
  __shared__ u16 Bs[32 * 32];
  __shared__ float Ct[32][36];
  int bid = blockIdx.x;
  int n0 = (bid >> 4) * 32;
  int m0 = (bid & 15) * 32;
  int tid = threadIdx.x, wid = tid >> 6, lane = tid & 63;
  int wr = wid >> 1, wc = wid & 1;
  f32x4 acc = (f32x4){0.f, 0.f, 0.f, 0.f};

  int t2 = tid & 127;
  int srow = t2 >> 2, sck = t2 & 3;
  bool isA = tid < 128;
  int kc = lane >> 4;
  int ar = wr * 16 + (lane & 15);
  int bc = wc * 16 + (lane & 15);

  uint4 pv;
  if (isA) pv = *(const uint4*)&xcat[(size_t)(m0 + srow) * KC + sck * 8];
  else     pv = *(const uint4*)&wcat[(size_t)(n0 + srow) * KC + sck * 8];

  for (int k0 = 0; k0 < KC; k0 += 32) {
    if (isA) *(uint4*)&As[swz(srow, sck)] = pv;
    else     *(uint4*)&Bs[swz(srow, sck)] = pv;
    __syncthreads();
    int k1 = k0 + 32;
    if (k1 < KC) {
      if (isA) pv = *(const uint4*)&xcat[(size_t)(m0 + srow) * KC + k1 + sck * 8];
      else     pv = *(const uint4*)&wcat[(size_t)(n0 + srow) * KC + k1 + sck * 8];
    }
    short8 afr = *(const short8*)&As[swz(ar, kc)];
    short8 bfr = *(const short8*)&Bs[swz(bc, kc)];
    acc = __builtin_amdgcn_mfma_f32_16x16x32_bf16(afr, bfr, acc, 0, 0, 0);
    __syncthreads();
  }

  int col0 = wc * 16 + (lane & 15);
  int row0 = wr * 16 + (lane >> 4) * 4;
  {
    float bv = bcat[n0 + col0];
#pragma unroll
    for (int j = 0; j < 4; ++j)
      Ct[row0 + j][col0] = acc[j] + bv;
  }
  __syncthreads();

  // fused LSTM: 32 b x 8 hh = 256 items; gates i,f,g,o contiguous per hh
  int hh0 = n0 >> 2;
  int b_loc = tid >> 3, hh_loc = tid & 7;
  float4 g4 = *(const float4*)&Ct[b_loc][hh_loc * 4];
  int b_g = m0 + b_loc, hh_g = hh0 + hh_loc;
  float cp = cprev[(size_t)b_g * HD + hh_g];
  float si = sigm_f(g4.x);
  float sf = sigm_f(g4.y);
  float so = sigm_f(g4.w);
  float c = sf * cp + si * tanh_f(g4.z);
  float h = so * tanh_f(c);
  cnext[(size_t)b_g * HD + hh_g] = c;
  xcat_next[(size_t)b_g * KC + CD + hh_g] = f2b(h);
}

// ---------------- fused attention: scores -> softmax -> ctx --------------------
__global__ __launch_bounds__(1024) void k_att(
    const u8* __restrict__ Hp, const u16* __restrict__ eos_p,
    const u16* __restrict__ Hl,
    const float* __restrict__ qb, const float* __restrict__ score_w,
    const float* __restrict__ mask, const float* __restrict__ eos_emb,
    u16* __restrict__ xcat, float* __restrict__ char_maps, int t, int T) {
  __shared__ float e_s[260];
  __shared__ float a_s[260];
  __shared__ float cpart[16][520];
  __shared__ float wred[16];
  __shared__ float sget[2];
  int b = blockIdx.x, tid = threadIdx.x;
  int wid = tid >> 6, lane = tid & 63;

  float q_r[8], sw_r[8];
  {
    const float4* q4 = (const float4*)(qb + (size_t)b * HD);
    float4 a0 = q4[lane * 2], a1 = q4[lane * 2 + 1];
    q_r[0] = a0.x; q_r[1] = a0.y; q_r[2] = a0.z; q_r[3] = a0.w;
    q_r[4] = a1.x; q_r[5] = a1.y; q_r[6] = a1.z; q_r[7] = a1.w;
    const float4* s4 = (const float4*)score_w;
    float4 s0 = s4[lane * 2], s1 = s4[lane * 2 + 1];
    sw_r[0] = s0.x; sw_r[1] = s0.y; sw_r[2] = s0.z; sw_r[3] = s0.w;
    sw_r[4] = s1.x; sw_r[5] = s1.y; sw_r[6] = s1.z; sw_r[7] = s1.w;
  }

  // ---- scores: wave per key row (Hp fp8; EOS row bf16)
  const u8* hpB = Hp + (size_t)b * LS * HD;
#pragma unroll 4
  for (int l = wid; l < LP1; l += 16) {
    float x[8];
    if (l < LS) {
      uint2 rv = *(const uint2*)(hpB + (size_t)l * HD + lane * 8);
      unpk8fp8(rv, x);
    } else {
      uint4 rv = *(const uint4*)(eos_p + lane * 8);
      unpack8(rv, x);
    }
    float e = 0.f;
#pragma unroll
    for (int j = 0; j < 8; ++j) e += tanh_f(x[j] + q_r[j]) * sw_r[j];
#pragma unroll
    for (int off = 32; off > 0; off >>= 1) e += __shfl_xor(e, off);
    if (lane == 0) e_s[l] = e;
  }
  __syncthreads();

  // ---- mask + softmax over 257
  float e = -INFINITY;
  if (tid < LS) {
    e = e_s[tid];
    float pm = rintf(1.0f - mask[(size_t)b * LS + tid]);
    if (pm >= 0.5f) e = -INFINITY;
  } else if (tid == LS) {
    e = e_s[LS];
  }
  {
    float mv = e;
#pragma unroll
    for (int off = 32; off > 0; off >>= 1) mv = fmaxf(mv, __shfl_xor(mv, off));
    if (lane == 0) wred[wid] = mv;
  }
  __syncthreads();
  if (tid == 0) {
    float m = wred[0];
#pragma unroll
    for (int i = 1; i < 5; ++i) m = fmaxf(m, wred[i]);
    sget[0] = m;
  }
  __syncthreads();
  float m = sget[0];
  float p = (tid <= LS) ? exp_f(e - m) : 0.f;
  {
    float sv = p;
#pragma unroll
    for (int off = 32; off > 0; off >>= 1) sv += __shfl_xor(sv, off);
    if (lane == 0) wred[wid] = sv;
  }
  __syncthreads();
  if (tid == 0) {
    float s = 0.f;
#pragma unroll
    for (int i = 0; i < 5; ++i) s += wred[i];
    sget[1] = 1.0f / s;
  }
  __syncthreads();
  float inv = sget[1];
  float* cm = char_maps + ((size_t)b * T + t) * LP1;
  if (tid <= LS) {
    float al = p * inv;
    a_s[tid] = al;
    cm[tid] = al;
  }
  __syncthreads();

  // ---- ctx[c] = sum_l a[l]*Hl[l][c] + a_eos*eos_emb[c] -> xcat[b][0:512] bf16
  float cacc[8] = {0.f, 0.f, 0.f, 0.f, 0.f, 0.f, 0.f, 0.f};
  const u16* HB = Hl + (size_t)b * LS * CD;
#pragma unroll 4
  for (int l = wid; l < LS; l += 16) {
    float al = a_s[l];
    uint4 rv = *(const uint4*)(HB + (size_t)l * CD + lane * 8);
    float x[8]; unpack8(rv, x);
#pragma unroll
    for (int j = 0; j < 8; ++j) cacc[j] += al * x[j];
  }
  if (wid == 0) {
    float ae = a_s[LS];
#pragma unroll
    for (int j = 0; j < 8; ++j) cacc[j] += ae * eos_emb[lane * 8 + j];
  }
  *(float4*)&cpart[wid][lane * 8]     = make_float4(cacc[0], cacc[1], cacc[2], cacc[3]);
  *(float4*)&cpart[wid][lane * 8 + 4] = make_float4(cacc[4], cacc[5], cacc[6], cacc[7]);
  __syncthreads();
  if (tid < CD) {
    float s = 0.f;
#pragma unroll
    for (int w = 0; w < 16; ++w) s += cpart[w][tid];
    xcat[(size_t)b * KC + tid] = f2b(s);
  }
}

extern "C" void kernel_launch(void* const* d_in, const int* in_sizes, int n_in,
                              void* d_out, int out_size, void* d_ws, size_t ws_size,
                              hipStream_t stream) {
  const float* batch_H = (const float*)d_in[0];
  const float* mask    = (const float*)d_in[1];
  const float* i2h_w   = (const float*)d_in[2];
  const float* h2h_w   = (const float*)d_in[3];
  const float* h2h_b   = (const float*)d_in[4];
  const float* score_w = (const float*)d_in[5];
  const float* w_ih    = (const float*)d_in[6];
  const float* w_hh    = (const float*)d_in[7];
  const float* b_ih    = (const float*)d_in[8];
  const float* b_hh    = (const float*)d_in[9];
  const float* gen_w   = (const float*)d_in[10];
  const float* gen_b   = (const float*)d_in[11];
  const float* eos_emb = (const float*)d_in[12];

  int T = out_size / (BB * (NCLS + LP1));   // 26

  char* p = (char*)d_ws;
  auto alloc = [&](size_t bytes) -> char* {
    char* r = p; p += (bytes + 255) & ~(size_t)255; return r;
  };
  u16*   Hl16  = (u16*)alloc((size_t)BB * LS * CD * 2);
  u8*    Hp8   = (u8*) alloc((size_t)BB * LS * HD);
  u16*   i2h16 = (u16*)alloc((size_t)HD * CD * 2);
  u16*   B16   = (u16*)alloc((size_t)NQ * HD * 2);
  float* bq    = (float*)alloc((size_t)NQ * 4);
  u16*   wcat  = (u16*)alloc((size_t)4 * HD * KC * 2);
  float* bcat  = (float*)alloc((size_t)4 * HD * 4);
  u16*   eos16 = (u16*)alloc((size_t)HD * 2);
  u16*   xcatA = (u16*)alloc((size_t)BB * KC * 2);
  u16*   xcatB = (u16*)alloc((size_t)BB * KC * 2);
  float* qb    = (float*)alloc((size_t)BB * HD * 4);
  float* c0    = (float*)alloc((size_t)BB * HD * 4);
  float* c1    = (float*)alloc((size_t)BB * HD * 4);

  float* logits    = (float*)d_out;
  float* char_maps = logits + (size_t)BB * T * NCLS;

  hipMemsetAsync(c0, 0, (size_t)BB * HD * 4, stream);
  hipMemsetAsync(xcatA, 0, (size_t)BB * KC * 2, stream);

  // prologue
  k_cvt<<<(HD * CD / 4 + 255) / 256, 256, 0, stream>>>(i2h_w, i2h16, HD * CD / 4);
  k_b16<<<(NQ * HD / 4) / 256, 256, 0, stream>>>(h2h_w, gen_w, B16);
  k_bq<<<(NQ + 255) / 256, 256, 0, stream>>>(h2h_b, gen_b, bq);
  k_wcat<<<(4 * HD * KC / 4) / 256, 256, 0, stream>>>(w_ih, w_hh, wcat);
  k_bcat<<<(4 * HD + 255) / 256, 256, 0, stream>>>(b_ih, b_hh, bcat);
  k_eos_p<<<2, 256, 0, stream>>>(i2h_w, eos_emb, eos16);
  k_tr16<<<dim3(CD / 32, LS / 32, BB), 256, 0, stream>>>(batch_H, Hl16);
  k_hp_mfma<<<4 * BB, 512, 0, stream>>>(Hl16, i2h16, Hp8);

  float *cp = c0, *cnb = c1;
  u16 *xcur = xcatA, *xnext = xcatB;
  for (int t = 0; t < T; ++t) {
    k_q<<<288, 256, 0, stream>>>(xcur + CD, B16, bq, qb, logits, t - 1, T);
    k_att<<<BB, 1024, 0, stream>>>(Hp8, eos16, Hl16, qb, score_w,
                                   mask, eos_emb, xcur, char_maps, t, T);
    k_gates<<<1024, 256, 0, stream>>>(xcur, wcat, bcat, cp, cnb, xnext);
    float* tmp = cp; cp = cnb; cnb = tmp;
    u16* tx = xcur; xcur = xnext; xnext = tx;
  }
  // final logits from h_T (q output unused)
  k_q<<<288, 256, 0, stream>>>(xcur + CD, B16, bq, qb, logits, T - 1, T);
}

// Round 18
// 1816.796 us; speedup vs baseline: 10.3177x; 1.0059x over previous
//
#include <hip/hip_runtime.h>
#include <math.h>

#define BB   512   // batch
#define CD   512   // channels c
#define HD   512   // hidden
#define LS   256   // spatial keys h*w
#define LP1  257   // keys + EOS
#define NCLS 38    // num classes
#define KC   1024  // concat K = CD + HD
#define NQ   576   // q rows (512) + logits rows (38) padded to 64

typedef unsigned short u16;
typedef unsigned char u8;
typedef __attribute__((ext_vector_type(8))) short short8;
typedef __attribute__((ext_vector_type(4))) float f32x4;
typedef __attribute__((ext_vector_type(2))) float f32x2;

#define LOG2E  1.4426950408889634f
#define LOG2E2 2.8853900817779268f

#if defined(__has_builtin)
#if __has_builtin(__builtin_amdgcn_global_load_lds)
#define HAS_GLL 1
#endif
#endif

__device__ __forceinline__ u16 f2b(float f) {
  union { float f; unsigned u; } v; v.f = f;
  unsigned r = v.u + 0x7fffu + ((v.u >> 16) & 1u);
  return (u16)(r >> 16);
}
__device__ __forceinline__ float b2f(unsigned bits) {
  union { unsigned u; float f; } v; v.u = bits << 16;
  return v.f;
}
__device__ __forceinline__ void unpack8(uint4 r, float* o) {
  o[0] = b2f(r.x & 0xffffu); o[1] = b2f(r.x >> 16);
  o[2] = b2f(r.y & 0xffffu); o[3] = b2f(r.y >> 16);
  o[4] = b2f(r.z & 0xffffu); o[5] = b2f(r.z >> 16);
  o[6] = b2f(r.w & 0xffffu); o[7] = b2f(r.w >> 16);
}
// 8x fp8 e4m3 -> 8x f32 (HW cvt)
__device__ __forceinline__ void unpk8fp8(uint2 r, float* o) {
  f32x2 a = __builtin_amdgcn_cvt_pk_f32_fp8(r.x, false);
  f32x2 b = __builtin_amdgcn_cvt_pk_f32_fp8(r.x, true);
  f32x2 c = __builtin_amdgcn_cvt_pk_f32_fp8(r.y, false);
  f32x2 d = __builtin_amdgcn_cvt_pk_f32_fp8(r.y, true);
  o[0] = a[0]; o[1] = a[1]; o[2] = b[0]; o[3] = b[1];
  o[4] = c[0]; o[5] = c[1]; o[6] = d[0]; o[7] = d[1];
}
__device__ __forceinline__ u8 f2fp8(float f) {
  return (u8)(__builtin_amdgcn_cvt_pk_fp8_f32(f, f, 0u, false) & 0xffu);
}
// fast tanh / sigmoid / exp via native v_exp_f32 (=exp2) / v_rcp_f32.
__device__ __forceinline__ float tanh_f(float x) {
  float t = __builtin_amdgcn_exp2f(x * LOG2E2);     // e^{2x}
  return 1.0f - 2.0f * __builtin_amdgcn_rcpf(t + 1.0f);
}
__device__ __forceinline__ float sigm_f(float x) {
  float t = __builtin_amdgcn_exp2f(-x * LOG2E);     // e^{-x}
  return __builtin_amdgcn_rcpf(1.0f + t);
}
__device__ __forceinline__ float exp_f(float x) {   // e^x
  return __builtin_amdgcn_exp2f(x * LOG2E);
}
// LDS swizzle for BK=32 u16 tiles, 8-elem (16B) chunks (verified: 0 conflicts)
__device__ __forceinline__ int swz(int row, int kchunk) {
  return row * 32 + (((kchunk ^ (row >> 1)) & 3) << 3);
}

// ---------------- f32 -> bf16 elementwise ------------------------------------
__global__ void k_cvt(const float* __restrict__ in, u16* __restrict__ out, int n4) {
  int i = blockIdx.x * 256 + threadIdx.x;
  if (i >= n4) return;
  float4 v = *(const float4*)&in[i * 4];
  ushort4 o;
  o.x = f2b(v.x); o.y = f2b(v.y); o.z = f2b(v.z); o.w = f2b(v.w);
  *(ushort4*)&out[i * 4] = o;
}

// ---------------- B16[576][512] = [h2h_w ; gen_w ; 0] bf16 ---------------------
__global__ void k_b16(const float* __restrict__ h2h_w, const float* __restrict__ gen_w,
                      u16* __restrict__ B16) {
  int idx = blockIdx.x * 256 + threadIdx.x;   // over 576*128
  int n = idx >> 7, k4 = (idx & 127) * 4;
  ushort4 o = {0, 0, 0, 0};
  if (n < HD) {
    float4 v = *(const float4*)&h2h_w[(size_t)n * HD + k4];
    o.x = f2b(v.x); o.y = f2b(v.y); o.z = f2b(v.z); o.w = f2b(v.w);
  } else if (n < HD + NCLS) {
    float4 v = *(const float4*)&gen_w[(size_t)(n - HD) * HD + k4];
    o.x = f2b(v.x); o.y = f2b(v.y); o.z = f2b(v.z); o.w = f2b(v.w);
  }
  *(ushort4*)&B16[(size_t)n * HD + k4] = o;
}
__global__ void k_bq(const float* __restrict__ h2h_b, const float* __restrict__ gen_b,
                     float* __restrict__ bq) {
  int n = blockIdx.x * 256 + threadIdx.x;
  if (n >= NQ) return;
  bq[n] = (n < HD) ? h2h_b[n] : ((n < HD + NCLS) ? gen_b[n - HD] : 0.f);
}

// ---------------- wcat[n][k]: n=4*hh+g -> w_ih/w_hh row (n&3)*512+(n>>2) -------
__global__ void k_wcat(const float* __restrict__ w_ih, const float* __restrict__ w_hh,
                       u16* __restrict__ wcat) {
  int idx = blockIdx.x * 256 + threadIdx.x;
  int n = idx >> 8, kq = idx & 255;
  int k = kq * 4;
  int orig = (n & 3) * HD + (n >> 2);
  const float* src = (k < CD) ? (w_ih + (size_t)orig * CD + k)
                              : (w_hh + (size_t)orig * HD + (k - CD));
  float4 v = *(const float4*)src;
  ushort4 o;
  o.x = f2b(v.x); o.y = f2b(v.y); o.z = f2b(v.z); o.w = f2b(v.w);
  *(ushort4*)&wcat[(size_t)n * KC + k] = o;
}
__global__ void k_bcat(const float* __restrict__ b_ih, const float* __restrict__ b_hh,
                       float* __restrict__ bcat) {
  int n = blockIdx.x * 256 + threadIdx.x;
  if (n >= 4 * HD) return;
  int orig = (n & 3) * HD + (n >> 2);
  bcat[n] = b_ih[orig] + b_hh[orig];
}

// ---------------- batch_H [b][c][l] f32 -> Hl16 [b][l][c] bf16 (once) ----------
__global__ __launch_bounds__(256) void k_tr16(const float* __restrict__ in,
                                              u16* __restrict__ out) {
  __shared__ float Ls[32][36];
  int b = blockIdx.z;
  int c0 = blockIdx.x * 32, l0 = blockIdx.y * 32;
  int tid = threadIdx.x;
  int r = tid >> 3, q4 = (tid & 7) * 4;
  float4 v = *(const float4*)&in[((size_t)b * CD + c0 + r) * LS + l0 + q4];
  Ls[r][q4] = v.x; Ls[r][q4 + 1] = v.y; Ls[r][q4 + 2] = v.z; Ls[r][q4 + 3] = v.w;
  __syncthreads();
  ushort4 o;
  o.x = f2b(Ls[q4 + 0][r]); o.y = f2b(Ls[q4 + 1][r]);
  o.z = f2b(Ls[q4 + 2][r]); o.w = f2b(Ls[q4 + 3][r]);
  *(ushort4*)&out[((size_t)b * LS + l0 + r) * CD + c0 + q4] = o;
}

// ---------------- eos_p[hh] -> bf16 -------------------------------------------
__global__ void k_eos_p(const float* __restrict__ i2h_w, const float* __restrict__ eos_emb,
                        u16* __restrict__ eos_p) {
  int hh = blockIdx.x * blockDim.x + threadIdx.x;
  if (hh >= HD) return;
  const float* row = i2h_w + (size_t)hh * CD;
  float acc = 0.f;
  for (int c = 0; c < CD; ++c) acc += row[c] * eos_emb[c];
  eos_p[hh] = f2b(acc);
}

// ---------------- prologue MFMA: Hp8[b][l][:] = (Hl16[b][l][:] . i2h16^T) fp8 --
// BM=64 (l), BN=512 (all hh), BK=32; 512 thr = 8 waves; gload_lds staging with
// linear LDS dest + pre-swizzled global source (rule #21). R16: -48us vs R12.
__global__ __launch_bounds__(512) void k_hp_mfma(const u16* __restrict__ A,
                                                 const u16* __restrict__ B,
                                                 u8* __restrict__ Hp) {
  __shared__ u16 As[64 * 32];
  __shared__ u16 Bs[512 * 32];
  int bid = blockIdx.x;
  int z = bid >> 2, m0 = (bid & 3) * 64;
  int tid = threadIdx.x, wid = tid >> 6, lane = tid & 63;
  f32x4 acc[4][4];
#pragma unroll
  for (int i = 0; i < 4; ++i)
#pragma unroll
    for (int j = 0; j < 4; ++j) acc[i][j] = (f32x4){0.f, 0.f, 0.f, 0.f};

  const u16* Az = A + (size_t)z * LS * CD + (size_t)m0 * CD;
  int kc = lane >> 4;
  int ar = lane & 15;
  int bc = wid * 64 + (lane & 15);

#ifdef HAS_GLL
  int arow_g = wid * 16 + (lane >> 2);                    // A rows (wid<4)
  int akc_g  = (lane & 3) ^ ((arow_g >> 1) & 3);
#else
  int arow = tid >> 2, ack = tid & 3;
#endif

  for (int k0 = 0; k0 < CD; k0 += 32) {
#ifdef HAS_GLL
    if (wid < 4) {
      __builtin_amdgcn_global_load_lds(
          (const __attribute__((address_space(1))) void*)(Az + (size_t)arow_g * CD + k0 + akc_g * 8),
          (__attribute__((address_space(3))) void*)&As[wid * 16 * 32],
          16, 0, 0);
    }
#pragma unroll
    for (int g = 0; g < 4; ++g) {
      int r0b  = wid * 64 + g * 16;
      int rowb = r0b + (lane >> 2);
      int kcb  = (lane & 3) ^ ((rowb >> 1) & 3);
      __builtin_amdgcn_global_load_lds(
          (const __attribute__((address_space(1))) void*)(B + (size_t)rowb * CD + k0 + kcb * 8),
          (__attribute__((address_space(3))) void*)&Bs[r0b * 32],
          16, 0, 0);
    }
#else
    if (tid < 256)
      *(uint4*)&As[swz(arow, ack)] = *(const uint4*)&Az[(size_t)arow * CD + k0 + ack * 8];
#pragma unroll
    for (int c = 0; c < 4; ++c)
      *(uint4*)&Bs[swz(tid, c)] = *(const uint4*)&B[(size_t)tid * CD + k0 + c * 8];
#endif
    __syncthreads();
    short8 afr[4], bfr[4];
#pragma unroll
    for (int fm = 0; fm < 4; ++fm) afr[fm] = *(const short8*)&As[swz(ar + fm * 16, kc)];
#pragma unroll
    for (int fn = 0; fn < 4; ++fn) bfr[fn] = *(const short8*)&Bs[swz(bc + fn * 16, kc)];
#pragma unroll
    for (int fm = 0; fm < 4; ++fm)
#pragma unroll
      for (int fn = 0; fn < 4; ++fn)
        acc[fm][fn] = __builtin_amdgcn_mfma_f32_16x16x32_bf16(afr[fm], bfr[fn],
                                                              acc[fm][fn], 0, 0, 0);
    __syncthreads();
  }
  int row0 = m0 + (lane >> 4) * 4;
  int col0 = wid * 64 + (lane & 15);
  u8* Hz = Hp + (size_t)z * LS * HD;
#pragma unroll
  for (int fm = 0; fm < 4; ++fm)
#pragma unroll
    for (int fn = 0; fn < 4; ++fn)
#pragma unroll
      for (int j = 0; j < 4; ++j)
        Hz[(size_t)(row0 + fm * 16 + j) * HD + col0 + fn * 16] = f2fp8(acc[fm][fn][j]);
}

// ---------------- q GEMM: 32x32 tiles, grid 288 (18n x 16m) --------------------
__global__ __launch_bounds__(256) void k_q(const u16* __restrict__ Ah,
                                           const u16* __restrict__ B16,
                                           const float* __restrict__ bq,
                                           float* __restrict__ qb,
                                           float* __restrict__ logits,
                                           int tprev, int T) {
  __shared__ u16 As[32 * 32];
  __shared__ u16 Bs[32 * 32];
  int bid = blockIdx.x;
  int n0 = (bid >> 4) * 32;
  int m0 = (bid & 15) * 32;
  int tid = threadIdx.x, wid = tid >> 6, lane = tid & 63;
  int wr = wid >> 1, wc = wid & 1;
  f32x4 acc = (f32x4){0.f, 0.f, 0.f, 0.f};

  int t2 = tid & 127;
  int srow = t2 >> 2, sck = t2 & 3;
  bool isA = tid < 128;
  int kc = lane >> 4;
  int ar = wr * 16 + (lane & 15);
  int bc = wc * 16 + (lane & 15);

  uint4 pv;
  if (isA) pv = *(const uint4*)&Ah[(size_t)(m0 + srow) * KC + sck * 8];
  else     pv = *(const uint4*)&B16[(size_t)(n0 + srow) * HD + sck * 8];

  for (int k0 = 0; k0 < HD; k0 += 32) {
    if (isA) *(uint4*)&As[swz(srow, sck)] = pv;
    else     *(uint4*)&Bs[swz(srow, sck)] = pv;
    __syncthreads();
    int k1 = k0 + 32;
    if (k1 < HD) {
      if (isA) pv = *(const uint4*)&Ah[(size_t)(m0 + srow) * KC + k1 + sck * 8];
      else     pv = *(const uint4*)&B16[(size_t)(n0 + srow) * HD + k1 + sck * 8];
    }
    short8 afr = *(const short8*)&As[swz(ar, kc)];
    short8 bfr = *(const short8*)&Bs[swz(bc, kc)];
    acc = __builtin_amdgcn_mfma_f32_16x16x32_bf16(afr, bfr, acc, 0, 0, 0);
    __syncthreads();
  }

  int c = n0 + wc * 16 + (lane & 15);
  int row0 = m0 + wr * 16 + (lane >> 4) * 4;
  float bv = bq[c];
#pragma unroll
  for (int j = 0; j < 4; ++j) {
    int b = row0 + j;
    float v = acc[j] + bv;
    if (c < HD) qb[(size_t)b * HD + c] = v;
    else if (c < HD + NCLS && tprev >= 0)
      logits[((size_t)b * T + tprev) * NCLS + (c - HD)] = v;
  }
}

// ---------------- gates GEMM + fused LSTM: 32x32 tiles, grid 1024 --------------
__global__ __launch_bounds__(256) void k_gates(const u16* __restrict__ xcat,
                                               const u16* __restrict__ wcat,
                                               const float* __restrict__ bcat,
                                               const float* __restrict__ cprev,
                                               float* __restrict__ cnext,
                                               u16* __restrict__ xcat_next) {
  __shared__ u16 As[32 * 32];
  __shared__ u16 Bs[32 * 32];
  __shared__ float Ct[32][36];
  int bid = blockIdx.x;
  int n0 = (bid >> 4) * 32;
  int m0 = (bid & 15) * 32;
  int tid = threadIdx.x, wid = tid >> 6, lane = tid & 63;
  int wr = wid >> 1, wc = wid & 1;
  f32x4 acc = (f32x4){0.f, 0.f, 0.f, 0.f};

  int t2 = tid & 127;
  int srow = t2 >> 2, sck = t2 & 3;
  bool isA = tid < 128;
  int kc = lane >> 4;
  int ar = wr * 16 + (lane & 15);
  int bc = wc * 16 + (lane & 15);

  uint4 pv;
  if (isA) pv = *(const uint4*)&xcat[(size_t)(m0 + srow) * KC + sck * 8];
  else     pv = *(const uint4*)&wcat[(size_t)(n0 + srow) * KC + sck * 8];

  for (int k0 = 0; k0 < KC; k0 += 32) {
    if (isA) *(uint4*)&As[swz(srow, sck)] = pv;
    else     *(uint4*)&Bs[swz(srow, sck)] = pv;
    __syncthreads();
    int k1 = k0 + 32;
    if (k1 < KC) {
      if (isA) pv = *(const uint4*)&xcat[(size_t)(m0 + srow) * KC + k1 + sck * 8];
      else     pv = *(const uint4*)&wcat[(size_t)(n0 + srow) * KC + k1 + sck * 8];
    }
    short8 afr = *(const short8*)&As[swz(ar, kc)];
    short8 bfr = *(const short8*)&Bs[swz(bc, kc)];
    acc = __builtin_amdgcn_mfma_f32_16x16x32_bf16(afr, bfr, acc, 0, 0, 0);
    __syncthreads();
  }

  int col0 = wc * 16 + (lane & 15);
  int row0 = wr * 16 + (lane >> 4) * 4;
  {
    float bv = bcat[n0 + col0];
#pragma unroll
    for (int j = 0; j < 4; ++j)
      Ct[row0 + j][col0] = acc[j] + bv;
  }
  __syncthreads();

  // fused LSTM: 32 b x 8 hh = 256 items; gates i,f,g,o contiguous per hh
  int hh0 = n0 >> 2;
  int b_loc = tid >> 3, hh_loc = tid & 7;
  float4 g4 = *(const float4*)&Ct[b_loc][hh_loc * 4];
  int b_g = m0 + b_loc, hh_g = hh0 + hh_loc;
  float cp = cprev[(size_t)b_g * HD + hh_g];
  float si = sigm_f(g4.x);
  float sf = sigm_f(g4.y);
  float so = sigm_f(g4.w);
  float c = sf * cp + si * tanh_f(g4.z);
  float h = so * tanh_f(c);
  cnext[(size_t)b_g * HD + hh_g] = c;
  xcat_next[(size_t)b_g * KC + CD + hh_g] = f2b(h);
}

// ---------------- fused attention: scores -> direct softmax -> ctx -------------
// scores are bounded (|e| <= ||score_w||_1 ~ 20) -> exp never overflows f32;
// skipping the max pass is exact up to fp rounding and saves 2 barriers.
__global__ __launch_bounds__(1024) void k_att(
    const u8* __restrict__ Hp, const u16* __restrict__ eos_p,
    const u16* __restrict__ Hl,
    const float* __restrict__ qb, const float* __restrict__ score_w,
    const float* __restrict__ mask, const float* __restrict__ eos_emb,
    u16* __restrict__ xcat, float* __restrict__ char_maps, int t, int T) {
  __shared__ float e_s[260];
  __shared__ float a_s[260];
  __shared__ float cpart[16][520];
  __shared__ float wred[16];
  __shared__ float sget[2];
  int b = blockIdx.x, tid = threadIdx.x;
  int wid = tid >> 6, lane = tid & 63;

  float q_r[8], sw_r[8];
  {
    const float4* q4 = (const float4*)(qb + (size_t)b * HD);
    float4 a0 = q4[lane * 2], a1 = q4[lane * 2 + 1];
    q_r[0] = a0.x; q_r[1] = a0.y; q_r[2] = a0.z; q_r[3] = a0.w;
    q_r[4] = a1.x; q_r[5] = a1.y; q_r[6] = a1.z; q_r[7] = a1.w;
    const float4* s4 = (const float4*)score_w;
    float4 s0 = s4[lane * 2], s1 = s4[lane * 2 + 1];
    sw_r[0] = s0.x; sw_r[1] = s0.y; sw_r[2] = s0.z; sw_r[3] = s0.w;
    sw_r[4] = s1.x; sw_r[5] = s1.y; sw_r[6] = s1.z; sw_r[7] = s1.w;
  }

  // ---- scores: wave per key row (Hp fp8; EOS row bf16)
  const u8* hpB = Hp + (size_t)b * LS * HD;
#pragma unroll 8
  for (int l = wid; l < LP1; l += 16) {
    float x[8];
    if (l < LS) {
      uint2 rv = *(const uint2*)(hpB + (size_t)l * HD + lane * 8);
      unpk8fp8(rv, x);
    } else {
      uint4 rv = *(const uint4*)(eos_p + lane * 8);
      unpack8(rv, x);
    }
    float e = 0.f;
#pragma unroll
    for (int j = 0; j < 8; ++j) e += tanh_f(x[j] + q_r[j]) * sw_r[j];
#pragma unroll
    for (int off = 32; off > 0; off >>= 1) e += __shfl_xor(e, off);
    if (lane == 0) e_s[l] = e;
  }
  __syncthreads();

  // ---- mask + direct softmax over 257 (no max pass)
  float p = 0.f;
  if (tid < LS) {
    float pm = rintf(1.0f - mask[(size_t)b * LS + tid]);
    p = (pm >= 0.5f) ? 0.f : exp_f(e_s[tid]);
  } else if (tid == LS) {
    p = exp_f(e_s[LS]);
  }
  {
    float sv = p;
#pragma unroll
    for (int off = 32; off > 0; off >>= 1) sv += __shfl_xor(sv, off);
    if (lane == 0) wred[wid] = sv;
  }
  __syncthreads();
  if (tid == 0) {
    float s = 0.f;
#pragma unroll
    for (int i = 0; i < 16; ++i) s += wred[i];
    sget[0] = 1.0f / s;
  }
  __syncthreads();
  float inv = sget[0];
  float* cm = char_maps + ((size_t)b * T + t) * LP1;
  if (tid <= LS) {
    float al = p * inv;
    a_s[tid] = al;
    cm[tid] = al;
  }
  __syncthreads();

  // ---- ctx[c] = sum_l a[l]*Hl[l][c] + a_eos*eos_emb[c] -> xcat[b][0:512] bf16
  float cacc[8] = {0.f, 0.f, 0.f, 0.f, 0.f, 0.f, 0.f, 0.f};
  const u16* HB = Hl + (size_t)b * LS * CD;
#pragma unroll 4
  for (int l = wid; l < LS; l += 16) {
    float al = a_s[l];
    uint4 rv = *(const uint4*)(HB + (size_t)l * CD + lane * 8);
    float x[8]; unpack8(rv, x);
#pragma unroll
    for (int j = 0; j < 8; ++j) cacc[j] += al * x[j];
  }
  if (wid == 0) {
    float ae = a_s[LS];
#pragma unroll
    for (int j = 0; j < 8; ++j) cacc[j] += ae * eos_emb[lane * 8 + j];
  }
  *(float4*)&cpart[wid][lane * 8]     = make_float4(cacc[0], cacc[1], cacc[2], cacc[3]);
  *(float4*)&cpart[wid][lane * 8 + 4] = make_float4(cacc[4], cacc[5], cacc[6], cacc[7]);
  __syncthreads();
  if (tid < CD) {
    float s = 0.f;
#pragma unroll
    for (int w = 0; w < 16; ++w) s += cpart[w][tid];
    xcat[(size_t)b * KC + tid] = f2b(s);
  }
}

extern "C" void kernel_launch(void* const* d_in, const int* in_sizes, int n_in,
                              void* d_out, int out_size, void* d_ws, size_t ws_size,
                              hipStream_t stream) {
  const float* batch_H = (const float*)d_in[0];
  const float* mask    = (const float*)d_in[1];
  const float* i2h_w   = (const float*)d_in[2];
  const float* h2h_w   = (const float*)d_in[3];
  const float* h2h_b   = (const float*)d_in[4];
  const float* score_w = (const float*)d_in[5];
  const float* w_ih    = (const float*)d_in[6];
  const float* w_hh    = (const float*)d_in[7];
  const float* b_ih    = (const float*)d_in[8];
  const float* b_hh    = (const float*)d_in[9];
  const float* gen_w   = (const float*)d_in[10];
  const float* gen_b   = (const float*)d_in[11];
  const float* eos_emb = (const float*)d_in[12];

  int T = out_size / (BB * (NCLS + LP1));   // 26

  char* p = (char*)d_ws;
  auto alloc = [&](size_t bytes) -> char* {
    char* r = p; p += (bytes + 255) & ~(size_t)255; return r;
  };
  u16*   Hl16  = (u16*)alloc((size_t)BB * LS * CD * 2);
  u8*    Hp8   = (u8*) alloc((size_t)BB * LS * HD);
  u16*   i2h16 = (u16*)alloc((size_t)HD * CD * 2);
  u16*   B16   = (u16*)alloc((size_t)NQ * HD * 2);
  float* bq    = (float*)alloc((size_t)NQ * 4);
  u16*   wcat  = (u16*)alloc((size_t)4 * HD * KC * 2);
  float* bcat  = (float*)alloc((size_t)4 * HD * 4);
  u16*   eos16 = (u16*)alloc((size_t)HD * 2);
  u16*   xcatA = (u16*)alloc((size_t)BB * KC * 2);
  u16*   xcatB = (u16*)alloc((size_t)BB * KC * 2);
  float* qb    = (float*)alloc((size_t)BB * HD * 4);
  float* c0    = (float*)alloc((size_t)BB * HD * 4);
  float* c1    = (float*)alloc((size_t)BB * HD * 4);

  float* logits    = (float*)d_out;
  float* char_maps = logits + (size_t)BB * T * NCLS;

  hipMemsetAsync(c0, 0, (size_t)BB * HD * 4, stream);
  hipMemsetAsync(xcatA, 0, (size_t)BB * KC * 2, stream);

  // prologue
  k_cvt<<<(HD * CD / 4 + 255) / 256, 256, 0, stream>>>(i2h_w, i2h16, HD * CD / 4);
  k_b16<<<(NQ * HD / 4) / 256, 256, 0, stream>>>(h2h_w, gen_w, B16);
  k_bq<<<(NQ + 255) / 256, 256, 0, stream>>>(h2h_b, gen_b, bq);
  k_wcat<<<(4 * HD * KC / 4) / 256, 256, 0, stream>>>(w_ih, w_hh, wcat);
  k_bcat<<<(4 * HD + 255) / 256, 256, 0, stream>>>(b_ih, b_hh, bcat);
  k_eos_p<<<2, 256, 0, stream>>>(i2h_w, eos_emb, eos16);
  k_tr16<<<dim3(CD / 32, LS / 32, BB), 256, 0, stream>>>(batch_H, Hl16);
  k_hp_mfma<<<4 * BB, 512, 0, stream>>>(Hl16, i2h16, Hp8);

  float *cp = c0, *cnb = c1;
  u16 *xcur = xcatA, *xnext = xcatB;
  for (int t = 0; t < T; ++t) {
    k_q<<<288, 256, 0, stream>>>(xcur + CD, B16, bq, qb, logits, t - 1, T);
    k_att<<<BB, 1024, 0, stream>>>(Hp8, eos16, Hl16, qb, score_w,
                                   mask, eos_emb, xcur, char_maps, t, T);
    k_gates<<<1024, 256, 0, stream>>>(xcur, wcat, bcat, cp, cnb, xnext);
    float* tmp = cp; cp = cnb; cnb = tmp;
    u16* tx = xcur; xcur = xnext; xnext = tx;
  }
  // final logits from h_T (q output unused)
  k_q<<<288, 256, 0, stream>>>(xcur + CD, B16, bq, qb, logits, T - 1, T);
}